// Round 11
// baseline (928.975 us; speedup 1.0000x reference)
//
#include <hip/hip_runtime.h>
#include <stdint.h>

// ---------------------------------------------------------------------------
// Enc_block: KNN graph + gumbel-softmax soft edges + PointTransformerConv +
// down + neighbor max-pool + GridSampling.  N=8192, Cin=64, Cout=128, K=16.
// ---------------------------------------------------------------------------

typedef unsigned int u32;
typedef float v2f __attribute__((ext_vector_type(2)));
typedef float v4f __attribute__((ext_vector_type(4)));

#define NN 8192
#define EPS20 1e-20f
#define QSCALE 489.0671f   // 65535/134; z in [-99.8, 33.3] -> q = (z+100)*QSCALE

// packed fp32 FMA with op_sel broadcast of src1 (no splat movs)
__device__ static inline void pk_fma_lo(v2f& acc, v2f w, v2f e){
  asm("v_pk_fma_f32 %0, %1, %2, %0 op_sel:[0,0,0] op_sel_hi:[1,0,1]"
      : "+v"(acc) : "v"(w), "v"(e));
}
__device__ static inline void pk_fma_hi(v2f& acc, v2f w, v2f e){
  asm("v_pk_fma_f32 %0, %1, %2, %0 op_sel:[0,1,0] op_sel_hi:[1,1,1]"
      : "+v"(acc) : "v"(w), "v"(e));
}

// ---------------- threefry2x32 (JAX key schedule) ----------------
__host__ __device__ static inline u32 rotl32(u32 v, int r){ return (v<<r)|(v>>(32-r)); }

__host__ __device__ static inline void tf2x32(u32 k0, u32 k1, u32 c0, u32 c1, u32& o0, u32& o1){
  u32 ks2 = k0 ^ k1 ^ 0x1BD11BDAu;
  u32 x0 = c0 + k0;
  u32 x1 = c1 + k1;
#define TFR(r) x0 += x1; x1 = rotl32(x1,(r)); x1 ^= x0;
  TFR(13) TFR(15) TFR(26) TFR(6)
  x0 += k1;  x1 += ks2 + 1u;
  TFR(17) TFR(29) TFR(16) TFR(24)
  x0 += ks2; x1 += k0 + 2u;
  TFR(13) TFR(15) TFR(26) TFR(6)
  x0 += k0;  x1 += k1 + 3u;
  TFR(17) TFR(29) TFR(16) TFR(24)
  x0 += k1;  x1 += ks2 + 4u;
  TFR(13) TFR(15) TFR(26) TFR(6)
  x0 += ks2; x1 += k0 + 5u;
#undef TFR
  o0 = x0; o1 = x1;
}

__device__ static inline u32 rbits(u32 k0, u32 k1, u32 idx){
  u32 o0,o1; tf2x32(k0,k1, 0u, idx, o0,o1);   // partitionable: counter (0, idx)
  return o0 ^ o1;                              // 32-bit fold
}

__device__ static inline float u01(u32 b){
  return __uint_as_float((b>>9) | 0x3f800000u) - 1.0f;   // [0,1), JAX formula
}

// z = 2*(log(exp(-d2)+eps) + g)  ==  2*(g - d2) for all entries that can reach
// top-16 or contribute to the colsum (eps correction <=1e-4 there).
__device__ static inline float gumbel_g(u32 ub){
  float u = u01(ub);
  float w = -__logf(u + EPS20);
  return -__logf(w + EPS20);
}

// ---------------- workspace layout ----------------
static constexpr size_t OFF_EMBF = 0;                              // [8192][12] f32: e[10], se, K
static constexpr size_t OFF_SP   = OFF_EMBF + (size_t)8192*12*4;   // (unused, kept for layout)
static constexpr size_t OFF_PSUM = OFF_SP   + (size_t)8192*4;      // [32][8192]
static constexpr size_t OFF_SSRC = OFF_PSUM + (size_t)32*8192*4;   // int [8192][16]
static constexpr size_t OFF_TOPV = OFF_SSRC + (size_t)8192*16*4;
static constexpr size_t OFF_KSRC = OFF_TOPV + (size_t)8192*16*4;   // int [8192][16]
static constexpr size_t OFF_HIST = OFF_KSRC + (size_t)8192*16*4;   // int [8192]
static constexpr size_t OFF_RANK = OFF_HIST + (size_t)8192*4;
static constexpr size_t OFF_UCNT = OFF_RANK + (size_t)8192*4;
static constexpr size_t OFF_VID  = OFF_UCNT + (size_t)8192*4;
static constexpr size_t OFF_META = OFF_VID  + (size_t)8192*4;      // mi i[3] @0, mx i[3] @16B, U i @32B
static constexpr size_t OFF_QKI  = OFF_META + 64;                  // int [8192] quantized K
static constexpr size_t OFF_CAND = OFF_QKI  + (size_t)8192*4;      // int [8192][32]
static constexpr size_t OFF_POS4 = OFF_CAND + (size_t)8192*32*4;   // float4 [8192] {x,y,z,|p|^2}
static constexpr size_t OFF_BIG  = (OFF_POS4 + (size_t)8192*16 + 255) & ~(size_t)255;
// Overlap region: u16 z-cache [8192][8192] lives here during colstats..rescore;
// A/B/V/H/HD/Y/ACCX/ACCP live here afterwards (k_xw launched after rescore).
static constexpr size_t OFF_A    = OFF_BIG;
static constexpr size_t OFF_B    = OFF_A    + (size_t)8192*128*4;
static constexpr size_t OFF_V    = OFF_B    + (size_t)8192*128*4;
static constexpr size_t OFF_H    = OFF_V    + (size_t)8192*128*4;
static constexpr size_t OFF_HD   = OFF_H    + (size_t)8192*128*4;
static constexpr size_t OFF_Y    = OFF_HD   + (size_t)8192*128*4;
static constexpr size_t OFF_ACCX = OFF_Y    + (size_t)8192*128*4;
static constexpr size_t OFF_ACCP = OFF_ACCX + (size_t)8192*128*4;
static constexpr size_t OFF_ZQ   = OFF_BIG;
static constexpr size_t ZQ_BYTES = (size_t)NN*NN*2;

// ---------------- kernels ----------------

__global__ void k_init0(int* __restrict__ mi, int* __restrict__ mx){
  int t = threadIdx.x;
  if (t < 3){ mi[t] = 0x7f7fffff; mx[t] = 0; }
}

// per-dim min of pos (positive floats: int-bit compare is order-preserving)
__global__ __launch_bounds__(256) void k_min(const float* __restrict__ pos, int* __restrict__ mi){
  __shared__ int red[768];
  int t = threadIdx.x;
  int n = blockIdx.x*256 + t;
  red[t]     = __float_as_int(pos[n*3+0]);
  red[256+t] = __float_as_int(pos[n*3+1]);
  red[512+t] = __float_as_int(pos[n*3+2]);
  __syncthreads();
  for (int s=128; s>0; s>>=1){
    if (t < s){
      red[t]     = min(red[t],     red[t+s]);
      red[256+t] = min(red[256+t], red[256+t+s]);
      red[512+t] = min(red[512+t], red[512+t+s]);
    }
    __syncthreads();
  }
  if (t == 0){ atomicMin(&mi[0], red[0]); atomicMin(&mi[1], red[256]); atomicMin(&mi[2], red[512]); }
}

// per-dim max voxel index
__global__ __launch_bounds__(256) void k_ext(const float* __restrict__ pos, const int* __restrict__ mi,
                                             int* __restrict__ mx){
  __shared__ int red[768];
  int t = threadIdx.x;
  int n = blockIdx.x*256 + t;
  float p0 = __int_as_float(mi[0]), p1 = __int_as_float(mi[1]), p2 = __int_as_float(mi[2]);
  red[t]     = (int)floorf((pos[n*3+0]-p0)*2.0f);   // /0.5 == *2 exactly
  red[256+t] = (int)floorf((pos[n*3+1]-p1)*2.0f);
  red[512+t] = (int)floorf((pos[n*3+2]-p2)*2.0f);
  __syncthreads();
  for (int s=128; s>0; s>>=1){
    if (t < s){
      red[t]     = max(red[t],     red[t+s]);
      red[256+t] = max(red[256+t], red[256+t+s]);
      red[512+t] = max(red[512+t], red[512+t+s]);
    }
    __syncthreads();
  }
  if (t == 0){ atomicMax(&mx[0], red[0]); atomicMax(&mx[1], red[256]); atomicMax(&mx[2], red[512]); }
}

// voxel id + histogram + SoA pos4 = {x,y,z,|p|^2}
__global__ __launch_bounds__(256) void k_vid(const float* __restrict__ pos,
                                             const int* __restrict__ mi, const int* __restrict__ mx,
                                             int* __restrict__ vid, int* __restrict__ hist,
                                             float4* __restrict__ pos4){
  int n = blockIdx.x*256 + threadIdx.x;
  float p0=pos[n*3], p1=pos[n*3+1], p2=pos[n*3+2];
  float4 p4; p4.x=p0; p4.y=p1; p4.z=p2; p4.w = p0*p0 + p1*p1 + p2*p2;
  pos4[n] = p4;
  float q0 = __int_as_float(mi[0]), q1 = __int_as_float(mi[1]), q2 = __int_as_float(mi[2]);
  int v0 = (int)floorf((p0-q0)*2.0f);
  int v1 = (int)floorf((p1-q1)*2.0f);
  int v2 = (int)floorf((p2-q2)*2.0f);
  int nv1 = mx[1]+1, nv2 = mx[2]+1;
  int id = (v0*nv1 + v1)*nv2 + v2;
  vid[n] = id;
  atomicAdd(&hist[id], 1);
}

// embF[i] = { relu(x@Wg1+bg1)@Wg2+bg2 + u*0.001  (10), |emb|^2, 0 }
__global__ __launch_bounds__(64) void k_emb(const float* __restrict__ x,
    const float* __restrict__ Wg1, const float* __restrict__ bg1,
    const float* __restrict__ Wg2, const float* __restrict__ bg2,
    u32 ka, u32 kb, float* __restrict__ embF){
  int i = blockIdx.x; int t = threadIdx.x;
  __shared__ float xs[64], hs[64], esq[10];
  xs[t] = x[i*64+t];
  __syncthreads();
  float a = bg1[t];
  for (int k=0; k<64; k++) a += xs[k]*Wg1[k*64+t];
  hs[t] = fmaxf(a, 0.0f);
  __syncthreads();
  if (t < 10){
    float e = bg2[t];
    for (int k=0; k<64; k++) e += hs[k]*Wg2[k*10+t];
    e += u01(rbits(ka, kb, (u32)(i*10+t))) * 0.001f;
    embF[i*12+t] = e;
    esq[t] = e*e;
  }
  __syncthreads();
  if (t == 0){
    float ssum = 0.0f;
    #pragma unroll
    for (int d=0; d<10; d++) ssum += esq[d];
    embF[i*12+10] = ssum;
    embF[i*12+11] = 0.0f;
  }
}

// KNN: top-16 smallest d2 per row (diag excluded), ties -> lower index.
// SoA float4 loads; per-lane top-8 (P[lane holds >8 of global top-16] ~ 1e-11/row);
// full 6-round shfl butterfly merge (known-good).
__global__ __launch_bounds__(64) void k_knn(const float4* __restrict__ pos4,
                                            int* __restrict__ knn_src){
  int i = blockIdx.x; int l = threadIdx.x;
  float4 pi = pos4[i];
  float lv[8]; int lj[8];
  #pragma unroll
  for (int s=0; s<8; s++){ lv[s]=1e30f; lj[s]=0x7fffffff; }
  for (int tt=0; tt<128; tt++){
    int j = l + 64*tt;
    float4 pj = pos4[j];
    float d = pi.w + pj.w - 2.0f*(pi.x*pj.x + pi.y*pj.y + pi.z*pj.z);
    d = fmaxf(d, 0.0f);
    if (j != i && d < lv[7]){
      lv[7]=d; lj[7]=j;
      #pragma unroll
      for (int s=7; s>0; s--){
        if (lv[s] < lv[s-1]){ float tv=lv[s]; lv[s]=lv[s-1]; lv[s-1]=tv; int tj=lj[s]; lj[s]=lj[s-1]; lj[s-1]=tj; }
      }
    }
  }
  for (int r=0; r<16; r++){
    float bv = lv[0]; int bj = lj[0];
    #pragma unroll
    for (int off=32; off>=1; off>>=1){
      float ov = __shfl_xor(bv, off);
      int   oj = __shfl_xor(bj, off);
      if (ov < bv || (ov == bv && oj < bj)){ bv = ov; bj = oj; }
    }
    if (l == 0) knn_src[i*16+r] = bj;
    if (lj[0] == bj){
      #pragma unroll
      for (int s=0; s<7; s++){ lv[s]=lv[s+1]; lj[s]=lj[s+1]; }
      lv[7]=1e30f; lj[7]=0x7fffffff;
    }
  }
}

// z = 2*(g - d2).  Hard bound: z <= 2*g_max <= 33.3, so sum(exp(z-40)) never
// overflows -> no max pass needed.  Stores quantized z (u16) into the cache.
template<bool STZ>
__global__ __launch_bounds__(256) void k_colstats(const float* __restrict__ embF,
                                                  u32 ka, u32 kb, float* __restrict__ psum,
                                                  unsigned short* __restrict__ zq){
  __shared__ float4 sE4[768];                 // 256 rows x 12 floats
  int t = threadIdx.x;
  int j = blockIdx.x*256 + t;
  int i0 = blockIdx.y*256;
  const float4* gF = (const float4*)embF;
  #pragma unroll
  for (int q=0; q<3; q++) sE4[t + 256*q] = gF[(size_t)i0*3 + t + 256*q];
  __syncthreads();
  float4 b0 = gF[j*3+0], b1 = gF[j*3+1], b2 = gF[j*3+2];
  float sej = b2.z;
  float s = 0.0f;
  unsigned short* zp = STZ ? (zq + ((size_t)i0<<13) + j) : nullptr;
  for (int r=0; r<256; r++){
    float4 a0 = sE4[r*3+0], a1 = sE4[r*3+1], a2 = sE4[r*3+2];
    float dot = a0.x*b0.x + a0.y*b0.y + a0.z*b0.z + a0.w*b0.w
              + a1.x*b1.x + a1.y*b1.y + a1.z*b1.z + a1.w*b1.w
              + a2.x*b2.x + a2.y*b2.y;
    float d2 = fmaxf(a2.z + sej - 2.0f*dot, 0.0f);
    float g = gumbel_g(rbits(ka, kb, (u32)(i0+r)*8192u + (u32)j));
    float z = 2.0f*(g - d2);
    s += __expf(z - 40.0f);
    if (STZ){
      float qf = (z + 100.0f)*QSCALE + 0.5f;
      qf = fminf(fmaxf(qf, 0.0f), 65535.0f);
      *zp = (unsigned short)qf;
      zp += NN;
    }
  }
  psum[blockIdx.y*NN + j] = s;
}

// K_j = 40 + log(sum_chunks psum); write f32 K into embF[j][11] and quantized K
__global__ __launch_bounds__(256) void k_colfin(const float* __restrict__ psum, float* __restrict__ embF,
                                                int* __restrict__ qKi){
  int j = blockIdx.x*256 + threadIdx.x;
  float S = 0.0f;
  for (int c=0; c<32; c++) S += psum[c*NN + j];
  float K = 40.0f + __logf(S);
  embF[j*12+11] = K;
  qKi[j] = (int)((K + 100.0f)*QSCALE + 0.5f);   // same transform as z
}

// FALLBACK: per-row top-16 of y = z - K_j by full recompute
__global__ __launch_bounds__(64) void k_rowtopk(const float* __restrict__ embF,
    u32 ka, u32 kb, int* __restrict__ soft_src, float* __restrict__ top_v){
  int i = blockIdx.x; int l = threadIdx.x;
  const float4* gF = (const float4*)embF;
  float4 b0 = gF[i*3+0], b1 = gF[i*3+1], b2 = gF[i*3+2];
  float sei = b2.z;
  float lv[16]; int lj[16];
  #pragma unroll
  for (int s=0; s<16; s++){ lv[s]=-1e30f; lj[s]=0x7fffffff; }
  for (int tt=0; tt<128; tt++){
    int j = l + 64*tt;
    float4 a0 = gF[j*3+0], a1 = gF[j*3+1], a2 = gF[j*3+2];
    float dot = a0.x*b0.x + a0.y*b0.y + a0.z*b0.z + a0.w*b0.w
              + a1.x*b1.x + a1.y*b1.y + a1.z*b1.z + a1.w*b1.w
              + a2.x*b2.x + a2.y*b2.y;
    float d2 = fmaxf(a2.z + sei - 2.0f*dot, 0.0f);
    float g = gumbel_g(rbits(ka, kb, (u32)i*8192u + (u32)j));
    float z = 2.0f*(g - d2);
    float y = z - a2.w;
    if (y > lv[15]){
      lv[15]=y; lj[15]=j;
      #pragma unroll
      for (int s=15; s>0; s--){
        if (lv[s] > lv[s-1]){ float tv=lv[s]; lv[s]=lv[s-1]; lv[s-1]=tv; int tj=lj[s]; lj[s]=lj[s-1]; lj[s-1]=tj; }
      }
    }
  }
  for (int r=0; r<16; r++){
    float bv = lv[0]; int bj = lj[0];
    #pragma unroll
    for (int off=32; off>=1; off>>=1){
      float ov = __shfl_xor(bv, off);
      int   oj = __shfl_xor(bj, off);
      if (ov > bv || (ov == bv && oj < bj)){ bv = ov; bj = oj; }
    }
    if (l == 0){ soft_src[i*16+r] = bj; top_v[i*16+r] = __expf(bv); }
    if (lj[0] == bj){
      #pragma unroll
      for (int s=0; s<15; s++){ lv[s]=lv[s+1]; lj[s]=lj[s+1]; }
      lv[15]=-1e30f; lj[15]=0x7fffffff;
    }
  }
}

// cached path A: per-row top-32 candidates by integer qy = q_z - q_K.
// per-lane top-8 + full shfl butterfly merge (known-good).
__global__ __launch_bounds__(64) void k_qtopk(const unsigned short* __restrict__ zq,
    const int* __restrict__ qKi, int* __restrict__ cand){
  int i = blockIdx.x; int l = threadIdx.x;
  const uint4* zrow = (const uint4*)(zq + ((size_t)i<<13));   // 8 u16 per uint4
  int lv[8]; int lj[8];
  #pragma unroll
  for (int s=0; s<8; s++){ lv[s]=-0x40000000; lj[s]=0x7fffffff; }
  for (int tt=0; tt<16; tt++){
    int blk = l + 64*tt;
    uint4 zv = zrow[blk];
    int jb = blk*8;
    const int4* qk4 = (const int4*)(qKi + jb);
    int4 ka4 = qk4[0], kb4 = qk4[1];
    u32 wv[4] = {zv.x, zv.y, zv.z, zv.w};
    int qk[8] = {ka4.x,ka4.y,ka4.z,ka4.w, kb4.x,kb4.y,kb4.z,kb4.w};
    #pragma unroll
    for (int c=0; c<8; c++){
      int qz = (int)((wv[c>>1] >> ((c&1)*16)) & 0xffffu);
      int qy = qz - qk[c];
      if (qy > lv[7]){
        lv[7]=qy; lj[7]=jb+c;
        #pragma unroll
        for (int s=7; s>0; s--){
          if (lv[s] > lv[s-1]){ int tv=lv[s]; lv[s]=lv[s-1]; lv[s-1]=tv; int tj=lj[s]; lj[s]=lj[s-1]; lj[s-1]=tj; }
        }
      }
    }
  }
  for (int r=0; r<32; r++){
    int bv = lv[0]; int bj = lj[0];
    #pragma unroll
    for (int off=32; off>=1; off>>=1){
      int ov = __shfl_xor(bv, off);
      int oj = __shfl_xor(bj, off);
      if (ov > bv || (ov == bv && oj < bj)){ bv = ov; bj = oj; }
    }
    if (l == 0) cand[i*32+r] = bj;
    if (lj[0] == bj){
      #pragma unroll
      for (int s=0; s<7; s++){ lv[s]=lv[s+1]; lj[s]=lj[s+1]; }
      lv[7]=-0x40000000; lj[7]=0x7fffffff;
    }
  }
}

// cached path B: exact rescore of the 32 candidates -> exact top-16
__global__ __launch_bounds__(64) void k_rescore(const float* __restrict__ embF,
    const int* __restrict__ cand, u32 ka, u32 kb,
    int* __restrict__ soft_src, float* __restrict__ top_v){
  int i = blockIdx.x; int l = threadIdx.x;
  const float4* gF = (const float4*)embF;
  float4 b0 = gF[i*3+0], b1 = gF[i*3+1], b2 = gF[i*3+2];
  float sei = b2.z;
  float y = -1e30f; int jc = 0x7fffffff;
  if (l < 32){
    jc = cand[i*32+l];
    float4 a0 = gF[jc*3+0], a1 = gF[jc*3+1], a2 = gF[jc*3+2];
    float dot = a0.x*b0.x + a0.y*b0.y + a0.z*b0.z + a0.w*b0.w
              + a1.x*b1.x + a1.y*b1.y + a1.z*b1.z + a1.w*b1.w
              + a2.x*b2.x + a2.y*b2.y;
    float d2 = fmaxf(a2.z + sei - 2.0f*dot, 0.0f);
    float g = gumbel_g(rbits(ka, kb, (u32)i*8192u + (u32)jc));
    float z = 2.0f*(g - d2);
    y = z - a2.w;
  }
  for (int r=0; r<16; r++){
    float bv = y; int bj = jc;
    #pragma unroll
    for (int off=32; off>=1; off>>=1){
      float ov = __shfl_xor(bv, off);
      int   oj = __shfl_xor(bj, off);
      if (ov > bv || (ov == bv && oj < bj)){ bv = ov; bj = oj; }
    }
    if (l == 0){ soft_src[i*16+r] = bj; top_v[i*16+r] = __expf(bv); }
    if (jc == bj){ y = -1e30f; jc = 0x7fffffff; }
  }
}

// A = x@Wsrc, B = x@Wdst, V = x@Wlin  (8 rows per block)
__global__ __launch_bounds__(128) void k_xw(const float* __restrict__ x,
    const float* __restrict__ Wsrc, const float* __restrict__ Wdst, const float* __restrict__ Wlin,
    float* __restrict__ A, float* __restrict__ B, float* __restrict__ V){
  int g0 = blockIdx.x*8; int c = threadIdx.x;
  __shared__ float xs[8][64];
  for (int idx=c; idx<512; idx+=128) xs[idx>>6][idx&63] = x[(g0 + (idx>>6))*64 + (idx&63)];
  __syncthreads();
  float aA[8], aB[8], aV[8];
  #pragma unroll
  for (int g=0; g<8; g++){ aA[g]=0.0f; aB[g]=0.0f; aV[g]=0.0f; }
  for (int k=0; k<64; k++){
    float ws=Wsrc[k*128+c], wd=Wdst[k*128+c], wl=Wlin[k*128+c];
    #pragma unroll
    for (int g=0; g<8; g++){
      float xv = xs[g][k];
      aA[g] += xv*ws; aB[g] += xv*wd; aV[g] += xv*wl;
    }
  }
  #pragma unroll
  for (int g=0; g<8; g++){
    A[(g0+g)*128+c]=aA[g]; B[(g0+g)*128+c]=aB[g]; V[(g0+g)*128+c]=aV[g];
  }
}

// k-split GEMM, op_sel packed FMA: lane (kh=l>>5, q=l&31) does 8 edges x 4 cols
// over its 64-k half; activation quad consumed via op_sel broadcast (0 movs).
#define GEMMW2(WPTR)                                                        \
  {                                                                         \
    const v4f* __restrict__ Wp = ((const v4f*)(WPTR)) + khbase*32 + q;      \
    _Pragma("unroll")                                                       \
    for (int e=0; e<8; e++){ accA[e] = (v2f){0.f,0.f}; accB[e] = (v2f){0.f,0.f}; } \
    for (int kk=0; kk<16; kk++){                                            \
      v4f w0 = Wp[0], w1 = Wp[32], w2 = Wp[64], w3 = Wp[96];                \
      Wp += 128;                                                            \
      v2f w0a = __builtin_shufflevector(w0,w0,0,1), w0b = __builtin_shufflevector(w0,w0,2,3); \
      v2f w1a = __builtin_shufflevector(w1,w1,0,1), w1b = __builtin_shufflevector(w1,w1,2,3); \
      v2f w2a = __builtin_shufflevector(w2,w2,0,1), w2b = __builtin_shufflevector(w2,w2,2,3); \
      v2f w3a = __builtin_shufflevector(w3,w3,0,1), w3b = __builtin_shufflevector(w3,w3,2,3); \
      _Pragma("unroll")                                                     \
      for (int e=0; e<8; e++){                                              \
        v4f ev = *(const v4f*)(&ein[e0+e][khbase + 4*kk]);                  \
        v2f exy = __builtin_shufflevector(ev,ev,0,1);                       \
        v2f ezw = __builtin_shufflevector(ev,ev,2,3);                       \
        pk_fma_lo(accA[e], w0a, exy); pk_fma_lo(accB[e], w0b, exy);         \
        pk_fma_hi(accA[e], w1a, exy); pk_fma_hi(accB[e], w1b, exy);         \
        pk_fma_lo(accA[e], w2a, ezw); pk_fma_lo(accB[e], w2b, ezw);         \
        pk_fma_hi(accA[e], w3a, ezw); pk_fma_hi(accB[e], w3b, ezw);         \
      }                                                                     \
    }                                                                       \
  }

// cross-half reduction (lane ^ 32) + bias (shfl form -- known good)
#define KREDUCE(BPTR)                                                       \
  {                                                                         \
    float4 bb = ((const float4*)(BPTR))[q];                                 \
    _Pragma("unroll")                                                       \
    for (int e=0; e<8; e++){                                                \
      accA[e].x += __shfl_xor(accA[e].x, 32); accA[e].x += bb.x;            \
      accA[e].y += __shfl_xor(accA[e].y, 32); accA[e].y += bb.y;            \
      accB[e].x += __shfl_xor(accB[e].x, 32); accB[e].x += bb.z;            \
      accB[e].y += __shfl_xor(accB[e].y, 32); accB[e].y += bb.w;            \
    }                                                                       \
  }

// PointTransformerConv, per-target fused. 256 threads = 4 waves x 8 edges.
// NOTE: no min-waves clause -- (256,4) forced VGPR=64 + catastrophic spill (R2).
__global__ __launch_bounds__(256) void k_edge(const float* __restrict__ pos,
    const int* __restrict__ soft_src, const float* __restrict__ top_v, const int* __restrict__ knn_src,
    const float* __restrict__ A, const float* __restrict__ B, const float* __restrict__ V,
    const float* __restrict__ Wp1, const float* __restrict__ bp1,
    const float* __restrict__ Wp2, const float* __restrict__ bp2,
    const float* __restrict__ Wa1, const float* __restrict__ ba1,
    const float* __restrict__ Wa2, const float* __restrict__ ba2,
    float* __restrict__ h){
  int i = blockIdx.x; int t = threadIdx.x;
  int l = t & 63; int w = t >> 6; int e0 = w*8;
  int kh = l >> 5; int q = l & 31;
  const int khbase = kh*64;
  __shared__ float ein[32][128];
  __shared__ int   ssrc[32];
  __shared__ float sw[32];
  __shared__ float sdp[32][3];
  if (t < 32){
    int s; float wt;
    if (t < 16){ s = soft_src[i*16+t]; wt = top_v[i*16+t]; }
    else       { s = knn_src[i*16+(t-16)]; wt = 1.0f; }
    ssrc[t]=s; sw[t]=wt;
    sdp[t][0]=pos[i*3]-pos[s*3]; sdp[t][1]=pos[i*3+1]-pos[s*3+1]; sdp[t][2]=pos[i*3+2]-pos[s*3+2];
  }
  __syncthreads();
  v2f accA[8], accB[8], dlA[8], dlB[8];
  // stage 1: ph = relu(dpos @ Wp1 + bp1)
  {
    const float2* W1v = (const float2*)Wp1;
    float2 r0 = W1v[l], r1 = W1v[64+l], r2 = W1v[128+l];
    float2 bb = ((const float2*)bp1)[l];
    #pragma unroll
    for (int e=0; e<8; e++){
      float d0=sdp[e0+e][0], d1=sdp[e0+e][1], d2=sdp[e0+e][2];
      float2 v;
      v.x = fmaxf(d0*r0.x + d1*r1.x + d2*r2.x + bb.x, 0.0f);
      v.y = fmaxf(d0*r0.y + d1*r1.y + d2*r2.y + bb.y, 0.0f);
      *(float2*)(&ein[e0+e][2*l]) = v;
    }
  }
  // delta = ph @ Wp2 + bp2
  GEMMW2(Wp2); KREDUCE(bp2);
  #pragma unroll
  for (int e=0; e<8; e++){ dlA[e] = accA[e]; dlB[e] = accB[e]; }
  // q = B[i] - A[src] + delta   (kh==0 lanes write float4)
  if (kh == 0){
    float4 bi = ((const float4*)(&B[(size_t)i*128]))[q];
    #pragma unroll
    for (int e=0; e<8; e++){
      float4 av = ((const float4*)(&A[(size_t)ssrc[e0+e]*128]))[q];
      float4 v; v.x = bi.x - av.x + dlA[e].x; v.y = bi.y - av.y + dlA[e].y;
      v.z = bi.z - av.z + dlB[e].x; v.w = bi.w - av.w + dlB[e].y;
      *(float4*)(&ein[e0+e][4*q]) = v;
    }
  }
  // ah = relu(q @ Wa1 + ba1)
  GEMMW2(Wa1); KREDUCE(ba1);
  if (kh == 0){
    #pragma unroll
    for (int e=0; e<8; e++){
      float4 v; v.x=fmaxf(accA[e].x,0.f); v.y=fmaxf(accA[e].y,0.f);
      v.z=fmaxf(accB[e].x,0.f); v.w=fmaxf(accB[e].y,0.f);
      *(float4*)(&ein[e0+e][4*q]) = v;
    }
  }
  // logits = ah @ Wa2 + ba2
  GEMMW2(Wa2); KREDUCE(ba2);
  // cross-wave softmax over 32 edges; partials reuse dead ein rows:
  float* rbuf = &ein[0][0];
  v2f mA = accA[0], mB = accB[0];
  #pragma unroll
  for (int e=1; e<8; e++){
    mA.x=fmaxf(mA.x,accA[e].x); mA.y=fmaxf(mA.y,accA[e].y);
    mB.x=fmaxf(mB.x,accB[e].x); mB.y=fmaxf(mB.y,accB[e].y);
  }
  __syncthreads();                                   // all GEMM3 LDS reads done
  if (kh == 0){
    float4 mv; mv.x=mA.x; mv.y=mA.y; mv.z=mB.x; mv.w=mB.y;
    *(float4*)(&rbuf[w*128 + 4*q]) = mv;
  }
  __syncthreads();
  float4 M; M.x=-1e30f; M.y=-1e30f; M.z=-1e30f; M.w=-1e30f;
  #pragma unroll
  for (int ww=0; ww<4; ww++){
    float4 mm = *(const float4*)(&rbuf[ww*128 + 4*q]);
    M.x=fmaxf(M.x,mm.x); M.y=fmaxf(M.y,mm.y); M.z=fmaxf(M.z,mm.z); M.w=fmaxf(M.w,mm.w);
  }
  if (kh == 0){
    float4 s2; s2.x=0.f; s2.y=0.f; s2.z=0.f; s2.w=0.f;
    float4 h2; h2.x=0.f; h2.y=0.f; h2.z=0.f; h2.w=0.f;
    #pragma unroll
    for (int e=0; e<8; e++){
      int s = ssrc[e0+e]; float wt = sw[e0+e];
      float4 vv = ((const float4*)(&V[(size_t)s*128]))[q];
      float p;
      p = __expf(accA[e].x - M.x); s2.x += p; h2.x += p*(vv.x + dlA[e].x)*wt;
      p = __expf(accA[e].y - M.y); s2.y += p; h2.y += p*(vv.y + dlA[e].y)*wt;
      p = __expf(accB[e].x - M.z); s2.z += p; h2.z += p*(vv.z + dlB[e].x)*wt;
      p = __expf(accB[e].y - M.w); s2.w += p; h2.w += p*(vv.w + dlB[e].y)*wt;
    }
    *(float4*)(&rbuf[512  + w*128 + 4*q]) = s2;
    *(float4*)(&rbuf[1024 + w*128 + 4*q]) = h2;
  }
  __syncthreads();
  if (w == 0 && kh == 0){
    float4 S; S.x=0.f; S.y=0.f; S.z=0.f; S.w=0.f;
    float4 H; H.x=0.f; H.y=0.f; H.z=0.f; H.w=0.f;
    #pragma unroll
    for (int ww=0; ww<4; ww++){
      float4 sv = *(const float4*)(&rbuf[512  + ww*128 + 4*q]);
      float4 hv = *(const float4*)(&rbuf[1024 + ww*128 + 4*q]);
      S.x+=sv.x; S.y+=sv.y; S.z+=sv.z; S.w+=sv.w;
      H.x+=hv.x; H.y+=hv.y; H.z+=hv.z; H.w+=hv.w;
    }
    float4 o; o.x=H.x/(S.x+1e-16f); o.y=H.y/(S.y+1e-16f);
    o.z=H.z/(S.z+1e-16f); o.w=H.w/(S.w+1e-16f);
    *(float4*)(&h[(size_t)i*128 + 4*q]) = o;
  }
}

// hd = relu(h @ Wd + bd)
__global__ __launch_bounds__(128) void k_down(const float* __restrict__ h,
    const float* __restrict__ Wd, const float* __restrict__ bd, float* __restrict__ hd){
  int g0 = blockIdx.x*8; int c = threadIdx.x;
  __shared__ float hs[8][128];
  for (int idx=c; idx<1024; idx+=128) hs[idx>>7][idx&127] = h[(g0 + (idx>>7))*128 + (idx&127)];
  __syncthreads();
  float acc[8]; float b = bd[c];
  #pragma unroll
  for (int g=0; g<8; g++) acc[g] = b;
  for (int k=0; k<128; k+=4){
    float w0=Wd[(k+0)*128+c], w1=Wd[(k+1)*128+c], w2=Wd[(k+2)*128+c], w3=Wd[(k+3)*128+c];
    #pragma unroll
    for (int g=0; g<8; g++){
      const float4 ev = *(const float4*)(&hs[g][k]);
      acc[g] += ev.x*w0 + ev.y*w1 + ev.z*w2 + ev.w*w3;
    }
  }
  #pragma unroll
  for (int g=0; g<8; g++) hd[(g0+g)*128+c] = fmaxf(acc[g], 0.0f);
}

// y = max(hd[i], max over 32 neighbors hd[src])
__global__ __launch_bounds__(128) void k_pool(const float* __restrict__ hd,
    const int* __restrict__ soft_src, const int* __restrict__ knn_src, float* __restrict__ y){
  int i = blockIdx.x; int c = threadIdx.x;
  __shared__ int ss[32];
  if (c < 16) ss[c] = soft_src[i*16+c];
  else if (c < 32) ss[c] = knn_src[i*16+(c-16)];
  __syncthreads();
  float p = hd[i*128+c];
  for (int e=0; e<32; e++) p = fmaxf(p, hd[ss[e]*128+c]);
  y[i*128+c] = p;
}

// ranks = sorted-unique inverse (count of nonzero bins with smaller vid)
__global__ __launch_bounds__(256) void k_scan(const int* __restrict__ hist,
    int* __restrict__ rank, int* __restrict__ ucnt, int* __restrict__ Uo){
  __shared__ int part[256];
  int t = threadIdx.x;
  int base = t*32;
  int cnt = 0;
  for (int b=0; b<32; b++) cnt += (hist[base+b] > 0);
  part[t] = cnt;
  __syncthreads();
  if (t == 0){
    int run = 0;
    for (int q=0; q<256; q++){ int v = part[q]; part[q] = run; run += v; }
    Uo[0] = run;
  }
  __syncthreads();
  int run = part[t];
  for (int b=0; b<32; b++){
    int bin = base + b;
    rank[bin] = run;
    int hv = hist[bin];
    if (hv > 0){ ucnt[run] = hv; run++; }
  }
}

__global__ __launch_bounds__(128) void k_agg(const float* __restrict__ y, const float* __restrict__ pos,
    const int* __restrict__ vid, const int* __restrict__ rank,
    float* __restrict__ accx, float* __restrict__ accp){
  int n = blockIdx.x; int c = threadIdx.x;
  int r = rank[vid[n]];
  atomicAdd(&accx[r*128+c], y[n*128+c]);
  if (c < 3) atomicAdd(&accp[r*3+c], pos[n*3+c]);
}

__global__ __launch_bounds__(128) void k_final(const float* __restrict__ accx, const float* __restrict__ accp,
    const int* __restrict__ ucnt, const int* __restrict__ Uo, float* __restrict__ out){
  int r = blockIdx.x; int c = threadIdx.x;
  int u = Uo[0];
  float cnt = (r < u) ? (float)ucnt[r] : 0.0f;
  float den = fmaxf(cnt, 1.0f);
  out[r*128+c] = (r < u) ? accx[r*128+c]/den : 0.0f;
  if (c < 3) out[(size_t)NN*128 + r*3 + c] = (r < u) ? accp[r*3+c]/den : 0.0f;
  if (c == 0) out[(size_t)NN*128 + (size_t)NN*3 + r] = cnt;
}

// ---------------- launcher ----------------
extern "C" void kernel_launch(void* const* d_in, const int* in_sizes, int n_in,
                              void* d_out, int out_size, void* d_ws, size_t ws_size,
                              hipStream_t stream){
  (void)in_sizes; (void)n_in; (void)out_size;
  const float* x    = (const float*)d_in[0];
  const float* pos  = (const float*)d_in[1];
  const float* Wg1  = (const float*)d_in[2];
  const float* bg1  = (const float*)d_in[3];
  const float* Wg2  = (const float*)d_in[4];
  const float* bg2  = (const float*)d_in[5];
  const float* Wlin = (const float*)d_in[6];
  const float* Wsrc = (const float*)d_in[7];
  const float* Wdst = (const float*)d_in[8];
  const float* Wp1  = (const float*)d_in[9];
  const float* bp1  = (const float*)d_in[10];
  const float* Wp2  = (const float*)d_in[11];
  const float* bp2  = (const float*)d_in[12];
  const float* Wa1  = (const float*)d_in[13];
  const float* ba1  = (const float*)d_in[14];
  const float* Wa2  = (const float*)d_in[15];
  const float* ba2  = (const float*)d_in[16];
  const float* Wd   = (const float*)d_in[17];
  const float* bd   = (const float*)d_in[18];

  char* ws = (char*)d_ws;
  float* embF   = (float*)(ws + OFF_EMBF);
  float* psum   = (float*)(ws + OFF_PSUM);
  int*   ssrc   = (int*)  (ws + OFF_SSRC);
  float* topv   = (float*)(ws + OFF_TOPV);
  int*   ksrc   = (int*)  (ws + OFF_KSRC);
  int*   hist   = (int*)  (ws + OFF_HIST);
  int*   rank   = (int*)  (ws + OFF_RANK);
  int*   ucnt   = (int*)  (ws + OFF_UCNT);
  int*   vid    = (int*)  (ws + OFF_VID);
  int*   mi     = (int*)  (ws + OFF_META);
  int*   mx     = (int*)  (ws + OFF_META + 16);
  int*   Uo     = (int*)  (ws + OFF_META + 32);
  int*   qKi    = (int*)  (ws + OFF_QKI);
  int*   cand   = (int*)  (ws + OFF_CAND);
  float4* pos4  = (float4*)(ws + OFF_POS4);
  float* A      = (float*)(ws + OFF_A);
  float* B      = (float*)(ws + OFF_B);
  float* V      = (float*)(ws + OFF_V);
  float* h      = (float*)(ws + OFF_H);
  float* hd     = (float*)(ws + OFF_HD);
  float* y      = (float*)(ws + OFF_Y);
  float* accx   = (float*)(ws + OFF_ACCX);
  float* accp   = (float*)(ws + OFF_ACCP);
  unsigned short* zq = (unsigned short*)(ws + OFF_ZQ);

  const bool use_q = (ws_size >= OFF_ZQ + ZQ_BYTES);   // constant per run -> deterministic

  // rk = jax.random.split(jax.random.key(42), 2)  -- host threefry (foldlike)
  u32 rk0a, rk0b, rk1a, rk1b;
  tf2x32(0u, 42u, 0u, 0u, rk0a, rk0b);
  tf2x32(0u, 42u, 0u, 1u, rk1a, rk1b);

  hipMemsetAsync(hist, 0, 8192*4, stream);
  k_init0<<<1, 64, 0, stream>>>(mi, mx);
  k_min<<<32, 256, 0, stream>>>(pos, mi);
  k_ext<<<32, 256, 0, stream>>>(pos, mi, mx);
  k_vid<<<32, 256, 0, stream>>>(pos, mi, mx, vid, hist, pos4);
  k_emb<<<8192, 64, 0, stream>>>(x, Wg1, bg1, Wg2, bg2, rk0a, rk0b, embF);
  k_knn<<<8192, 64, 0, stream>>>(pos4, ksrc);
  if (use_q){
    k_colstats<true><<<dim3(32,32), 256, 0, stream>>>(embF, rk1a, rk1b, psum, zq);
    k_colfin<<<32, 256, 0, stream>>>(psum, embF, qKi);
    k_qtopk<<<8192, 64, 0, stream>>>(zq, qKi, cand);
    k_rescore<<<8192, 64, 0, stream>>>(embF, cand, rk1a, rk1b, ssrc, topv);
  } else {
    k_colstats<false><<<dim3(32,32), 256, 0, stream>>>(embF, rk1a, rk1b, psum, nullptr);
    k_colfin<<<32, 256, 0, stream>>>(psum, embF, qKi);
    k_rowtopk<<<8192, 64, 0, stream>>>(embF, rk1a, rk1b, ssrc, topv);
  }
  // Overlap region is free of z-cache readers from here on.
  k_xw<<<1024, 128, 0, stream>>>(x, Wsrc, Wdst, Wlin, A, B, V);
  k_edge<<<8192, 256, 0, stream>>>(pos, ssrc, topv, ksrc, A, B, V,
                                   Wp1, bp1, Wp2, bp2, Wa1, ba1, Wa2, ba2, h);
  k_down<<<1024, 128, 0, stream>>>(h, Wd, bd, hd);
  k_pool<<<8192, 128, 0, stream>>>(hd, ssrc, ksrc, y);
  hipMemsetAsync(accx, 0, (size_t)8192*128*4, stream);
  hipMemsetAsync(accp, 0, (size_t)8192*3*4, stream);
  k_scan<<<1, 256, 0, stream>>>(hist, rank, ucnt, Uo);
  k_agg<<<8192, 128, 0, stream>>>(y, pos, vid, rank, accx, accp);
  k_final<<<8192, 128, 0, stream>>>(accx, accp, ucnt, Uo, (float*)d_out);
}

// Round 12
// 925.058 us; speedup vs baseline: 1.0042x; 1.0042x over previous
//
#include <hip/hip_runtime.h>
#include <stdint.h>

// ---------------------------------------------------------------------------
// Enc_block: KNN graph + gumbel-softmax soft edges + PointTransformerConv +
// down + neighbor max-pool + GridSampling.  N=8192, Cin=64, Cout=128, K=16.
// ---------------------------------------------------------------------------

typedef unsigned int u32;
typedef float v2f __attribute__((ext_vector_type(2)));
typedef float v4f __attribute__((ext_vector_type(4)));

#define NN 8192
#define EPS20 1e-20f
#define QSCALE 489.0671f   // 65535/134; z in [-99.8, 33.3] -> q = (z+100)*QSCALE

// packed fp32 FMA with op_sel broadcast of src1 (no splat movs)
__device__ static inline void pk_fma_lo(v2f& acc, v2f w, v2f e){
  asm("v_pk_fma_f32 %0, %1, %2, %0 op_sel:[0,0,0] op_sel_hi:[1,0,1]"
      : "+v"(acc) : "v"(w), "v"(e));
}
__device__ static inline void pk_fma_hi(v2f& acc, v2f w, v2f e){
  asm("v_pk_fma_f32 %0, %1, %2, %0 op_sel:[0,1,0] op_sel_hi:[1,1,1]"
      : "+v"(acc) : "v"(w), "v"(e));
}

// ---------------- threefry2x32 (JAX key schedule) ----------------
__host__ __device__ static inline u32 rotl32(u32 v, int r){ return (v<<r)|(v>>(32-r)); }

__host__ __device__ static inline void tf2x32(u32 k0, u32 k1, u32 c0, u32 c1, u32& o0, u32& o1){
  u32 ks2 = k0 ^ k1 ^ 0x1BD11BDAu;
  u32 x0 = c0 + k0;
  u32 x1 = c1 + k1;
#define TFR(r) x0 += x1; x1 = rotl32(x1,(r)); x1 ^= x0;
  TFR(13) TFR(15) TFR(26) TFR(6)
  x0 += k1;  x1 += ks2 + 1u;
  TFR(17) TFR(29) TFR(16) TFR(24)
  x0 += ks2; x1 += k0 + 2u;
  TFR(13) TFR(15) TFR(26) TFR(6)
  x0 += k0;  x1 += k1 + 3u;
  TFR(17) TFR(29) TFR(16) TFR(24)
  x0 += k1;  x1 += ks2 + 4u;
  TFR(13) TFR(15) TFR(26) TFR(6)
  x0 += ks2; x1 += k0 + 5u;
#undef TFR
  o0 = x0; o1 = x1;
}

__device__ static inline u32 rbits(u32 k0, u32 k1, u32 idx){
  u32 o0,o1; tf2x32(k0,k1, 0u, idx, o0,o1);   // partitionable: counter (0, idx)
  return o0 ^ o1;                              // 32-bit fold
}

__device__ static inline float u01(u32 b){
  return __uint_as_float((b>>9) | 0x3f800000u) - 1.0f;   // [0,1), JAX formula
}

// z = 2*(log(exp(-d2)+eps) + g)  ==  2*(g - d2) for all entries that can reach
// top-16 or contribute to the colsum (eps correction <=1e-4 there).
__device__ static inline float gumbel_g(u32 ub){
  float u = u01(ub);
  float w = -__logf(u + EPS20);
  return -__logf(w + EPS20);
}

// ---------------- workspace layout ----------------
static constexpr size_t OFF_EMBF = 0;                              // [8192][12] f32: e[10], se, K
static constexpr size_t OFF_SP   = OFF_EMBF + (size_t)8192*12*4;   // (unused, kept for layout)
static constexpr size_t OFF_PSUM = OFF_SP   + (size_t)8192*4;      // [32][8192]
static constexpr size_t OFF_SSRC = OFF_PSUM + (size_t)32*8192*4;   // int [8192][16]
static constexpr size_t OFF_TOPV = OFF_SSRC + (size_t)8192*16*4;
static constexpr size_t OFF_KSRC = OFF_TOPV + (size_t)8192*16*4;   // int [8192][16]
static constexpr size_t OFF_HIST = OFF_KSRC + (size_t)8192*16*4;   // int [8192]
static constexpr size_t OFF_RANK = OFF_HIST + (size_t)8192*4;
static constexpr size_t OFF_UCNT = OFF_RANK + (size_t)8192*4;
static constexpr size_t OFF_VID  = OFF_UCNT + (size_t)8192*4;
static constexpr size_t OFF_META = OFF_VID  + (size_t)8192*4;      // mi i[3] @0, mx i[3] @16B, U i @32B
static constexpr size_t OFF_QKI  = OFF_META + 64;                  // int [8192] quantized K
static constexpr size_t OFF_CAND = OFF_QKI  + (size_t)8192*4;      // int [8192][32]
static constexpr size_t OFF_POS4 = OFF_CAND + (size_t)8192*32*4;   // float4 [8192] {x,y,z,|p|^2}
static constexpr size_t OFF_BIG  = (OFF_POS4 + (size_t)8192*16 + 255) & ~(size_t)255;
// Overlap region: u16 z-cache [8192][8192] lives here during colstats..rescore;
// A/B/V/H/HD/Y/ACCX/ACCP live here afterwards (k_xw launched after rescore).
static constexpr size_t OFF_A    = OFF_BIG;
static constexpr size_t OFF_B    = OFF_A    + (size_t)8192*128*4;
static constexpr size_t OFF_V    = OFF_B    + (size_t)8192*128*4;
static constexpr size_t OFF_H    = OFF_V    + (size_t)8192*128*4;
static constexpr size_t OFF_HD   = OFF_H    + (size_t)8192*128*4;
static constexpr size_t OFF_Y    = OFF_HD   + (size_t)8192*128*4;
static constexpr size_t OFF_ACCX = OFF_Y    + (size_t)8192*128*4;
static constexpr size_t OFF_ACCP = OFF_ACCX + (size_t)8192*128*4;
static constexpr size_t OFF_ZQ   = OFF_BIG;
static constexpr size_t ZQ_BYTES = (size_t)NN*NN*2;

// ---------------- kernels ----------------

__global__ void k_init0(int* __restrict__ mi, int* __restrict__ mx){
  int t = threadIdx.x;
  if (t < 3){ mi[t] = 0x7f7fffff; mx[t] = 0; }
}

// per-dim min of pos (positive floats: int-bit compare is order-preserving)
__global__ __launch_bounds__(256) void k_min(const float* __restrict__ pos, int* __restrict__ mi){
  __shared__ int red[768];
  int t = threadIdx.x;
  int n = blockIdx.x*256 + t;
  red[t]     = __float_as_int(pos[n*3+0]);
  red[256+t] = __float_as_int(pos[n*3+1]);
  red[512+t] = __float_as_int(pos[n*3+2]);
  __syncthreads();
  for (int s=128; s>0; s>>=1){
    if (t < s){
      red[t]     = min(red[t],     red[t+s]);
      red[256+t] = min(red[256+t], red[256+t+s]);
      red[512+t] = min(red[512+t], red[512+t+s]);
    }
    __syncthreads();
  }
  if (t == 0){ atomicMin(&mi[0], red[0]); atomicMin(&mi[1], red[256]); atomicMin(&mi[2], red[512]); }
}

// per-dim max voxel index
__global__ __launch_bounds__(256) void k_ext(const float* __restrict__ pos, const int* __restrict__ mi,
                                             int* __restrict__ mx){
  __shared__ int red[768];
  int t = threadIdx.x;
  int n = blockIdx.x*256 + t;
  float p0 = __int_as_float(mi[0]), p1 = __int_as_float(mi[1]), p2 = __int_as_float(mi[2]);
  red[t]     = (int)floorf((pos[n*3+0]-p0)*2.0f);   // /0.5 == *2 exactly
  red[256+t] = (int)floorf((pos[n*3+1]-p1)*2.0f);
  red[512+t] = (int)floorf((pos[n*3+2]-p2)*2.0f);
  __syncthreads();
  for (int s=128; s>0; s>>=1){
    if (t < s){
      red[t]     = max(red[t],     red[t+s]);
      red[256+t] = max(red[256+t], red[256+t+s]);
      red[512+t] = max(red[512+t], red[512+t+s]);
    }
    __syncthreads();
  }
  if (t == 0){ atomicMax(&mx[0], red[0]); atomicMax(&mx[1], red[256]); atomicMax(&mx[2], red[512]); }
}

// voxel id + histogram + SoA pos4 = {x,y,z,|p|^2}
__global__ __launch_bounds__(256) void k_vid(const float* __restrict__ pos,
                                             const int* __restrict__ mi, const int* __restrict__ mx,
                                             int* __restrict__ vid, int* __restrict__ hist,
                                             float4* __restrict__ pos4){
  int n = blockIdx.x*256 + threadIdx.x;
  float p0=pos[n*3], p1=pos[n*3+1], p2=pos[n*3+2];
  float4 p4; p4.x=p0; p4.y=p1; p4.z=p2; p4.w = p0*p0 + p1*p1 + p2*p2;
  pos4[n] = p4;
  float q0 = __int_as_float(mi[0]), q1 = __int_as_float(mi[1]), q2 = __int_as_float(mi[2]);
  int v0 = (int)floorf((p0-q0)*2.0f);
  int v1 = (int)floorf((p1-q1)*2.0f);
  int v2 = (int)floorf((p2-q2)*2.0f);
  int nv1 = mx[1]+1, nv2 = mx[2]+1;
  int id = (v0*nv1 + v1)*nv2 + v2;
  vid[n] = id;
  atomicAdd(&hist[id], 1);
}

// embF[i] = { relu(x@Wg1+bg1)@Wg2+bg2 + u*0.001  (10), |emb|^2, 0 }
__global__ __launch_bounds__(64) void k_emb(const float* __restrict__ x,
    const float* __restrict__ Wg1, const float* __restrict__ bg1,
    const float* __restrict__ Wg2, const float* __restrict__ bg2,
    u32 ka, u32 kb, float* __restrict__ embF){
  int i = blockIdx.x; int t = threadIdx.x;
  __shared__ float xs[64], hs[64], esq[10];
  xs[t] = x[i*64+t];
  __syncthreads();
  float a = bg1[t];
  for (int k=0; k<64; k++) a += xs[k]*Wg1[k*64+t];
  hs[t] = fmaxf(a, 0.0f);
  __syncthreads();
  if (t < 10){
    float e = bg2[t];
    for (int k=0; k<64; k++) e += hs[k]*Wg2[k*10+t];
    e += u01(rbits(ka, kb, (u32)(i*10+t))) * 0.001f;
    embF[i*12+t] = e;
    esq[t] = e*e;
  }
  __syncthreads();
  if (t == 0){
    float ssum = 0.0f;
    #pragma unroll
    for (int d=0; d<10; d++) ssum += esq[d];
    embF[i*12+10] = ssum;
    embF[i*12+11] = 0.0f;
  }
}

// KNN: top-16 smallest d2 per row (diag excluded), ties -> lower index.
// SoA float4 loads; per-lane top-8 (P[lane holds >8 of global top-16] ~ 1e-11/row);
// full 6-round shfl butterfly merge (known-good).
__global__ __launch_bounds__(64) void k_knn(const float4* __restrict__ pos4,
                                            int* __restrict__ knn_src){
  int i = blockIdx.x; int l = threadIdx.x;
  float4 pi = pos4[i];
  float lv[8]; int lj[8];
  #pragma unroll
  for (int s=0; s<8; s++){ lv[s]=1e30f; lj[s]=0x7fffffff; }
  for (int tt=0; tt<128; tt++){
    int j = l + 64*tt;
    float4 pj = pos4[j];
    float d = pi.w + pj.w - 2.0f*(pi.x*pj.x + pi.y*pj.y + pi.z*pj.z);
    d = fmaxf(d, 0.0f);
    if (j != i && d < lv[7]){
      lv[7]=d; lj[7]=j;
      #pragma unroll
      for (int s=7; s>0; s--){
        if (lv[s] < lv[s-1]){ float tv=lv[s]; lv[s]=lv[s-1]; lv[s-1]=tv; int tj=lj[s]; lj[s]=lj[s-1]; lj[s-1]=tj; }
      }
    }
  }
  for (int r=0; r<16; r++){
    float bv = lv[0]; int bj = lj[0];
    #pragma unroll
    for (int off=32; off>=1; off>>=1){
      float ov = __shfl_xor(bv, off);
      int   oj = __shfl_xor(bj, off);
      if (ov < bv || (ov == bv && oj < bj)){ bv = ov; bj = oj; }
    }
    if (l == 0) knn_src[i*16+r] = bj;
    if (lj[0] == bj){
      #pragma unroll
      for (int s=0; s<7; s++){ lv[s]=lv[s+1]; lj[s]=lj[s+1]; }
      lv[7]=1e30f; lj[7]=0x7fffffff;
    }
  }
}

// z = 2*(g - d2).  Hard bound: z <= 2*g_max <= 33.3, so sum(exp(z-40)) never
// overflows -> no max pass needed.  Stores quantized z (u16) into the cache.
template<bool STZ>
__global__ __launch_bounds__(256) void k_colstats(const float* __restrict__ embF,
                                                  u32 ka, u32 kb, float* __restrict__ psum,
                                                  unsigned short* __restrict__ zq){
  __shared__ float4 sE4[768];                 // 256 rows x 12 floats
  int t = threadIdx.x;
  int j = blockIdx.x*256 + t;
  int i0 = blockIdx.y*256;
  const float4* gF = (const float4*)embF;
  #pragma unroll
  for (int q=0; q<3; q++) sE4[t + 256*q] = gF[(size_t)i0*3 + t + 256*q];
  __syncthreads();
  float4 b0 = gF[j*3+0], b1 = gF[j*3+1], b2 = gF[j*3+2];
  float sej = b2.z;
  float s = 0.0f;
  unsigned short* zp = STZ ? (zq + ((size_t)i0<<13) + j) : nullptr;
  for (int r=0; r<256; r++){
    float4 a0 = sE4[r*3+0], a1 = sE4[r*3+1], a2 = sE4[r*3+2];
    float dot = a0.x*b0.x + a0.y*b0.y + a0.z*b0.z + a0.w*b0.w
              + a1.x*b1.x + a1.y*b1.y + a1.z*b1.z + a1.w*b1.w
              + a2.x*b2.x + a2.y*b2.y;
    float d2 = fmaxf(a2.z + sej - 2.0f*dot, 0.0f);
    float g = gumbel_g(rbits(ka, kb, (u32)(i0+r)*8192u + (u32)j));
    float z = 2.0f*(g - d2);
    s += __expf(z - 40.0f);
    if (STZ){
      float qf = (z + 100.0f)*QSCALE + 0.5f;
      qf = fminf(fmaxf(qf, 0.0f), 65535.0f);
      *zp = (unsigned short)qf;
      zp += NN;
    }
  }
  psum[blockIdx.y*NN + j] = s;
}

// K_j = 40 + log(sum_chunks psum); write f32 K into embF[j][11] and quantized K
__global__ __launch_bounds__(256) void k_colfin(const float* __restrict__ psum, float* __restrict__ embF,
                                                int* __restrict__ qKi){
  int j = blockIdx.x*256 + threadIdx.x;
  float S = 0.0f;
  for (int c=0; c<32; c++) S += psum[c*NN + j];
  float K = 40.0f + __logf(S);
  embF[j*12+11] = K;
  qKi[j] = (int)((K + 100.0f)*QSCALE + 0.5f);   // same transform as z
}

// FALLBACK: per-row top-16 of y = z - K_j by full recompute
__global__ __launch_bounds__(64) void k_rowtopk(const float* __restrict__ embF,
    u32 ka, u32 kb, int* __restrict__ soft_src, float* __restrict__ top_v){
  int i = blockIdx.x; int l = threadIdx.x;
  const float4* gF = (const float4*)embF;
  float4 b0 = gF[i*3+0], b1 = gF[i*3+1], b2 = gF[i*3+2];
  float sei = b2.z;
  float lv[16]; int lj[16];
  #pragma unroll
  for (int s=0; s<16; s++){ lv[s]=-1e30f; lj[s]=0x7fffffff; }
  for (int tt=0; tt<128; tt++){
    int j = l + 64*tt;
    float4 a0 = gF[j*3+0], a1 = gF[j*3+1], a2 = gF[j*3+2];
    float dot = a0.x*b0.x + a0.y*b0.y + a0.z*b0.z + a0.w*b0.w
              + a1.x*b1.x + a1.y*b1.y + a1.z*b1.z + a1.w*b1.w
              + a2.x*b2.x + a2.y*b2.y;
    float d2 = fmaxf(a2.z + sei - 2.0f*dot, 0.0f);
    float g = gumbel_g(rbits(ka, kb, (u32)i*8192u + (u32)j));
    float z = 2.0f*(g - d2);
    float y = z - a2.w;
    if (y > lv[15]){
      lv[15]=y; lj[15]=j;
      #pragma unroll
      for (int s=15; s>0; s--){
        if (lv[s] > lv[s-1]){ float tv=lv[s]; lv[s]=lv[s-1]; lv[s-1]=tv; int tj=lj[s]; lj[s]=lj[s-1]; lj[s-1]=tj; }
      }
    }
  }
  for (int r=0; r<16; r++){
    float bv = lv[0]; int bj = lj[0];
    #pragma unroll
    for (int off=32; off>=1; off>>=1){
      float ov = __shfl_xor(bv, off);
      int   oj = __shfl_xor(bj, off);
      if (ov > bv || (ov == bv && oj < bj)){ bv = ov; bj = oj; }
    }
    if (l == 0){ soft_src[i*16+r] = bj; top_v[i*16+r] = __expf(bv); }
    if (lj[0] == bj){
      #pragma unroll
      for (int s=0; s<15; s++){ lv[s]=lv[s+1]; lj[s]=lj[s+1]; }
      lv[15]=-1e30f; lj[15]=0x7fffffff;
    }
  }
}

// cached path A: per-row top-32 candidates by integer qy = q_z - q_K.
// per-lane top-8 + full shfl butterfly merge (known-good).
__global__ __launch_bounds__(64) void k_qtopk(const unsigned short* __restrict__ zq,
    const int* __restrict__ qKi, int* __restrict__ cand){
  int i = blockIdx.x; int l = threadIdx.x;
  const uint4* zrow = (const uint4*)(zq + ((size_t)i<<13));   // 8 u16 per uint4
  int lv[8]; int lj[8];
  #pragma unroll
  for (int s=0; s<8; s++){ lv[s]=-0x40000000; lj[s]=0x7fffffff; }
  for (int tt=0; tt<16; tt++){
    int blk = l + 64*tt;
    uint4 zv = zrow[blk];
    int jb = blk*8;
    const int4* qk4 = (const int4*)(qKi + jb);
    int4 ka4 = qk4[0], kb4 = qk4[1];
    u32 wv[4] = {zv.x, zv.y, zv.z, zv.w};
    int qk[8] = {ka4.x,ka4.y,ka4.z,ka4.w, kb4.x,kb4.y,kb4.z,kb4.w};
    #pragma unroll
    for (int c=0; c<8; c++){
      int qz = (int)((wv[c>>1] >> ((c&1)*16)) & 0xffffu);
      int qy = qz - qk[c];
      if (qy > lv[7]){
        lv[7]=qy; lj[7]=jb+c;
        #pragma unroll
        for (int s=7; s>0; s--){
          if (lv[s] > lv[s-1]){ int tv=lv[s]; lv[s]=lv[s-1]; lv[s-1]=tv; int tj=lj[s]; lj[s]=lj[s-1]; lj[s-1]=tj; }
        }
      }
    }
  }
  for (int r=0; r<32; r++){
    int bv = lv[0]; int bj = lj[0];
    #pragma unroll
    for (int off=32; off>=1; off>>=1){
      int ov = __shfl_xor(bv, off);
      int oj = __shfl_xor(bj, off);
      if (ov > bv || (ov == bv && oj < bj)){ bv = ov; bj = oj; }
    }
    if (l == 0) cand[i*32+r] = bj;
    if (lj[0] == bj){
      #pragma unroll
      for (int s=0; s<7; s++){ lv[s]=lv[s+1]; lj[s]=lj[s+1]; }
      lv[7]=-0x40000000; lj[7]=0x7fffffff;
    }
  }
}

// cached path B: exact rescore of the 32 candidates -> exact top-16
__global__ __launch_bounds__(64) void k_rescore(const float* __restrict__ embF,
    const int* __restrict__ cand, u32 ka, u32 kb,
    int* __restrict__ soft_src, float* __restrict__ top_v){
  int i = blockIdx.x; int l = threadIdx.x;
  const float4* gF = (const float4*)embF;
  float4 b0 = gF[i*3+0], b1 = gF[i*3+1], b2 = gF[i*3+2];
  float sei = b2.z;
  float y = -1e30f; int jc = 0x7fffffff;
  if (l < 32){
    jc = cand[i*32+l];
    float4 a0 = gF[jc*3+0], a1 = gF[jc*3+1], a2 = gF[jc*3+2];
    float dot = a0.x*b0.x + a0.y*b0.y + a0.z*b0.z + a0.w*b0.w
              + a1.x*b1.x + a1.y*b1.y + a1.z*b1.z + a1.w*b1.w
              + a2.x*b2.x + a2.y*b2.y;
    float d2 = fmaxf(a2.z + sei - 2.0f*dot, 0.0f);
    float g = gumbel_g(rbits(ka, kb, (u32)i*8192u + (u32)jc));
    float z = 2.0f*(g - d2);
    y = z - a2.w;
  }
  for (int r=0; r<16; r++){
    float bv = y; int bj = jc;
    #pragma unroll
    for (int off=32; off>=1; off>>=1){
      float ov = __shfl_xor(bv, off);
      int   oj = __shfl_xor(bj, off);
      if (ov > bv || (ov == bv && oj < bj)){ bv = ov; bj = oj; }
    }
    if (l == 0){ soft_src[i*16+r] = bj; top_v[i*16+r] = __expf(bv); }
    if (jc == bj){ y = -1e30f; jc = 0x7fffffff; }
  }
}

// A = x@Wsrc, B = x@Wdst, V = x@Wlin  (8 rows per block)
__global__ __launch_bounds__(128) void k_xw(const float* __restrict__ x,
    const float* __restrict__ Wsrc, const float* __restrict__ Wdst, const float* __restrict__ Wlin,
    float* __restrict__ A, float* __restrict__ B, float* __restrict__ V){
  int g0 = blockIdx.x*8; int c = threadIdx.x;
  __shared__ float xs[8][64];
  for (int idx=c; idx<512; idx+=128) xs[idx>>6][idx&63] = x[(g0 + (idx>>6))*64 + (idx&63)];
  __syncthreads();
  float aA[8], aB[8], aV[8];
  #pragma unroll
  for (int g=0; g<8; g++){ aA[g]=0.0f; aB[g]=0.0f; aV[g]=0.0f; }
  for (int k=0; k<64; k++){
    float ws=Wsrc[k*128+c], wd=Wdst[k*128+c], wl=Wlin[k*128+c];
    #pragma unroll
    for (int g=0; g<8; g++){
      float xv = xs[g][k];
      aA[g] += xv*ws; aB[g] += xv*wd; aV[g] += xv*wl;
    }
  }
  #pragma unroll
  for (int g=0; g<8; g++){
    A[(g0+g)*128+c]=aA[g]; B[(g0+g)*128+c]=aB[g]; V[(g0+g)*128+c]=aV[g];
  }
}

// k-split GEMM, op_sel packed FMA: lane (kh=l>>5, q=l&31) does 8 edges x 4 cols
// over its 64-k half; activation quad consumed via op_sel broadcast (0 movs).
#define GEMMW2(WPTR)                                                        \
  {                                                                         \
    const v4f* __restrict__ Wp = ((const v4f*)(WPTR)) + khbase*32 + q;      \
    _Pragma("unroll")                                                       \
    for (int e=0; e<8; e++){ accA[e] = (v2f){0.f,0.f}; accB[e] = (v2f){0.f,0.f}; } \
    for (int kk=0; kk<16; kk++){                                            \
      v4f w0 = Wp[0], w1 = Wp[32], w2 = Wp[64], w3 = Wp[96];                \
      Wp += 128;                                                            \
      v2f w0a = __builtin_shufflevector(w0,w0,0,1), w0b = __builtin_shufflevector(w0,w0,2,3); \
      v2f w1a = __builtin_shufflevector(w1,w1,0,1), w1b = __builtin_shufflevector(w1,w1,2,3); \
      v2f w2a = __builtin_shufflevector(w2,w2,0,1), w2b = __builtin_shufflevector(w2,w2,2,3); \
      v2f w3a = __builtin_shufflevector(w3,w3,0,1), w3b = __builtin_shufflevector(w3,w3,2,3); \
      _Pragma("unroll")                                                     \
      for (int e=0; e<8; e++){                                              \
        v4f ev = *(const v4f*)(&ein[e0+e][khbase + 4*kk]);                  \
        v2f exy = __builtin_shufflevector(ev,ev,0,1);                       \
        v2f ezw = __builtin_shufflevector(ev,ev,2,3);                       \
        pk_fma_lo(accA[e], w0a, exy); pk_fma_lo(accB[e], w0b, exy);         \
        pk_fma_hi(accA[e], w1a, exy); pk_fma_hi(accB[e], w1b, exy);         \
        pk_fma_lo(accA[e], w2a, ezw); pk_fma_lo(accB[e], w2b, ezw);         \
        pk_fma_hi(accA[e], w3a, ezw); pk_fma_hi(accB[e], w3b, ezw);         \
      }                                                                     \
    }                                                                       \
  }

// cross-half reduction (lane ^ 32) + bias (shfl form -- known good)
#define KREDUCE(BPTR)                                                       \
  {                                                                         \
    float4 bb = ((const float4*)(BPTR))[q];                                 \
    _Pragma("unroll")                                                       \
    for (int e=0; e<8; e++){                                                \
      accA[e].x += __shfl_xor(accA[e].x, 32); accA[e].x += bb.x;            \
      accA[e].y += __shfl_xor(accA[e].y, 32); accA[e].y += bb.y;            \
      accB[e].x += __shfl_xor(accB[e].x, 32); accB[e].x += bb.z;            \
      accB[e].y += __shfl_xor(accB[e].y, 32); accB[e].y += bb.w;            \
    }                                                                       \
  }

// PointTransformerConv, per-target fused. 256 threads = 4 waves x 8 edges.
// NOTE: no min-waves clause -- (256,4) forced VGPR=64 + catastrophic spill (R2).
__global__ __launch_bounds__(256) void k_edge(const float* __restrict__ pos,
    const int* __restrict__ soft_src, const float* __restrict__ top_v, const int* __restrict__ knn_src,
    const float* __restrict__ A, const float* __restrict__ B, const float* __restrict__ V,
    const float* __restrict__ Wp1, const float* __restrict__ bp1,
    const float* __restrict__ Wp2, const float* __restrict__ bp2,
    const float* __restrict__ Wa1, const float* __restrict__ ba1,
    const float* __restrict__ Wa2, const float* __restrict__ ba2,
    float* __restrict__ h){
  int i = blockIdx.x; int t = threadIdx.x;
  int l = t & 63; int w = t >> 6; int e0 = w*8;
  int kh = l >> 5; int q = l & 31;
  const int khbase = kh*64;
  __shared__ float ein[32][128];
  __shared__ int   ssrc[32];
  __shared__ float sw[32];
  __shared__ float sdp[32][3];
  if (t < 32){
    int s; float wt;
    if (t < 16){ s = soft_src[i*16+t]; wt = top_v[i*16+t]; }
    else       { s = knn_src[i*16+(t-16)]; wt = 1.0f; }
    ssrc[t]=s; sw[t]=wt;
    sdp[t][0]=pos[i*3]-pos[s*3]; sdp[t][1]=pos[i*3+1]-pos[s*3+1]; sdp[t][2]=pos[i*3+2]-pos[s*3+2];
  }
  __syncthreads();
  v2f accA[8], accB[8], dlA[8], dlB[8];
  // stage 1: ph = relu(dpos @ Wp1 + bp1)
  {
    const float2* W1v = (const float2*)Wp1;
    float2 r0 = W1v[l], r1 = W1v[64+l], r2 = W1v[128+l];
    float2 bb = ((const float2*)bp1)[l];
    #pragma unroll
    for (int e=0; e<8; e++){
      float d0=sdp[e0+e][0], d1=sdp[e0+e][1], d2=sdp[e0+e][2];
      float2 v;
      v.x = fmaxf(d0*r0.x + d1*r1.x + d2*r2.x + bb.x, 0.0f);
      v.y = fmaxf(d0*r0.y + d1*r1.y + d2*r2.y + bb.y, 0.0f);
      *(float2*)(&ein[e0+e][2*l]) = v;
    }
  }
  // delta = ph @ Wp2 + bp2
  GEMMW2(Wp2); KREDUCE(bp2);
  #pragma unroll
  for (int e=0; e<8; e++){ dlA[e] = accA[e]; dlB[e] = accB[e]; }
  // q = B[i] - A[src] + delta   (kh==0 lanes write float4)
  if (kh == 0){
    float4 bi = ((const float4*)(&B[(size_t)i*128]))[q];
    #pragma unroll
    for (int e=0; e<8; e++){
      float4 av = ((const float4*)(&A[(size_t)ssrc[e0+e]*128]))[q];
      float4 v; v.x = bi.x - av.x + dlA[e].x; v.y = bi.y - av.y + dlA[e].y;
      v.z = bi.z - av.z + dlB[e].x; v.w = bi.w - av.w + dlB[e].y;
      *(float4*)(&ein[e0+e][4*q]) = v;
    }
  }
  // ah = relu(q @ Wa1 + ba1)
  GEMMW2(Wa1); KREDUCE(ba1);
  if (kh == 0){
    #pragma unroll
    for (int e=0; e<8; e++){
      float4 v; v.x=fmaxf(accA[e].x,0.f); v.y=fmaxf(accA[e].y,0.f);
      v.z=fmaxf(accB[e].x,0.f); v.w=fmaxf(accB[e].y,0.f);
      *(float4*)(&ein[e0+e][4*q]) = v;
    }
  }
  // logits = ah @ Wa2 + ba2
  GEMMW2(Wa2); KREDUCE(ba2);
  // cross-wave softmax over 32 edges; partials reuse dead ein rows:
  float* rbuf = &ein[0][0];
  v2f mA = accA[0], mB = accB[0];
  #pragma unroll
  for (int e=1; e<8; e++){
    mA.x=fmaxf(mA.x,accA[e].x); mA.y=fmaxf(mA.y,accA[e].y);
    mB.x=fmaxf(mB.x,accB[e].x); mB.y=fmaxf(mB.y,accB[e].y);
  }
  __syncthreads();                                   // all GEMM3 LDS reads done
  if (kh == 0){
    float4 mv; mv.x=mA.x; mv.y=mA.y; mv.z=mB.x; mv.w=mB.y;
    *(float4*)(&rbuf[w*128 + 4*q]) = mv;
  }
  __syncthreads();
  float4 M; M.x=-1e30f; M.y=-1e30f; M.z=-1e30f; M.w=-1e30f;
  #pragma unroll
  for (int ww=0; ww<4; ww++){
    float4 mm = *(const float4*)(&rbuf[ww*128 + 4*q]);
    M.x=fmaxf(M.x,mm.x); M.y=fmaxf(M.y,mm.y); M.z=fmaxf(M.z,mm.z); M.w=fmaxf(M.w,mm.w);
  }
  if (kh == 0){
    float4 s2; s2.x=0.f; s2.y=0.f; s2.z=0.f; s2.w=0.f;
    float4 h2; h2.x=0.f; h2.y=0.f; h2.z=0.f; h2.w=0.f;
    #pragma unroll
    for (int e=0; e<8; e++){
      int s = ssrc[e0+e]; float wt = sw[e0+e];
      float4 vv = ((const float4*)(&V[(size_t)s*128]))[q];
      float p;
      p = __expf(accA[e].x - M.x); s2.x += p; h2.x += p*(vv.x + dlA[e].x)*wt;
      p = __expf(accA[e].y - M.y); s2.y += p; h2.y += p*(vv.y + dlA[e].y)*wt;
      p = __expf(accB[e].x - M.z); s2.z += p; h2.z += p*(vv.z + dlB[e].x)*wt;
      p = __expf(accB[e].y - M.w); s2.w += p; h2.w += p*(vv.w + dlB[e].y)*wt;
    }
    *(float4*)(&rbuf[512  + w*128 + 4*q]) = s2;
    *(float4*)(&rbuf[1024 + w*128 + 4*q]) = h2;
  }
  __syncthreads();
  if (w == 0 && kh == 0){
    float4 S; S.x=0.f; S.y=0.f; S.z=0.f; S.w=0.f;
    float4 H; H.x=0.f; H.y=0.f; H.z=0.f; H.w=0.f;
    #pragma unroll
    for (int ww=0; ww<4; ww++){
      float4 sv = *(const float4*)(&rbuf[512  + ww*128 + 4*q]);
      float4 hv = *(const float4*)(&rbuf[1024 + ww*128 + 4*q]);
      S.x+=sv.x; S.y+=sv.y; S.z+=sv.z; S.w+=sv.w;
      H.x+=hv.x; H.y+=hv.y; H.z+=hv.z; H.w+=hv.w;
    }
    float4 o; o.x=H.x/(S.x+1e-16f); o.y=H.y/(S.y+1e-16f);
    o.z=H.z/(S.z+1e-16f); o.w=H.w/(S.w+1e-16f);
    *(float4*)(&h[(size_t)i*128 + 4*q]) = o;
  }
}

// hd = relu(h @ Wd + bd)
__global__ __launch_bounds__(128) void k_down(const float* __restrict__ h,
    const float* __restrict__ Wd, const float* __restrict__ bd, float* __restrict__ hd){
  int g0 = blockIdx.x*8; int c = threadIdx.x;
  __shared__ float hs[8][128];
  for (int idx=c; idx<1024; idx+=128) hs[idx>>7][idx&127] = h[(g0 + (idx>>7))*128 + (idx&127)];
  __syncthreads();
  float acc[8]; float b = bd[c];
  #pragma unroll
  for (int g=0; g<8; g++) acc[g] = b;
  for (int k=0; k<128; k+=4){
    float w0=Wd[(k+0)*128+c], w1=Wd[(k+1)*128+c], w2=Wd[(k+2)*128+c], w3=Wd[(k+3)*128+c];
    #pragma unroll
    for (int g=0; g<8; g++){
      const float4 ev = *(const float4*)(&hs[g][k]);
      acc[g] += ev.x*w0 + ev.y*w1 + ev.z*w2 + ev.w*w3;
    }
  }
  #pragma unroll
  for (int g=0; g<8; g++) hd[(g0+g)*128+c] = fmaxf(acc[g], 0.0f);
}

// y = max(hd[i], max over 32 neighbors hd[src])
__global__ __launch_bounds__(128) void k_pool(const float* __restrict__ hd,
    const int* __restrict__ soft_src, const int* __restrict__ knn_src, float* __restrict__ y){
  int i = blockIdx.x; int c = threadIdx.x;
  __shared__ int ss[32];
  if (c < 16) ss[c] = soft_src[i*16+c];
  else if (c < 32) ss[c] = knn_src[i*16+(c-16)];
  __syncthreads();
  float p = hd[i*128+c];
  for (int e=0; e<32; e++) p = fmaxf(p, hd[ss[e]*128+c]);
  y[i*128+c] = p;
}

// ranks = sorted-unique inverse (count of nonzero bins with smaller vid)
__global__ __launch_bounds__(256) void k_scan(const int* __restrict__ hist,
    int* __restrict__ rank, int* __restrict__ ucnt, int* __restrict__ Uo){
  __shared__ int part[256];
  int t = threadIdx.x;
  int base = t*32;
  int cnt = 0;
  for (int b=0; b<32; b++) cnt += (hist[base+b] > 0);
  part[t] = cnt;
  __syncthreads();
  if (t == 0){
    int run = 0;
    for (int q=0; q<256; q++){ int v = part[q]; part[q] = run; run += v; }
    Uo[0] = run;
  }
  __syncthreads();
  int run = part[t];
  for (int b=0; b<32; b++){
    int bin = base + b;
    rank[bin] = run;
    int hv = hist[bin];
    if (hv > 0){ ucnt[run] = hv; run++; }
  }
}

__global__ __launch_bounds__(128) void k_agg(const float* __restrict__ y, const float* __restrict__ pos,
    const int* __restrict__ vid, const int* __restrict__ rank,
    float* __restrict__ accx, float* __restrict__ accp){
  int n = blockIdx.x; int c = threadIdx.x;
  int r = rank[vid[n]];
  atomicAdd(&accx[r*128+c], y[n*128+c]);
  if (c < 3) atomicAdd(&accp[r*3+c], pos[n*3+c]);
}

__global__ __launch_bounds__(128) void k_final(const float* __restrict__ accx, const float* __restrict__ accp,
    const int* __restrict__ ucnt, const int* __restrict__ Uo, float* __restrict__ out){
  int r = blockIdx.x; int c = threadIdx.x;
  int u = Uo[0];
  float cnt = (r < u) ? (float)ucnt[r] : 0.0f;
  float den = fmaxf(cnt, 1.0f);
  out[r*128+c] = (r < u) ? accx[r*128+c]/den : 0.0f;
  if (c < 3) out[(size_t)NN*128 + r*3 + c] = (r < u) ? accp[r*3+c]/den : 0.0f;
  if (c == 0) out[(size_t)NN*128 + (size_t)NN*3 + r] = cnt;
}

// ---------------- launcher ----------------
extern "C" void kernel_launch(void* const* d_in, const int* in_sizes, int n_in,
                              void* d_out, int out_size, void* d_ws, size_t ws_size,
                              hipStream_t stream){
  (void)in_sizes; (void)n_in; (void)out_size;
  const float* x    = (const float*)d_in[0];
  const float* pos  = (const float*)d_in[1];
  const float* Wg1  = (const float*)d_in[2];
  const float* bg1  = (const float*)d_in[3];
  const float* Wg2  = (const float*)d_in[4];
  const float* bg2  = (const float*)d_in[5];
  const float* Wlin = (const float*)d_in[6];
  const float* Wsrc = (const float*)d_in[7];
  const float* Wdst = (const float*)d_in[8];
  const float* Wp1  = (const float*)d_in[9];
  const float* bp1  = (const float*)d_in[10];
  const float* Wp2  = (const float*)d_in[11];
  const float* bp2  = (const float*)d_in[12];
  const float* Wa1  = (const float*)d_in[13];
  const float* ba1  = (const float*)d_in[14];
  const float* Wa2  = (const float*)d_in[15];
  const float* ba2  = (const float*)d_in[16];
  const float* Wd   = (const float*)d_in[17];
  const float* bd   = (const float*)d_in[18];

  char* ws = (char*)d_ws;
  float* embF   = (float*)(ws + OFF_EMBF);
  float* psum   = (float*)(ws + OFF_PSUM);
  int*   ssrc   = (int*)  (ws + OFF_SSRC);
  float* topv   = (float*)(ws + OFF_TOPV);
  int*   ksrc   = (int*)  (ws + OFF_KSRC);
  int*   hist   = (int*)  (ws + OFF_HIST);
  int*   rank   = (int*)  (ws + OFF_RANK);
  int*   ucnt   = (int*)  (ws + OFF_UCNT);
  int*   vid    = (int*)  (ws + OFF_VID);
  int*   mi     = (int*)  (ws + OFF_META);
  int*   mx     = (int*)  (ws + OFF_META + 16);
  int*   Uo     = (int*)  (ws + OFF_META + 32);
  int*   qKi    = (int*)  (ws + OFF_QKI);
  int*   cand   = (int*)  (ws + OFF_CAND);
  float4* pos4  = (float4*)(ws + OFF_POS4);
  float* A      = (float*)(ws + OFF_A);
  float* B      = (float*)(ws + OFF_B);
  float* V      = (float*)(ws + OFF_V);
  float* h      = (float*)(ws + OFF_H);
  float* hd     = (float*)(ws + OFF_HD);
  float* y      = (float*)(ws + OFF_Y);
  float* accx   = (float*)(ws + OFF_ACCX);
  float* accp   = (float*)(ws + OFF_ACCP);
  unsigned short* zq = (unsigned short*)(ws + OFF_ZQ);

  const bool use_q = (ws_size >= OFF_ZQ + ZQ_BYTES);   // constant per run -> deterministic

  // rk = jax.random.split(jax.random.key(42), 2)  -- host threefry (foldlike)
  u32 rk0a, rk0b, rk1a, rk1b;
  tf2x32(0u, 42u, 0u, 0u, rk0a, rk0b);
  tf2x32(0u, 42u, 0u, 1u, rk1a, rk1b);

  hipMemsetAsync(hist, 0, 8192*4, stream);
  k_init0<<<1, 64, 0, stream>>>(mi, mx);
  k_min<<<32, 256, 0, stream>>>(pos, mi);
  k_ext<<<32, 256, 0, stream>>>(pos, mi, mx);
  k_vid<<<32, 256, 0, stream>>>(pos, mi, mx, vid, hist, pos4);
  k_emb<<<8192, 64, 0, stream>>>(x, Wg1, bg1, Wg2, bg2, rk0a, rk0b, embF);
  k_knn<<<8192, 64, 0, stream>>>(pos4, ksrc);
  if (use_q){
    k_colstats<true><<<dim3(32,32), 256, 0, stream>>>(embF, rk1a, rk1b, psum, zq);
    k_colfin<<<32, 256, 0, stream>>>(psum, embF, qKi);
    k_qtopk<<<8192, 64, 0, stream>>>(zq, qKi, cand);
    k_rescore<<<8192, 64, 0, stream>>>(embF, cand, rk1a, rk1b, ssrc, topv);
  } else {
    k_colstats<false><<<dim3(32,32), 256, 0, stream>>>(embF, rk1a, rk1b, psum, nullptr);
    k_colfin<<<32, 256, 0, stream>>>(psum, embF, qKi);
    k_rowtopk<<<8192, 64, 0, stream>>>(embF, rk1a, rk1b, ssrc, topv);
  }
  // Overlap region is free of z-cache readers from here on.
  k_xw<<<1024, 128, 0, stream>>>(x, Wsrc, Wdst, Wlin, A, B, V);
  k_edge<<<8192, 256, 0, stream>>>(pos, ssrc, topv, ksrc, A, B, V,
                                   Wp1, bp1, Wp2, bp2, Wa1, ba1, Wa2, ba2, h);
  k_down<<<1024, 128, 0, stream>>>(h, Wd, bd, hd);
  k_pool<<<8192, 128, 0, stream>>>(hd, ssrc, ksrc, y);
  hipMemsetAsync(accx, 0, (size_t)8192*128*4, stream);
  hipMemsetAsync(accp, 0, (size_t)8192*3*4, stream);
  k_scan<<<1, 256, 0, stream>>>(hist, rank, ucnt, Uo);
  k_agg<<<8192, 128, 0, stream>>>(y, pos, vid, rank, accx, accp);
  k_final<<<8192, 128, 0, stream>>>(accx, accp, ucnt, Uo, (float*)d_out);
}

// Round 13
// 797.522 us; speedup vs baseline: 1.1648x; 1.1599x over previous
//
#include <hip/hip_runtime.h>
#include <stdint.h>

// ---------------------------------------------------------------------------
// Enc_block: KNN graph + gumbel-softmax soft edges + PointTransformerConv +
// down + neighbor max-pool + GridSampling.  N=8192, Cin=64, Cout=128, K=16.
// k_edge now uses MFMA (bf16 hi/lo split => ~fp32 accuracy, ~2^-16 rel err).
// ---------------------------------------------------------------------------

typedef unsigned int u32;
typedef float v2f __attribute__((ext_vector_type(2)));
typedef float f32x4 __attribute__((ext_vector_type(4)));
typedef short bf16x8 __attribute__((ext_vector_type(8)));

#define NN 8192
#define EPS20 1e-20f
#define QSCALE 489.0671f   // 65535/134; z in [-99.8, 33.3] -> q = (z+100)*QSCALE

// f32 -> bf16 round-to-nearest-even (returns low 16 bits)
__host__ __device__ static inline u32 bf16rne(float x){
  u32 b = __float_as_uint(x);
  return (b + 0x7fffu + ((b>>16)&1u)) >> 16;
}

// ---------------- threefry2x32 (JAX key schedule) ----------------
__host__ __device__ static inline u32 rotl32(u32 v, int r){ return (v<<r)|(v>>(32-r)); }

__host__ __device__ static inline void tf2x32(u32 k0, u32 k1, u32 c0, u32 c1, u32& o0, u32& o1){
  u32 ks2 = k0 ^ k1 ^ 0x1BD11BDAu;
  u32 x0 = c0 + k0;
  u32 x1 = c1 + k1;
#define TFR(r) x0 += x1; x1 = rotl32(x1,(r)); x1 ^= x0;
  TFR(13) TFR(15) TFR(26) TFR(6)
  x0 += k1;  x1 += ks2 + 1u;
  TFR(17) TFR(29) TFR(16) TFR(24)
  x0 += ks2; x1 += k0 + 2u;
  TFR(13) TFR(15) TFR(26) TFR(6)
  x0 += k0;  x1 += k1 + 3u;
  TFR(17) TFR(29) TFR(16) TFR(24)
  x0 += k1;  x1 += ks2 + 4u;
  TFR(13) TFR(15) TFR(26) TFR(6)
  x0 += ks2; x1 += k0 + 5u;
#undef TFR
  o0 = x0; o1 = x1;
}

__device__ static inline u32 rbits(u32 k0, u32 k1, u32 idx){
  u32 o0,o1; tf2x32(k0,k1, 0u, idx, o0,o1);   // partitionable: counter (0, idx)
  return o0 ^ o1;                              // 32-bit fold
}

__device__ static inline float u01(u32 b){
  return __uint_as_float((b>>9) | 0x3f800000u) - 1.0f;   // [0,1), JAX formula
}

// z = 2*(g - d2); eps correction negligible for all selection-relevant entries
__device__ static inline float gumbel_g(u32 ub){
  float u = u01(ub);
  float w = -__logf(u + EPS20);
  return -__logf(w + EPS20);
}

// ---------------- workspace layout ----------------
static constexpr size_t OFF_EMBF = 0;                              // [8192][12] f32: e[10], se, K
static constexpr size_t OFF_SP   = OFF_EMBF + (size_t)8192*12*4;   // (unused, kept for layout)
static constexpr size_t OFF_PSUM = OFF_SP   + (size_t)8192*4;      // [32][8192]
static constexpr size_t OFF_SSRC = OFF_PSUM + (size_t)32*8192*4;   // int [8192][16]
static constexpr size_t OFF_TOPV = OFF_SSRC + (size_t)8192*16*4;
static constexpr size_t OFF_KSRC = OFF_TOPV + (size_t)8192*16*4;   // int [8192][16]
static constexpr size_t OFF_HIST = OFF_KSRC + (size_t)8192*16*4;   // int [8192]
static constexpr size_t OFF_RANK = OFF_HIST + (size_t)8192*4;
static constexpr size_t OFF_UCNT = OFF_RANK + (size_t)8192*4;
static constexpr size_t OFF_VID  = OFF_UCNT + (size_t)8192*4;
static constexpr size_t OFF_META = OFF_VID  + (size_t)8192*4;      // mi i[3] @0, mx i[3] @16B, U i @32B
static constexpr size_t OFF_QKI  = OFF_META + 64;                  // int [8192] quantized K
static constexpr size_t OFF_CAND = OFF_QKI  + (size_t)8192*4;      // int [8192][32]
static constexpr size_t OFF_POS4 = OFF_CAND + (size_t)8192*32*4;   // float4 [8192] {x,y,z,|p|^2}
static constexpr size_t OFF_WH   = (OFF_POS4 + (size_t)8192*16 + 255) & ~(size_t)255; // bf16 [3][128c][128k]
static constexpr size_t OFF_WL   = OFF_WH + (size_t)3*16384*2;
static constexpr size_t OFF_BIG  = (OFF_WL + (size_t)3*16384*2 + 255) & ~(size_t)255;
// Overlap region: u16 z-cache [8192][8192] lives here during colstats..rescore;
// A/B/V/H/HD/Y/ACCX/ACCP live here afterwards (k_xw launched after rescore).
static constexpr size_t OFF_A    = OFF_BIG;
static constexpr size_t OFF_B    = OFF_A    + (size_t)8192*128*4;
static constexpr size_t OFF_V    = OFF_B    + (size_t)8192*128*4;
static constexpr size_t OFF_H    = OFF_V    + (size_t)8192*128*4;
static constexpr size_t OFF_HD   = OFF_H    + (size_t)8192*128*4;
static constexpr size_t OFF_Y    = OFF_HD   + (size_t)8192*128*4;
static constexpr size_t OFF_ACCX = OFF_Y    + (size_t)8192*128*4;
static constexpr size_t OFF_ACCP = OFF_ACCX + (size_t)8192*128*4;
static constexpr size_t OFF_ZQ   = OFF_BIG;
static constexpr size_t ZQ_BYTES = (size_t)NN*NN*2;

// ---------------- kernels ----------------

__global__ void k_init0(int* __restrict__ mi, int* __restrict__ mx){
  int t = threadIdx.x;
  if (t < 3){ mi[t] = 0x7f7fffff; mx[t] = 0; }
}

// weight prep: Wp2/Wa1/Wa2 -> transposed bf16 hi/lo: W*[k][c] -> wt[m][c][k]
__global__ __launch_bounds__(128) void k_wprep(const float* __restrict__ Wp2,
    const float* __restrict__ Wa1, const float* __restrict__ Wa2,
    unsigned short* __restrict__ WH, unsigned short* __restrict__ WL){
  int m = blockIdx.x >> 7;
  int c = blockIdx.x & 127;
  int k = threadIdx.x;
  const float* Wm = (m==0) ? Wp2 : (m==1) ? Wa1 : Wa2;
  float x = Wm[k*128 + c];
  u32 hi = bf16rne(x);
  float lo = x - __uint_as_float(hi<<16);
  u32 lo16 = bf16rne(lo);
  size_t base = (size_t)m*16384 + (size_t)c*128 + k;
  WH[base] = (unsigned short)hi;
  WL[base] = (unsigned short)lo16;
}

// per-dim min of pos (positive floats: int-bit compare is order-preserving)
__global__ __launch_bounds__(256) void k_min(const float* __restrict__ pos, int* __restrict__ mi){
  __shared__ int red[768];
  int t = threadIdx.x;
  int n = blockIdx.x*256 + t;
  red[t]     = __float_as_int(pos[n*3+0]);
  red[256+t] = __float_as_int(pos[n*3+1]);
  red[512+t] = __float_as_int(pos[n*3+2]);
  __syncthreads();
  for (int s=128; s>0; s>>=1){
    if (t < s){
      red[t]     = min(red[t],     red[t+s]);
      red[256+t] = min(red[256+t], red[256+t+s]);
      red[512+t] = min(red[512+t], red[512+t+s]);
    }
    __syncthreads();
  }
  if (t == 0){ atomicMin(&mi[0], red[0]); atomicMin(&mi[1], red[256]); atomicMin(&mi[2], red[512]); }
}

// per-dim max voxel index
__global__ __launch_bounds__(256) void k_ext(const float* __restrict__ pos, const int* __restrict__ mi,
                                             int* __restrict__ mx){
  __shared__ int red[768];
  int t = threadIdx.x;
  int n = blockIdx.x*256 + t;
  float p0 = __int_as_float(mi[0]), p1 = __int_as_float(mi[1]), p2 = __int_as_float(mi[2]);
  red[t]     = (int)floorf((pos[n*3+0]-p0)*2.0f);   // /0.5 == *2 exactly
  red[256+t] = (int)floorf((pos[n*3+1]-p1)*2.0f);
  red[512+t] = (int)floorf((pos[n*3+2]-p2)*2.0f);
  __syncthreads();
  for (int s=128; s>0; s>>=1){
    if (t < s){
      red[t]     = max(red[t],     red[t+s]);
      red[256+t] = max(red[256+t], red[256+t+s]);
      red[512+t] = max(red[512+t], red[512+t+s]);
    }
    __syncthreads();
  }
  if (t == 0){ atomicMax(&mx[0], red[0]); atomicMax(&mx[1], red[256]); atomicMax(&mx[2], red[512]); }
}

// voxel id + histogram + SoA pos4 = {x,y,z,|p|^2}
__global__ __launch_bounds__(256) void k_vid(const float* __restrict__ pos,
                                             const int* __restrict__ mi, const int* __restrict__ mx,
                                             int* __restrict__ vid, int* __restrict__ hist,
                                             float4* __restrict__ pos4){
  int n = blockIdx.x*256 + threadIdx.x;
  float p0=pos[n*3], p1=pos[n*3+1], p2=pos[n*3+2];
  float4 p4; p4.x=p0; p4.y=p1; p4.z=p2; p4.w = p0*p0 + p1*p1 + p2*p2;
  pos4[n] = p4;
  float q0 = __int_as_float(mi[0]), q1 = __int_as_float(mi[1]), q2 = __int_as_float(mi[2]);
  int v0 = (int)floorf((p0-q0)*2.0f);
  int v1 = (int)floorf((p1-q1)*2.0f);
  int v2 = (int)floorf((p2-q2)*2.0f);
  int nv1 = mx[1]+1, nv2 = mx[2]+1;
  int id = (v0*nv1 + v1)*nv2 + v2;
  vid[n] = id;
  atomicAdd(&hist[id], 1);
}

// embF[i] = { relu(x@Wg1+bg1)@Wg2+bg2 + u*0.001  (10), |emb|^2, 0 }
__global__ __launch_bounds__(64) void k_emb(const float* __restrict__ x,
    const float* __restrict__ Wg1, const float* __restrict__ bg1,
    const float* __restrict__ Wg2, const float* __restrict__ bg2,
    u32 ka, u32 kb, float* __restrict__ embF){
  int i = blockIdx.x; int t = threadIdx.x;
  __shared__ float xs[64], hs[64], esq[10];
  xs[t] = x[i*64+t];
  __syncthreads();
  float a = bg1[t];
  for (int k=0; k<64; k++) a += xs[k]*Wg1[k*64+t];
  hs[t] = fmaxf(a, 0.0f);
  __syncthreads();
  if (t < 10){
    float e = bg2[t];
    for (int k=0; k<64; k++) e += hs[k]*Wg2[k*10+t];
    e += u01(rbits(ka, kb, (u32)(i*10+t))) * 0.001f;
    embF[i*12+t] = e;
    esq[t] = e*e;
  }
  __syncthreads();
  if (t == 0){
    float ssum = 0.0f;
    #pragma unroll
    for (int d=0; d<10; d++) ssum += esq[d];
    embF[i*12+10] = ssum;
    embF[i*12+11] = 0.0f;
  }
}

// KNN: top-16 smallest d2 per row (diag excluded), ties -> lower index.
__global__ __launch_bounds__(64) void k_knn(const float4* __restrict__ pos4,
                                            int* __restrict__ knn_src){
  int i = blockIdx.x; int l = threadIdx.x;
  float4 pi = pos4[i];
  float lv[8]; int lj[8];
  #pragma unroll
  for (int s=0; s<8; s++){ lv[s]=1e30f; lj[s]=0x7fffffff; }
  for (int tt=0; tt<128; tt++){
    int j = l + 64*tt;
    float4 pj = pos4[j];
    float d = pi.w + pj.w - 2.0f*(pi.x*pj.x + pi.y*pj.y + pi.z*pj.z);
    d = fmaxf(d, 0.0f);
    if (j != i && d < lv[7]){
      lv[7]=d; lj[7]=j;
      #pragma unroll
      for (int s=7; s>0; s--){
        if (lv[s] < lv[s-1]){ float tv=lv[s]; lv[s]=lv[s-1]; lv[s-1]=tv; int tj=lj[s]; lj[s]=lj[s-1]; lj[s-1]=tj; }
      }
    }
  }
  for (int r=0; r<16; r++){
    float bv = lv[0]; int bj = lj[0];
    #pragma unroll
    for (int off=32; off>=1; off>>=1){
      float ov = __shfl_xor(bv, off);
      int   oj = __shfl_xor(bj, off);
      if (ov < bv || (ov == bv && oj < bj)){ bv = ov; bj = oj; }
    }
    if (l == 0) knn_src[i*16+r] = bj;
    if (lj[0] == bj){
      #pragma unroll
      for (int s=0; s<7; s++){ lv[s]=lv[s+1]; lj[s]=lj[s+1]; }
      lv[7]=1e30f; lj[7]=0x7fffffff;
    }
  }
}

// column partial sums of exp(z-40); stores quantized z (u16) into the cache.
template<bool STZ>
__global__ __launch_bounds__(256) void k_colstats(const float* __restrict__ embF,
                                                  u32 ka, u32 kb, float* __restrict__ psum,
                                                  unsigned short* __restrict__ zq){
  __shared__ float4 sE4[768];                 // 256 rows x 12 floats
  int t = threadIdx.x;
  int j = blockIdx.x*256 + t;
  int i0 = blockIdx.y*256;
  const float4* gF = (const float4*)embF;
  #pragma unroll
  for (int q=0; q<3; q++) sE4[t + 256*q] = gF[(size_t)i0*3 + t + 256*q];
  __syncthreads();
  float4 b0 = gF[j*3+0], b1 = gF[j*3+1], b2 = gF[j*3+2];
  float sej = b2.z;
  float s = 0.0f;
  unsigned short* zp = STZ ? (zq + ((size_t)i0<<13) + j) : nullptr;
  for (int r=0; r<256; r++){
    float4 a0 = sE4[r*3+0], a1 = sE4[r*3+1], a2 = sE4[r*3+2];
    float dot = a0.x*b0.x + a0.y*b0.y + a0.z*b0.z + a0.w*b0.w
              + a1.x*b1.x + a1.y*b1.y + a1.z*b1.z + a1.w*b1.w
              + a2.x*b2.x + a2.y*b2.y;
    float d2 = fmaxf(a2.z + sej - 2.0f*dot, 0.0f);
    float g = gumbel_g(rbits(ka, kb, (u32)(i0+r)*8192u + (u32)j));
    float z = 2.0f*(g - d2);
    s += __expf(z - 40.0f);
    if (STZ){
      float qf = (z + 100.0f)*QSCALE + 0.5f;
      qf = fminf(fmaxf(qf, 0.0f), 65535.0f);
      *zp = (unsigned short)qf;
      zp += NN;
    }
  }
  psum[blockIdx.y*NN + j] = s;
}

// K_j = 40 + log(sum_chunks psum); write f32 K into embF[j][11] and quantized K
__global__ __launch_bounds__(256) void k_colfin(const float* __restrict__ psum, float* __restrict__ embF,
                                                int* __restrict__ qKi){
  int j = blockIdx.x*256 + threadIdx.x;
  float S = 0.0f;
  for (int c=0; c<32; c++) S += psum[c*NN + j];
  float K = 40.0f + __logf(S);
  embF[j*12+11] = K;
  qKi[j] = (int)((K + 100.0f)*QSCALE + 0.5f);   // same transform as z
}

// FALLBACK: per-row top-16 of y = z - K_j by full recompute
__global__ __launch_bounds__(64) void k_rowtopk(const float* __restrict__ embF,
    u32 ka, u32 kb, int* __restrict__ soft_src, float* __restrict__ top_v){
  int i = blockIdx.x; int l = threadIdx.x;
  const float4* gF = (const float4*)embF;
  float4 b0 = gF[i*3+0], b1 = gF[i*3+1], b2 = gF[i*3+2];
  float sei = b2.z;
  float lv[16]; int lj[16];
  #pragma unroll
  for (int s=0; s<16; s++){ lv[s]=-1e30f; lj[s]=0x7fffffff; }
  for (int tt=0; tt<128; tt++){
    int j = l + 64*tt;
    float4 a0 = gF[j*3+0], a1 = gF[j*3+1], a2 = gF[j*3+2];
    float dot = a0.x*b0.x + a0.y*b0.y + a0.z*b0.z + a0.w*b0.w
              + a1.x*b1.x + a1.y*b1.y + a1.z*b1.z + a1.w*b1.w
              + a2.x*b2.x + a2.y*b2.y;
    float d2 = fmaxf(a2.z + sei - 2.0f*dot, 0.0f);
    float g = gumbel_g(rbits(ka, kb, (u32)i*8192u + (u32)j));
    float z = 2.0f*(g - d2);
    float y = z - a2.w;
    if (y > lv[15]){
      lv[15]=y; lj[15]=j;
      #pragma unroll
      for (int s=15; s>0; s--){
        if (lv[s] > lv[s-1]){ float tv=lv[s]; lv[s]=lv[s-1]; lv[s-1]=tv; int tj=lj[s]; lj[s]=lj[s-1]; lj[s-1]=tj; }
      }
    }
  }
  for (int r=0; r<16; r++){
    float bv = lv[0]; int bj = lj[0];
    #pragma unroll
    for (int off=32; off>=1; off>>=1){
      float ov = __shfl_xor(bv, off);
      int   oj = __shfl_xor(bj, off);
      if (ov > bv || (ov == bv && oj < bj)){ bv = ov; bj = oj; }
    }
    if (l == 0){ soft_src[i*16+r] = bj; top_v[i*16+r] = __expf(bv); }
    if (lj[0] == bj){
      #pragma unroll
      for (int s=0; s<15; s++){ lv[s]=lv[s+1]; lj[s]=lj[s+1]; }
      lv[15]=-1e30f; lj[15]=0x7fffffff;
    }
  }
}

// cached path A: per-row top-32 candidates by integer qy = q_z - q_K
__global__ __launch_bounds__(64) void k_qtopk(const unsigned short* __restrict__ zq,
    const int* __restrict__ qKi, int* __restrict__ cand){
  int i = blockIdx.x; int l = threadIdx.x;
  const uint4* zrow = (const uint4*)(zq + ((size_t)i<<13));   // 8 u16 per uint4
  int lv[8]; int lj[8];
  #pragma unroll
  for (int s=0; s<8; s++){ lv[s]=-0x40000000; lj[s]=0x7fffffff; }
  for (int tt=0; tt<16; tt++){
    int blk = l + 64*tt;
    uint4 zv = zrow[blk];
    int jb = blk*8;
    const int4* qk4 = (const int4*)(qKi + jb);
    int4 ka4 = qk4[0], kb4 = qk4[1];
    u32 wv[4] = {zv.x, zv.y, zv.z, zv.w};
    int qk[8] = {ka4.x,ka4.y,ka4.z,ka4.w, kb4.x,kb4.y,kb4.z,kb4.w};
    #pragma unroll
    for (int c=0; c<8; c++){
      int qz = (int)((wv[c>>1] >> ((c&1)*16)) & 0xffffu);
      int qy = qz - qk[c];
      if (qy > lv[7]){
        lv[7]=qy; lj[7]=jb+c;
        #pragma unroll
        for (int s=7; s>0; s--){
          if (lv[s] > lv[s-1]){ int tv=lv[s]; lv[s]=lv[s-1]; lv[s-1]=tv; int tj=lj[s]; lj[s]=lj[s-1]; lj[s-1]=tj; }
        }
      }
    }
  }
  for (int r=0; r<32; r++){
    int bv = lv[0]; int bj = lj[0];
    #pragma unroll
    for (int off=32; off>=1; off>>=1){
      int ov = __shfl_xor(bv, off);
      int oj = __shfl_xor(bj, off);
      if (ov > bv || (ov == bv && oj < bj)){ bv = ov; bj = oj; }
    }
    if (l == 0) cand[i*32+r] = bj;
    if (lj[0] == bj){
      #pragma unroll
      for (int s=0; s<7; s++){ lv[s]=lv[s+1]; lj[s]=lj[s+1]; }
      lv[7]=-0x40000000; lj[7]=0x7fffffff;
    }
  }
}

// cached path B: exact rescore of the 32 candidates -> exact top-16
__global__ __launch_bounds__(64) void k_rescore(const float* __restrict__ embF,
    const int* __restrict__ cand, u32 ka, u32 kb,
    int* __restrict__ soft_src, float* __restrict__ top_v){
  int i = blockIdx.x; int l = threadIdx.x;
  const float4* gF = (const float4*)embF;
  float4 b0 = gF[i*3+0], b1 = gF[i*3+1], b2 = gF[i*3+2];
  float sei = b2.z;
  float y = -1e30f; int jc = 0x7fffffff;
  if (l < 32){
    jc = cand[i*32+l];
    float4 a0 = gF[jc*3+0], a1 = gF[jc*3+1], a2 = gF[jc*3+2];
    float dot = a0.x*b0.x + a0.y*b0.y + a0.z*b0.z + a0.w*b0.w
              + a1.x*b1.x + a1.y*b1.y + a1.z*b1.z + a1.w*b1.w
              + a2.x*b2.x + a2.y*b2.y;
    float d2 = fmaxf(a2.z + sei - 2.0f*dot, 0.0f);
    float g = gumbel_g(rbits(ka, kb, (u32)i*8192u + (u32)jc));
    float z = 2.0f*(g - d2);
    y = z - a2.w;
  }
  for (int r=0; r<16; r++){
    float bv = y; int bj = jc;
    #pragma unroll
    for (int off=32; off>=1; off>>=1){
      float ov = __shfl_xor(bv, off);
      int   oj = __shfl_xor(bj, off);
      if (ov > bv || (ov == bv && oj < bj)){ bv = ov; bj = oj; }
    }
    if (l == 0){ soft_src[i*16+r] = bj; top_v[i*16+r] = __expf(bv); }
    if (jc == bj){ y = -1e30f; jc = 0x7fffffff; }
  }
}

// A = x@Wsrc, B = x@Wdst, V = x@Wlin  (8 rows per block)
__global__ __launch_bounds__(128) void k_xw(const float* __restrict__ x,
    const float* __restrict__ Wsrc, const float* __restrict__ Wdst, const float* __restrict__ Wlin,
    float* __restrict__ A, float* __restrict__ B, float* __restrict__ V){
  int g0 = blockIdx.x*8; int c = threadIdx.x;
  __shared__ float xs[8][64];
  for (int idx=c; idx<512; idx+=128) xs[idx>>6][idx&63] = x[(g0 + (idx>>6))*64 + (idx&63)];
  __syncthreads();
  float aA[8], aB[8], aV[8];
  #pragma unroll
  for (int g=0; g<8; g++){ aA[g]=0.0f; aB[g]=0.0f; aV[g]=0.0f; }
  for (int k=0; k<64; k++){
    float ws=Wsrc[k*128+c], wd=Wdst[k*128+c], wl=Wlin[k*128+c];
    #pragma unroll
    for (int g=0; g<8; g++){
      float xv = xs[g][k];
      aA[g] += xv*ws; aB[g] += xv*wd; aV[g] += xv*wl;
    }
  }
  #pragma unroll
  for (int g=0; g<8; g++){
    A[(g0+g)*128+c]=aA[g]; B[(g0+g)*128+c]=aB[g]; V[(g0+g)*128+c]=aV[g];
  }
}

// 12 MFMA per k-step: (hi*hi + hi*lo + lo*hi) x 4 C-tiles.  A from LDS, B (weights) from L2.
#define MFMA3(WHP, WLP)                                                     \
  {                                                                         \
    _Pragma("unroll")                                                       \
    for (int s=0; s<4; s++){                                                \
      int kk = 32*s + 8*g;                                                  \
      bf16x8 a0h = *(const bf16x8*)(&ah[r0][kk]);                           \
      bf16x8 a1h = *(const bf16x8*)(&ah[16+r0][kk]);                        \
      bf16x8 a0l = *(const bf16x8*)(&al[r0][kk]);                           \
      bf16x8 a1l = *(const bf16x8*)(&al[16+r0][kk]);                        \
      const unsigned short* whp = (WHP) + (size_t)cn0*128 + kk;             \
      const unsigned short* wlp = (WLP) + (size_t)cn0*128 + kk;             \
      bf16x8 b0h = *(const bf16x8*)(whp);                                   \
      bf16x8 b1h = *(const bf16x8*)(whp + 2048);                            \
      bf16x8 b0l = *(const bf16x8*)(wlp);                                   \
      bf16x8 b1l = *(const bf16x8*)(wlp + 2048);                            \
      c00 = __builtin_amdgcn_mfma_f32_16x16x32_bf16(a0h,b0h,c00,0,0,0);     \
      c01 = __builtin_amdgcn_mfma_f32_16x16x32_bf16(a0h,b1h,c01,0,0,0);     \
      c10 = __builtin_amdgcn_mfma_f32_16x16x32_bf16(a1h,b0h,c10,0,0,0);     \
      c11 = __builtin_amdgcn_mfma_f32_16x16x32_bf16(a1h,b1h,c11,0,0,0);     \
      c00 = __builtin_amdgcn_mfma_f32_16x16x32_bf16(a0h,b0l,c00,0,0,0);     \
      c01 = __builtin_amdgcn_mfma_f32_16x16x32_bf16(a0h,b1l,c01,0,0,0);     \
      c10 = __builtin_amdgcn_mfma_f32_16x16x32_bf16(a1h,b0l,c10,0,0,0);     \
      c11 = __builtin_amdgcn_mfma_f32_16x16x32_bf16(a1h,b1l,c11,0,0,0);     \
      c00 = __builtin_amdgcn_mfma_f32_16x16x32_bf16(a0l,b0h,c00,0,0,0);     \
      c01 = __builtin_amdgcn_mfma_f32_16x16x32_bf16(a0l,b1h,c01,0,0,0);     \
      c10 = __builtin_amdgcn_mfma_f32_16x16x32_bf16(a1l,b0h,c10,0,0,0);     \
      c11 = __builtin_amdgcn_mfma_f32_16x16x32_bf16(a1l,b1h,c11,0,0,0);     \
    }                                                                       \
  }

// PointTransformerConv via MFMA.  256 threads = 4 waves; wave w owns output
// cols [32w, 32w+32).  A-fragments: row = l&15 (+16 per m-tile), k = 8*(l>>4)+i.
// B from transposed bf16 weights wt[col][k].  C/D: col = l&15 (+16n), row =
// (l>>4)*4 + reg (+16m)  [guide-verified mapping].
__global__ __launch_bounds__(256) void k_edge(const float* __restrict__ pos,
    const int* __restrict__ soft_src, const float* __restrict__ top_v, const int* __restrict__ knn_src,
    const float* __restrict__ A, const float* __restrict__ B, const float* __restrict__ V,
    const float* __restrict__ Wp1, const float* __restrict__ bp1,
    const unsigned short* __restrict__ WH, const unsigned short* __restrict__ WL,
    const float* __restrict__ bp2, const float* __restrict__ ba1, const float* __restrict__ ba2,
    float* __restrict__ h){
  int i = blockIdx.x; int t = threadIdx.x;
  int l = t & 63; int w = t >> 6;
  int g = l >> 4; int r0 = l & 15;
  int cn0 = 32*w + r0;
  __shared__ __align__(16) unsigned short ah[32][136];
  __shared__ __align__(16) unsigned short al[32][136];
  __shared__ int   ssrc[32];
  __shared__ float sw[32];
  __shared__ float sdp[32][3];
  if (t < 32){
    int s; float wt;
    if (t < 16){ s = soft_src[i*16+t]; wt = top_v[i*16+t]; }
    else       { s = knn_src[i*16+(t-16)]; wt = 1.0f; }
    ssrc[t]=s; sw[t]=wt;
    sdp[t][0]=pos[i*3]-pos[s*3]; sdp[t][1]=pos[i*3+1]-pos[s*3+1]; sdp[t][2]=pos[i*3+2]-pos[s*3+2];
  }
  __syncthreads();
  // stage1: ph = relu(dpos @ Wp1 + bp1) -> bf16 hi/lo.  thread: wave rows x cols {2l,2l+1}
  {
    const float2* W1v = (const float2*)Wp1;
    float2 q0 = W1v[l], q1 = W1v[64+l], q2 = W1v[128+l];
    float2 bb = ((const float2*)bp1)[l];
    #pragma unroll
    for (int e=0; e<8; e++){
      int row = 8*w + e;
      float d0=sdp[row][0], d1=sdp[row][1], d2=sdp[row][2];
      float vx = fmaxf(d0*q0.x + d1*q1.x + d2*q2.x + bb.x, 0.0f);
      float vy = fmaxf(d0*q0.y + d1*q1.y + d2*q2.y + bb.y, 0.0f);
      u32 hx = bf16rne(vx), hy = bf16rne(vy);
      float lx = vx - __uint_as_float(hx<<16);
      float ly = vy - __uint_as_float(hy<<16);
      u32 lx16 = bf16rne(lx), ly16 = bf16rne(ly);
      *(u32*)(&ah[row][2*l]) = hx | (hy<<16);
      *(u32*)(&al[row][2*l]) = lx16 | (ly16<<16);
    }
  }
  __syncthreads();
  f32x4 c00={0,0,0,0}, c01={0,0,0,0}, c10={0,0,0,0}, c11={0,0,0,0};
  // GEMM1: delta = ph @ Wp2 + bp2
  MFMA3(WH, WL);
  f32x4 dl00, dl01, dl10, dl11;
  {
    float bi0 = bp2[cn0], bi1 = bp2[cn0+16];
    #pragma unroll
    for (int r=0; r<4; r++){
      dl00[r]=c00[r]+bi0; dl01[r]=c01[r]+bi1;
      dl10[r]=c10[r]+bi0; dl11[r]=c11[r]+bi1;
    }
  }
  __syncthreads();                 // all GEMM1 reads of ah/al done
  // q-stage: q = B[i] - A[src] + delta -> bf16 hi/lo (scatter per C-frag element)
  int ssv[8];
  {
    float B0 = B[(size_t)i*128 + cn0];
    float B1 = B[(size_t)i*128 + cn0 + 16];
    #pragma unroll
    for (int m=0; m<2; m++){
      #pragma unroll
      for (int r=0; r<4; r++){
        int row = 16*m + 4*g + r;
        int sv = ssrc[row]; ssv[m*4+r] = sv;
        float a0 = A[(size_t)sv*128 + cn0];
        float a1 = A[(size_t)sv*128 + cn0 + 16];
        float q0 = B0 - a0 + (m ? dl10[r] : dl00[r]);
        float q1 = B1 - a1 + (m ? dl11[r] : dl01[r]);
        u32 h0 = bf16rne(q0); float lf0 = q0 - __uint_as_float(h0<<16);
        u32 h1 = bf16rne(q1); float lf1 = q1 - __uint_as_float(h1<<16);
        ah[row][cn0]    = (unsigned short)h0;  al[row][cn0]    = (unsigned short)bf16rne(lf0);
        ah[row][cn0+16] = (unsigned short)h1;  al[row][cn0+16] = (unsigned short)bf16rne(lf1);
      }
    }
  }
  __syncthreads();
  // GEMM2: ah_pre = q @ Wa1 + ba1
  c00=(f32x4){0,0,0,0}; c01=c00; c10=c00; c11=c00;
  MFMA3(WH + 16384, WL + 16384);
  __syncthreads();                 // all GEMM2 reads done
  {
    float b0v = ba1[cn0], b1v = ba1[cn0+16];
    #pragma unroll
    for (int m=0; m<2; m++){
      #pragma unroll
      for (int r=0; r<4; r++){
        int row = 16*m + 4*g + r;
        float v0 = fmaxf((m ? c10[r] : c00[r]) + b0v, 0.0f);
        float v1 = fmaxf((m ? c11[r] : c01[r]) + b1v, 0.0f);
        u32 h0 = bf16rne(v0); float lf0 = v0 - __uint_as_float(h0<<16);
        u32 h1 = bf16rne(v1); float lf1 = v1 - __uint_as_float(h1<<16);
        ah[row][cn0]    = (unsigned short)h0;  al[row][cn0]    = (unsigned short)bf16rne(lf0);
        ah[row][cn0+16] = (unsigned short)h1;  al[row][cn0+16] = (unsigned short)bf16rne(lf1);
      }
    }
  }
  __syncthreads();
  // GEMM3: logits = relu_out @ Wa2 + ba2
  c00=(f32x4){0,0,0,0}; c01=c00; c10=c00; c11=c00;
  MFMA3(WH + 32768, WL + 32768);
  // epilogue: per-col softmax over 32 edges (wave-local: rows split over lane groups)
  {
    float b0v = ba2[cn0], b1v = ba2[cn0+16];
    float lg[2][2][4];
    float M0 = -1e30f, M1 = -1e30f;
    #pragma unroll
    for (int m=0; m<2; m++){
      #pragma unroll
      for (int r=0; r<4; r++){
        lg[m][0][r] = (m ? c10[r] : c00[r]) + b0v;
        lg[m][1][r] = (m ? c11[r] : c01[r]) + b1v;
        M0 = fmaxf(M0, lg[m][0][r]);
        M1 = fmaxf(M1, lg[m][1][r]);
      }
    }
    M0 = fmaxf(M0, __shfl_xor(M0, 16)); M0 = fmaxf(M0, __shfl_xor(M0, 32));
    M1 = fmaxf(M1, __shfl_xor(M1, 16)); M1 = fmaxf(M1, __shfl_xor(M1, 32));
    float s0=0.0f, s1=0.0f, o0=0.0f, o1=0.0f;
    #pragma unroll
    for (int m=0; m<2; m++){
      #pragma unroll
      for (int r=0; r<4; r++){
        int row = 16*m + 4*g + r;
        int sv = ssv[m*4+r]; float wt = sw[row];
        float p0 = __expf(lg[m][0][r] - M0);
        float p1 = __expf(lg[m][1][r] - M1);
        s0 += p0; s1 += p1;
        float v0 = V[(size_t)sv*128 + cn0];
        float v1 = V[(size_t)sv*128 + cn0 + 16];
        o0 += p0*(v0 + (m ? dl10[r] : dl00[r]))*wt;
        o1 += p1*(v1 + (m ? dl11[r] : dl01[r]))*wt;
      }
    }
    s0 += __shfl_xor(s0, 16); s0 += __shfl_xor(s0, 32);
    s1 += __shfl_xor(s1, 16); s1 += __shfl_xor(s1, 32);
    o0 += __shfl_xor(o0, 16); o0 += __shfl_xor(o0, 32);
    o1 += __shfl_xor(o1, 16); o1 += __shfl_xor(o1, 32);
    if (g == 0){
      h[(size_t)i*128 + cn0]      = o0/(s0 + 1e-16f);
      h[(size_t)i*128 + cn0 + 16] = o1/(s1 + 1e-16f);
    }
  }
}

// hd = relu(h @ Wd + bd)
__global__ __launch_bounds__(128) void k_down(const float* __restrict__ h,
    const float* __restrict__ Wd, const float* __restrict__ bd, float* __restrict__ hd){
  int g0 = blockIdx.x*8; int c = threadIdx.x;
  __shared__ float hs[8][128];
  for (int idx=c; idx<1024; idx+=128) hs[idx>>7][idx&127] = h[(g0 + (idx>>7))*128 + (idx&127)];
  __syncthreads();
  float acc[8]; float b = bd[c];
  #pragma unroll
  for (int g=0; g<8; g++) acc[g] = b;
  for (int k=0; k<128; k+=4){
    float w0=Wd[(k+0)*128+c], w1=Wd[(k+1)*128+c], w2=Wd[(k+2)*128+c], w3=Wd[(k+3)*128+c];
    #pragma unroll
    for (int g=0; g<8; g++){
      const float4 ev = *(const float4*)(&hs[g][k]);
      acc[g] += ev.x*w0 + ev.y*w1 + ev.z*w2 + ev.w*w3;
    }
  }
  #pragma unroll
  for (int g=0; g<8; g++) hd[(g0+g)*128+c] = fmaxf(acc[g], 0.0f);
}

// y = max(hd[i], max over 32 neighbors hd[src])
__global__ __launch_bounds__(128) void k_pool(const float* __restrict__ hd,
    const int* __restrict__ soft_src, const int* __restrict__ knn_src, float* __restrict__ y){
  int i = blockIdx.x; int c = threadIdx.x;
  __shared__ int ss[32];
  if (c < 16) ss[c] = soft_src[i*16+c];
  else if (c < 32) ss[c] = knn_src[i*16+(c-16)];
  __syncthreads();
  float p = hd[i*128+c];
  for (int e=0; e<32; e++) p = fmaxf(p, hd[ss[e]*128+c]);
  y[i*128+c] = p;
}

// ranks = sorted-unique inverse (count of nonzero bins with smaller vid)
__global__ __launch_bounds__(256) void k_scan(const int* __restrict__ hist,
    int* __restrict__ rank, int* __restrict__ ucnt, int* __restrict__ Uo){
  __shared__ int part[256];
  int t = threadIdx.x;
  int base = t*32;
  int cnt = 0;
  for (int b=0; b<32; b++) cnt += (hist[base+b] > 0);
  part[t] = cnt;
  __syncthreads();
  if (t == 0){
    int run = 0;
    for (int q=0; q<256; q++){ int v = part[q]; part[q] = run; run += v; }
    Uo[0] = run;
  }
  __syncthreads();
  int run = part[t];
  for (int b=0; b<32; b++){
    int bin = base + b;
    rank[bin] = run;
    int hv = hist[bin];
    if (hv > 0){ ucnt[run] = hv; run++; }
  }
}

__global__ __launch_bounds__(128) void k_agg(const float* __restrict__ y, const float* __restrict__ pos,
    const int* __restrict__ vid, const int* __restrict__ rank,
    float* __restrict__ accx, float* __restrict__ accp){
  int n = blockIdx.x; int c = threadIdx.x;
  int r = rank[vid[n]];
  atomicAdd(&accx[r*128+c], y[n*128+c]);
  if (c < 3) atomicAdd(&accp[r*3+c], pos[n*3+c]);
}

__global__ __launch_bounds__(128) void k_final(const float* __restrict__ accx, const float* __restrict__ accp,
    const int* __restrict__ ucnt, const int* __restrict__ Uo, float* __restrict__ out){
  int r = blockIdx.x; int c = threadIdx.x;
  int u = Uo[0];
  float cnt = (r < u) ? (float)ucnt[r] : 0.0f;
  float den = fmaxf(cnt, 1.0f);
  out[r*128+c] = (r < u) ? accx[r*128+c]/den : 0.0f;
  if (c < 3) out[(size_t)NN*128 + r*3 + c] = (r < u) ? accp[r*3+c]/den : 0.0f;
  if (c == 0) out[(size_t)NN*128 + (size_t)NN*3 + r] = cnt;
}

// ---------------- launcher ----------------
extern "C" void kernel_launch(void* const* d_in, const int* in_sizes, int n_in,
                              void* d_out, int out_size, void* d_ws, size_t ws_size,
                              hipStream_t stream){
  (void)in_sizes; (void)n_in; (void)out_size;
  const float* x    = (const float*)d_in[0];
  const float* pos  = (const float*)d_in[1];
  const float* Wg1  = (const float*)d_in[2];
  const float* bg1  = (const float*)d_in[3];
  const float* Wg2  = (const float*)d_in[4];
  const float* bg2  = (const float*)d_in[5];
  const float* Wlin = (const float*)d_in[6];
  const float* Wsrc = (const float*)d_in[7];
  const float* Wdst = (const float*)d_in[8];
  const float* Wp1  = (const float*)d_in[9];
  const float* bp1  = (const float*)d_in[10];
  const float* Wp2  = (const float*)d_in[11];
  const float* bp2  = (const float*)d_in[12];
  const float* Wa1  = (const float*)d_in[13];
  const float* ba1  = (const float*)d_in[14];
  const float* Wa2  = (const float*)d_in[15];
  const float* ba2  = (const float*)d_in[16];
  const float* Wd   = (const float*)d_in[17];
  const float* bd   = (const float*)d_in[18];

  char* ws = (char*)d_ws;
  float* embF   = (float*)(ws + OFF_EMBF);
  float* psum   = (float*)(ws + OFF_PSUM);
  int*   ssrc   = (int*)  (ws + OFF_SSRC);
  float* topv   = (float*)(ws + OFF_TOPV);
  int*   ksrc   = (int*)  (ws + OFF_KSRC);
  int*   hist   = (int*)  (ws + OFF_HIST);
  int*   rank   = (int*)  (ws + OFF_RANK);
  int*   ucnt   = (int*)  (ws + OFF_UCNT);
  int*   vid    = (int*)  (ws + OFF_VID);
  int*   mi     = (int*)  (ws + OFF_META);
  int*   mx     = (int*)  (ws + OFF_META + 16);
  int*   Uo     = (int*)  (ws + OFF_META + 32);
  int*   qKi    = (int*)  (ws + OFF_QKI);
  int*   cand   = (int*)  (ws + OFF_CAND);
  float4* pos4  = (float4*)(ws + OFF_POS4);
  unsigned short* WH = (unsigned short*)(ws + OFF_WH);
  unsigned short* WL = (unsigned short*)(ws + OFF_WL);
  float* A      = (float*)(ws + OFF_A);
  float* B      = (float*)(ws + OFF_B);
  float* V      = (float*)(ws + OFF_V);
  float* h      = (float*)(ws + OFF_H);
  float* hd     = (float*)(ws + OFF_HD);
  float* y      = (float*)(ws + OFF_Y);
  float* accx   = (float*)(ws + OFF_ACCX);
  float* accp   = (float*)(ws + OFF_ACCP);
  unsigned short* zq = (unsigned short*)(ws + OFF_ZQ);

  const bool use_q = (ws_size >= OFF_ZQ + ZQ_BYTES);   // constant per run -> deterministic

  // rk = jax.random.split(jax.random.key(42), 2)  -- host threefry (foldlike)
  u32 rk0a, rk0b, rk1a, rk1b;
  tf2x32(0u, 42u, 0u, 0u, rk0a, rk0b);
  tf2x32(0u, 42u, 0u, 1u, rk1a, rk1b);

  hipMemsetAsync(hist, 0, 8192*4, stream);
  k_wprep<<<384, 128, 0, stream>>>(Wp2, Wa1, Wa2, WH, WL);
  k_init0<<<1, 64, 0, stream>>>(mi, mx);
  k_min<<<32, 256, 0, stream>>>(pos, mi);
  k_ext<<<32, 256, 0, stream>>>(pos, mi, mx);
  k_vid<<<32, 256, 0, stream>>>(pos, mi, mx, vid, hist, pos4);
  k_emb<<<8192, 64, 0, stream>>>(x, Wg1, bg1, Wg2, bg2, rk0a, rk0b, embF);
  k_knn<<<8192, 64, 0, stream>>>(pos4, ksrc);
  if (use_q){
    k_colstats<true><<<dim3(32,32), 256, 0, stream>>>(embF, rk1a, rk1b, psum, zq);
    k_colfin<<<32, 256, 0, stream>>>(psum, embF, qKi);
    k_qtopk<<<8192, 64, 0, stream>>>(zq, qKi, cand);
    k_rescore<<<8192, 64, 0, stream>>>(embF, cand, rk1a, rk1b, ssrc, topv);
  } else {
    k_colstats<false><<<dim3(32,32), 256, 0, stream>>>(embF, rk1a, rk1b, psum, nullptr);
    k_colfin<<<32, 256, 0, stream>>>(psum, embF, qKi);
    k_rowtopk<<<8192, 64, 0, stream>>>(embF, rk1a, rk1b, ssrc, topv);
  }
  // Overlap region is free of z-cache readers from here on.
  k_xw<<<1024, 128, 0, stream>>>(x, Wsrc, Wdst, Wlin, A, B, V);
  k_edge<<<8192, 256, 0, stream>>>(pos, ssrc, topv, ksrc, A, B, V,
                                   Wp1, bp1, WH, WL, bp2, ba1, ba2, h);
  k_down<<<1024, 128, 0, stream>>>(h, Wd, bd, hd);
  k_pool<<<8192, 128, 0, stream>>>(hd, ssrc, ksrc, y);
  hipMemsetAsync(accx, 0, (size_t)8192*128*4, stream);
  hipMemsetAsync(accp, 0, (size_t)8192*3*4, stream);
  k_scan<<<1, 256, 0, stream>>>(hist, rank, ucnt, Uo);
  k_agg<<<8192, 128, 0, stream>>>(y, pos, vid, rank, accx, accp);
  k_final<<<8192, 128, 0, stream>>>(accx, accp, ucnt, Uo, (float*)d_out);
}

// Round 14
// 796.919 us; speedup vs baseline: 1.1657x; 1.0008x over previous
//
#include <hip/hip_runtime.h>
#include <stdint.h>

// ---------------------------------------------------------------------------
// Enc_block: KNN graph + gumbel-softmax soft edges + PointTransformerConv +
// down + neighbor max-pool + GridSampling.  N=8192, Cin=64, Cout=128, K=16.
// k_edge now uses MFMA (bf16 hi/lo split => ~fp32 accuracy, ~2^-16 rel err).
// ---------------------------------------------------------------------------

typedef unsigned int u32;
typedef float v2f __attribute__((ext_vector_type(2)));
typedef float f32x4 __attribute__((ext_vector_type(4)));
typedef short bf16x8 __attribute__((ext_vector_type(8)));

#define NN 8192
#define EPS20 1e-20f
#define QSCALE 489.0671f   // 65535/134; z in [-99.8, 33.3] -> q = (z+100)*QSCALE

// f32 -> bf16 round-to-nearest-even (returns low 16 bits)
__host__ __device__ static inline u32 bf16rne(float x){
  u32 b = __float_as_uint(x);
  return (b + 0x7fffu + ((b>>16)&1u)) >> 16;
}

// ---------------- threefry2x32 (JAX key schedule) ----------------
__host__ __device__ static inline u32 rotl32(u32 v, int r){ return (v<<r)|(v>>(32-r)); }

__host__ __device__ static inline void tf2x32(u32 k0, u32 k1, u32 c0, u32 c1, u32& o0, u32& o1){
  u32 ks2 = k0 ^ k1 ^ 0x1BD11BDAu;
  u32 x0 = c0 + k0;
  u32 x1 = c1 + k1;
#define TFR(r) x0 += x1; x1 = rotl32(x1,(r)); x1 ^= x0;
  TFR(13) TFR(15) TFR(26) TFR(6)
  x0 += k1;  x1 += ks2 + 1u;
  TFR(17) TFR(29) TFR(16) TFR(24)
  x0 += ks2; x1 += k0 + 2u;
  TFR(13) TFR(15) TFR(26) TFR(6)
  x0 += k0;  x1 += k1 + 3u;
  TFR(17) TFR(29) TFR(16) TFR(24)
  x0 += k1;  x1 += ks2 + 4u;
  TFR(13) TFR(15) TFR(26) TFR(6)
  x0 += ks2; x1 += k0 + 5u;
#undef TFR
  o0 = x0; o1 = x1;
}

__device__ static inline u32 rbits(u32 k0, u32 k1, u32 idx){
  u32 o0,o1; tf2x32(k0,k1, 0u, idx, o0,o1);   // partitionable: counter (0, idx)
  return o0 ^ o1;                              // 32-bit fold
}

__device__ static inline float u01(u32 b){
  return __uint_as_float((b>>9) | 0x3f800000u) - 1.0f;   // [0,1), JAX formula
}

// z = 2*(g - d2); eps correction negligible for all selection-relevant entries
__device__ static inline float gumbel_g(u32 ub){
  float u = u01(ub);
  float w = -__logf(u + EPS20);
  return -__logf(w + EPS20);
}

// ---------------- workspace layout ----------------
static constexpr size_t OFF_EMBF = 0;                              // [8192][12] f32: e[10], se, K
static constexpr size_t OFF_SP   = OFF_EMBF + (size_t)8192*12*4;   // (unused, kept for layout)
static constexpr size_t OFF_PSUM = OFF_SP   + (size_t)8192*4;      // [32][8192]
static constexpr size_t OFF_SSRC = OFF_PSUM + (size_t)32*8192*4;   // int [8192][16]
static constexpr size_t OFF_TOPV = OFF_SSRC + (size_t)8192*16*4;
static constexpr size_t OFF_KSRC = OFF_TOPV + (size_t)8192*16*4;   // int [8192][16]
static constexpr size_t OFF_HIST = OFF_KSRC + (size_t)8192*16*4;   // int [8192]
static constexpr size_t OFF_RANK = OFF_HIST + (size_t)8192*4;
static constexpr size_t OFF_UCNT = OFF_RANK + (size_t)8192*4;
static constexpr size_t OFF_VID  = OFF_UCNT + (size_t)8192*4;
static constexpr size_t OFF_META = OFF_VID  + (size_t)8192*4;      // mi i[3] @0, mx i[3] @16B, U i @32B
static constexpr size_t OFF_QKI  = OFF_META + 64;                  // int [8192] quantized K
static constexpr size_t OFF_CAND = OFF_QKI  + (size_t)8192*4;      // int [8192][32]
static constexpr size_t OFF_POS4 = OFF_CAND + (size_t)8192*32*4;   // float4 [8192] {x,y,z,|p|^2}
static constexpr size_t OFF_WH   = (OFF_POS4 + (size_t)8192*16 + 255) & ~(size_t)255; // bf16 [3][128c][128k]
static constexpr size_t OFF_WL   = OFF_WH + (size_t)3*16384*2;
static constexpr size_t OFF_BIG  = (OFF_WL + (size_t)3*16384*2 + 255) & ~(size_t)255;
// Overlap region: u16 z-cache [8192][8192] lives here during colstats..rescore;
// A/B/V/H/HD/Y/ACCX/ACCP live here afterwards (k_xw launched after rescore).
static constexpr size_t OFF_A    = OFF_BIG;
static constexpr size_t OFF_B    = OFF_A    + (size_t)8192*128*4;
static constexpr size_t OFF_V    = OFF_B    + (size_t)8192*128*4;
static constexpr size_t OFF_H    = OFF_V    + (size_t)8192*128*4;
static constexpr size_t OFF_HD   = OFF_H    + (size_t)8192*128*4;
static constexpr size_t OFF_Y    = OFF_HD   + (size_t)8192*128*4;
static constexpr size_t OFF_ACCX = OFF_Y    + (size_t)8192*128*4;
static constexpr size_t OFF_ACCP = OFF_ACCX + (size_t)8192*128*4;
static constexpr size_t OFF_ZQ   = OFF_BIG;
static constexpr size_t ZQ_BYTES = (size_t)NN*NN*2;

// ---------------- kernels ----------------

__global__ void k_init0(int* __restrict__ mi, int* __restrict__ mx){
  int t = threadIdx.x;
  if (t < 3){ mi[t] = 0x7f7fffff; mx[t] = 0; }
}

// weight prep: Wp2/Wa1/Wa2 -> transposed bf16 hi/lo: W*[k][c] -> wt[m][c][k]
__global__ __launch_bounds__(128) void k_wprep(const float* __restrict__ Wp2,
    const float* __restrict__ Wa1, const float* __restrict__ Wa2,
    unsigned short* __restrict__ WH, unsigned short* __restrict__ WL){
  int m = blockIdx.x >> 7;
  int c = blockIdx.x & 127;
  int k = threadIdx.x;
  const float* Wm = (m==0) ? Wp2 : (m==1) ? Wa1 : Wa2;
  float x = Wm[k*128 + c];
  u32 hi = bf16rne(x);
  float lo = x - __uint_as_float(hi<<16);
  u32 lo16 = bf16rne(lo);
  size_t base = (size_t)m*16384 + (size_t)c*128 + k;
  WH[base] = (unsigned short)hi;
  WL[base] = (unsigned short)lo16;
}

// per-dim min of pos (positive floats: int-bit compare is order-preserving)
__global__ __launch_bounds__(256) void k_min(const float* __restrict__ pos, int* __restrict__ mi){
  __shared__ int red[768];
  int t = threadIdx.x;
  int n = blockIdx.x*256 + t;
  red[t]     = __float_as_int(pos[n*3+0]);
  red[256+t] = __float_as_int(pos[n*3+1]);
  red[512+t] = __float_as_int(pos[n*3+2]);
  __syncthreads();
  for (int s=128; s>0; s>>=1){
    if (t < s){
      red[t]     = min(red[t],     red[t+s]);
      red[256+t] = min(red[256+t], red[256+t+s]);
      red[512+t] = min(red[512+t], red[512+t+s]);
    }
    __syncthreads();
  }
  if (t == 0){ atomicMin(&mi[0], red[0]); atomicMin(&mi[1], red[256]); atomicMin(&mi[2], red[512]); }
}

// per-dim max voxel index
__global__ __launch_bounds__(256) void k_ext(const float* __restrict__ pos, const int* __restrict__ mi,
                                             int* __restrict__ mx){
  __shared__ int red[768];
  int t = threadIdx.x;
  int n = blockIdx.x*256 + t;
  float p0 = __int_as_float(mi[0]), p1 = __int_as_float(mi[1]), p2 = __int_as_float(mi[2]);
  red[t]     = (int)floorf((pos[n*3+0]-p0)*2.0f);   // /0.5 == *2 exactly
  red[256+t] = (int)floorf((pos[n*3+1]-p1)*2.0f);
  red[512+t] = (int)floorf((pos[n*3+2]-p2)*2.0f);
  __syncthreads();
  for (int s=128; s>0; s>>=1){
    if (t < s){
      red[t]     = max(red[t],     red[t+s]);
      red[256+t] = max(red[256+t], red[256+t+s]);
      red[512+t] = max(red[512+t], red[512+t+s]);
    }
    __syncthreads();
  }
  if (t == 0){ atomicMax(&mx[0], red[0]); atomicMax(&mx[1], red[256]); atomicMax(&mx[2], red[512]); }
}

// voxel id + histogram + SoA pos4 = {x,y,z,|p|^2}
__global__ __launch_bounds__(256) void k_vid(const float* __restrict__ pos,
                                             const int* __restrict__ mi, const int* __restrict__ mx,
                                             int* __restrict__ vid, int* __restrict__ hist,
                                             float4* __restrict__ pos4){
  int n = blockIdx.x*256 + threadIdx.x;
  float p0=pos[n*3], p1=pos[n*3+1], p2=pos[n*3+2];
  float4 p4; p4.x=p0; p4.y=p1; p4.z=p2; p4.w = p0*p0 + p1*p1 + p2*p2;
  pos4[n] = p4;
  float q0 = __int_as_float(mi[0]), q1 = __int_as_float(mi[1]), q2 = __int_as_float(mi[2]);
  int v0 = (int)floorf((p0-q0)*2.0f);
  int v1 = (int)floorf((p1-q1)*2.0f);
  int v2 = (int)floorf((p2-q2)*2.0f);
  int nv1 = mx[1]+1, nv2 = mx[2]+1;
  int id = (v0*nv1 + v1)*nv2 + v2;
  vid[n] = id;
  atomicAdd(&hist[id], 1);
}

// embF[i] = { relu(x@Wg1+bg1)@Wg2+bg2 + u*0.001  (10), |emb|^2, 0 }
__global__ __launch_bounds__(64) void k_emb(const float* __restrict__ x,
    const float* __restrict__ Wg1, const float* __restrict__ bg1,
    const float* __restrict__ Wg2, const float* __restrict__ bg2,
    u32 ka, u32 kb, float* __restrict__ embF){
  int i = blockIdx.x; int t = threadIdx.x;
  __shared__ float xs[64], hs[64], esq[10];
  xs[t] = x[i*64+t];
  __syncthreads();
  float a = bg1[t];
  for (int k=0; k<64; k++) a += xs[k]*Wg1[k*64+t];
  hs[t] = fmaxf(a, 0.0f);
  __syncthreads();
  if (t < 10){
    float e = bg2[t];
    for (int k=0; k<64; k++) e += hs[k]*Wg2[k*10+t];
    e += u01(rbits(ka, kb, (u32)(i*10+t))) * 0.001f;
    embF[i*12+t] = e;
    esq[t] = e*e;
  }
  __syncthreads();
  if (t == 0){
    float ssum = 0.0f;
    #pragma unroll
    for (int d=0; d<10; d++) ssum += esq[d];
    embF[i*12+10] = ssum;
    embF[i*12+11] = 0.0f;
  }
}

// KNN: top-16 smallest d2 per row (diag excluded), ties -> lower index.
__global__ __launch_bounds__(64) void k_knn(const float4* __restrict__ pos4,
                                            int* __restrict__ knn_src){
  int i = blockIdx.x; int l = threadIdx.x;
  float4 pi = pos4[i];
  float lv[8]; int lj[8];
  #pragma unroll
  for (int s=0; s<8; s++){ lv[s]=1e30f; lj[s]=0x7fffffff; }
  for (int tt=0; tt<128; tt++){
    int j = l + 64*tt;
    float4 pj = pos4[j];
    float d = pi.w + pj.w - 2.0f*(pi.x*pj.x + pi.y*pj.y + pi.z*pj.z);
    d = fmaxf(d, 0.0f);
    if (j != i && d < lv[7]){
      lv[7]=d; lj[7]=j;
      #pragma unroll
      for (int s=7; s>0; s--){
        if (lv[s] < lv[s-1]){ float tv=lv[s]; lv[s]=lv[s-1]; lv[s-1]=tv; int tj=lj[s]; lj[s]=lj[s-1]; lj[s-1]=tj; }
      }
    }
  }
  for (int r=0; r<16; r++){
    float bv = lv[0]; int bj = lj[0];
    #pragma unroll
    for (int off=32; off>=1; off>>=1){
      float ov = __shfl_xor(bv, off);
      int   oj = __shfl_xor(bj, off);
      if (ov < bv || (ov == bv && oj < bj)){ bv = ov; bj = oj; }
    }
    if (l == 0) knn_src[i*16+r] = bj;
    if (lj[0] == bj){
      #pragma unroll
      for (int s=0; s<7; s++){ lv[s]=lv[s+1]; lj[s]=lj[s+1]; }
      lv[7]=1e30f; lj[7]=0x7fffffff;
    }
  }
}

// column partial sums of exp(z-40); stores quantized z (u16) into the cache.
template<bool STZ>
__global__ __launch_bounds__(256) void k_colstats(const float* __restrict__ embF,
                                                  u32 ka, u32 kb, float* __restrict__ psum,
                                                  unsigned short* __restrict__ zq){
  __shared__ float4 sE4[768];                 // 256 rows x 12 floats
  int t = threadIdx.x;
  int j = blockIdx.x*256 + t;
  int i0 = blockIdx.y*256;
  const float4* gF = (const float4*)embF;
  #pragma unroll
  for (int q=0; q<3; q++) sE4[t + 256*q] = gF[(size_t)i0*3 + t + 256*q];
  __syncthreads();
  float4 b0 = gF[j*3+0], b1 = gF[j*3+1], b2 = gF[j*3+2];
  float sej = b2.z;
  float s = 0.0f;
  unsigned short* zp = STZ ? (zq + ((size_t)i0<<13) + j) : nullptr;
  for (int r=0; r<256; r++){
    float4 a0 = sE4[r*3+0], a1 = sE4[r*3+1], a2 = sE4[r*3+2];
    float dot = a0.x*b0.x + a0.y*b0.y + a0.z*b0.z + a0.w*b0.w
              + a1.x*b1.x + a1.y*b1.y + a1.z*b1.z + a1.w*b1.w
              + a2.x*b2.x + a2.y*b2.y;
    float d2 = fmaxf(a2.z + sej - 2.0f*dot, 0.0f);
    float g = gumbel_g(rbits(ka, kb, (u32)(i0+r)*8192u + (u32)j));
    float z = 2.0f*(g - d2);
    s += __expf(z - 40.0f);
    if (STZ){
      float qf = (z + 100.0f)*QSCALE + 0.5f;
      qf = fminf(fmaxf(qf, 0.0f), 65535.0f);
      *zp = (unsigned short)qf;
      zp += NN;
    }
  }
  psum[blockIdx.y*NN + j] = s;
}

// K_j = 40 + log(sum_chunks psum); write f32 K into embF[j][11] and quantized K
__global__ __launch_bounds__(256) void k_colfin(const float* __restrict__ psum, float* __restrict__ embF,
                                                int* __restrict__ qKi){
  int j = blockIdx.x*256 + threadIdx.x;
  float S = 0.0f;
  for (int c=0; c<32; c++) S += psum[c*NN + j];
  float K = 40.0f + __logf(S);
  embF[j*12+11] = K;
  qKi[j] = (int)((K + 100.0f)*QSCALE + 0.5f);   // same transform as z
}

// FALLBACK: per-row top-16 of y = z - K_j by full recompute
__global__ __launch_bounds__(64) void k_rowtopk(const float* __restrict__ embF,
    u32 ka, u32 kb, int* __restrict__ soft_src, float* __restrict__ top_v){
  int i = blockIdx.x; int l = threadIdx.x;
  const float4* gF = (const float4*)embF;
  float4 b0 = gF[i*3+0], b1 = gF[i*3+1], b2 = gF[i*3+2];
  float sei = b2.z;
  float lv[16]; int lj[16];
  #pragma unroll
  for (int s=0; s<16; s++){ lv[s]=-1e30f; lj[s]=0x7fffffff; }
  for (int tt=0; tt<128; tt++){
    int j = l + 64*tt;
    float4 a0 = gF[j*3+0], a1 = gF[j*3+1], a2 = gF[j*3+2];
    float dot = a0.x*b0.x + a0.y*b0.y + a0.z*b0.z + a0.w*b0.w
              + a1.x*b1.x + a1.y*b1.y + a1.z*b1.z + a1.w*b1.w
              + a2.x*b2.x + a2.y*b2.y;
    float d2 = fmaxf(a2.z + sei - 2.0f*dot, 0.0f);
    float g = gumbel_g(rbits(ka, kb, (u32)i*8192u + (u32)j));
    float z = 2.0f*(g - d2);
    float y = z - a2.w;
    if (y > lv[15]){
      lv[15]=y; lj[15]=j;
      #pragma unroll
      for (int s=15; s>0; s--){
        if (lv[s] > lv[s-1]){ float tv=lv[s]; lv[s]=lv[s-1]; lv[s-1]=tv; int tj=lj[s]; lj[s]=lj[s-1]; lj[s-1]=tj; }
      }
    }
  }
  for (int r=0; r<16; r++){
    float bv = lv[0]; int bj = lj[0];
    #pragma unroll
    for (int off=32; off>=1; off>>=1){
      float ov = __shfl_xor(bv, off);
      int   oj = __shfl_xor(bj, off);
      if (ov > bv || (ov == bv && oj < bj)){ bv = ov; bj = oj; }
    }
    if (l == 0){ soft_src[i*16+r] = bj; top_v[i*16+r] = __expf(bv); }
    if (lj[0] == bj){
      #pragma unroll
      for (int s=0; s<15; s++){ lv[s]=lv[s+1]; lj[s]=lj[s+1]; }
      lv[15]=-1e30f; lj[15]=0x7fffffff;
    }
  }
}

// cached path A: per-row top-32 candidates by integer qy = q_z - q_K
__global__ __launch_bounds__(64) void k_qtopk(const unsigned short* __restrict__ zq,
    const int* __restrict__ qKi, int* __restrict__ cand){
  int i = blockIdx.x; int l = threadIdx.x;
  const uint4* zrow = (const uint4*)(zq + ((size_t)i<<13));   // 8 u16 per uint4
  int lv[8]; int lj[8];
  #pragma unroll
  for (int s=0; s<8; s++){ lv[s]=-0x40000000; lj[s]=0x7fffffff; }
  for (int tt=0; tt<16; tt++){
    int blk = l + 64*tt;
    uint4 zv = zrow[blk];
    int jb = blk*8;
    const int4* qk4 = (const int4*)(qKi + jb);
    int4 ka4 = qk4[0], kb4 = qk4[1];
    u32 wv[4] = {zv.x, zv.y, zv.z, zv.w};
    int qk[8] = {ka4.x,ka4.y,ka4.z,ka4.w, kb4.x,kb4.y,kb4.z,kb4.w};
    #pragma unroll
    for (int c=0; c<8; c++){
      int qz = (int)((wv[c>>1] >> ((c&1)*16)) & 0xffffu);
      int qy = qz - qk[c];
      if (qy > lv[7]){
        lv[7]=qy; lj[7]=jb+c;
        #pragma unroll
        for (int s=7; s>0; s--){
          if (lv[s] > lv[s-1]){ int tv=lv[s]; lv[s]=lv[s-1]; lv[s-1]=tv; int tj=lj[s]; lj[s]=lj[s-1]; lj[s-1]=tj; }
        }
      }
    }
  }
  for (int r=0; r<32; r++){
    int bv = lv[0]; int bj = lj[0];
    #pragma unroll
    for (int off=32; off>=1; off>>=1){
      int ov = __shfl_xor(bv, off);
      int oj = __shfl_xor(bj, off);
      if (ov > bv || (ov == bv && oj < bj)){ bv = ov; bj = oj; }
    }
    if (l == 0) cand[i*32+r] = bj;
    if (lj[0] == bj){
      #pragma unroll
      for (int s=0; s<7; s++){ lv[s]=lv[s+1]; lj[s]=lj[s+1]; }
      lv[7]=-0x40000000; lj[7]=0x7fffffff;
    }
  }
}

// cached path B: exact rescore of the 32 candidates -> exact top-16
__global__ __launch_bounds__(64) void k_rescore(const float* __restrict__ embF,
    const int* __restrict__ cand, u32 ka, u32 kb,
    int* __restrict__ soft_src, float* __restrict__ top_v){
  int i = blockIdx.x; int l = threadIdx.x;
  const float4* gF = (const float4*)embF;
  float4 b0 = gF[i*3+0], b1 = gF[i*3+1], b2 = gF[i*3+2];
  float sei = b2.z;
  float y = -1e30f; int jc = 0x7fffffff;
  if (l < 32){
    jc = cand[i*32+l];
    float4 a0 = gF[jc*3+0], a1 = gF[jc*3+1], a2 = gF[jc*3+2];
    float dot = a0.x*b0.x + a0.y*b0.y + a0.z*b0.z + a0.w*b0.w
              + a1.x*b1.x + a1.y*b1.y + a1.z*b1.z + a1.w*b1.w
              + a2.x*b2.x + a2.y*b2.y;
    float d2 = fmaxf(a2.z + sei - 2.0f*dot, 0.0f);
    float g = gumbel_g(rbits(ka, kb, (u32)i*8192u + (u32)jc));
    float z = 2.0f*(g - d2);
    y = z - a2.w;
  }
  for (int r=0; r<16; r++){
    float bv = y; int bj = jc;
    #pragma unroll
    for (int off=32; off>=1; off>>=1){
      float ov = __shfl_xor(bv, off);
      int   oj = __shfl_xor(bj, off);
      if (ov > bv || (ov == bv && oj < bj)){ bv = ov; bj = oj; }
    }
    if (l == 0){ soft_src[i*16+r] = bj; top_v[i*16+r] = __expf(bv); }
    if (jc == bj){ y = -1e30f; jc = 0x7fffffff; }
  }
}

// A = x@Wsrc, B = x@Wdst, V = x@Wlin  (8 rows per block)
__global__ __launch_bounds__(128) void k_xw(const float* __restrict__ x,
    const float* __restrict__ Wsrc, const float* __restrict__ Wdst, const float* __restrict__ Wlin,
    float* __restrict__ A, float* __restrict__ B, float* __restrict__ V){
  int g0 = blockIdx.x*8; int c = threadIdx.x;
  __shared__ float xs[8][64];
  for (int idx=c; idx<512; idx+=128) xs[idx>>6][idx&63] = x[(g0 + (idx>>6))*64 + (idx&63)];
  __syncthreads();
  float aA[8], aB[8], aV[8];
  #pragma unroll
  for (int g=0; g<8; g++){ aA[g]=0.0f; aB[g]=0.0f; aV[g]=0.0f; }
  for (int k=0; k<64; k++){
    float ws=Wsrc[k*128+c], wd=Wdst[k*128+c], wl=Wlin[k*128+c];
    #pragma unroll
    for (int g=0; g<8; g++){
      float xv = xs[g][k];
      aA[g] += xv*ws; aB[g] += xv*wd; aV[g] += xv*wl;
    }
  }
  #pragma unroll
  for (int g=0; g<8; g++){
    A[(g0+g)*128+c]=aA[g]; B[(g0+g)*128+c]=aB[g]; V[(g0+g)*128+c]=aV[g];
  }
}

// 12 MFMA per k-step: (hi*hi + hi*lo + lo*hi) x 4 C-tiles.  A from LDS, B (weights) from L2.
#define MFMA3(WHP, WLP)                                                     \
  {                                                                         \
    _Pragma("unroll")                                                       \
    for (int s=0; s<4; s++){                                                \
      int kk = 32*s + 8*g;                                                  \
      bf16x8 a0h = *(const bf16x8*)(&ah[r0][kk]);                           \
      bf16x8 a1h = *(const bf16x8*)(&ah[16+r0][kk]);                        \
      bf16x8 a0l = *(const bf16x8*)(&al[r0][kk]);                           \
      bf16x8 a1l = *(const bf16x8*)(&al[16+r0][kk]);                        \
      const unsigned short* whp = (WHP) + (size_t)cn0*128 + kk;             \
      const unsigned short* wlp = (WLP) + (size_t)cn0*128 + kk;             \
      bf16x8 b0h = *(const bf16x8*)(whp);                                   \
      bf16x8 b1h = *(const bf16x8*)(whp + 2048);                            \
      bf16x8 b0l = *(const bf16x8*)(wlp);                                   \
      bf16x8 b1l = *(const bf16x8*)(wlp + 2048);                            \
      c00 = __builtin_amdgcn_mfma_f32_16x16x32_bf16(a0h,b0h,c00,0,0,0);     \
      c01 = __builtin_amdgcn_mfma_f32_16x16x32_bf16(a0h,b1h,c01,0,0,0);     \
      c10 = __builtin_amdgcn_mfma_f32_16x16x32_bf16(a1h,b0h,c10,0,0,0);     \
      c11 = __builtin_amdgcn_mfma_f32_16x16x32_bf16(a1h,b1h,c11,0,0,0);     \
      c00 = __builtin_amdgcn_mfma_f32_16x16x32_bf16(a0h,b0l,c00,0,0,0);     \
      c01 = __builtin_amdgcn_mfma_f32_16x16x32_bf16(a0h,b1l,c01,0,0,0);     \
      c10 = __builtin_amdgcn_mfma_f32_16x16x32_bf16(a1h,b0l,c10,0,0,0);     \
      c11 = __builtin_amdgcn_mfma_f32_16x16x32_bf16(a1h,b1l,c11,0,0,0);     \
      c00 = __builtin_amdgcn_mfma_f32_16x16x32_bf16(a0l,b0h,c00,0,0,0);     \
      c01 = __builtin_amdgcn_mfma_f32_16x16x32_bf16(a0l,b1h,c01,0,0,0);     \
      c10 = __builtin_amdgcn_mfma_f32_16x16x32_bf16(a1l,b0h,c10,0,0,0);     \
      c11 = __builtin_amdgcn_mfma_f32_16x16x32_bf16(a1l,b1h,c11,0,0,0);     \
    }                                                                       \
  }

// PointTransformerConv via MFMA.  256 threads = 4 waves; wave w owns output
// cols [32w, 32w+32).  A-fragments: row = l&15 (+16 per m-tile), k = 8*(l>>4)+i.
// B from transposed bf16 weights wt[col][k].  C/D: col = l&15 (+16n), row =
// (l>>4)*4 + reg (+16m)  [guide-verified mapping].
__global__ __launch_bounds__(256) void k_edge(const float* __restrict__ pos,
    const int* __restrict__ soft_src, const float* __restrict__ top_v, const int* __restrict__ knn_src,
    const float* __restrict__ A, const float* __restrict__ B, const float* __restrict__ V,
    const float* __restrict__ Wp1, const float* __restrict__ bp1,
    const unsigned short* __restrict__ WH, const unsigned short* __restrict__ WL,
    const float* __restrict__ bp2, const float* __restrict__ ba1, const float* __restrict__ ba2,
    float* __restrict__ h){
  int i = blockIdx.x; int t = threadIdx.x;
  int l = t & 63; int w = t >> 6;
  int g = l >> 4; int r0 = l & 15;
  int cn0 = 32*w + r0;
  __shared__ __align__(16) unsigned short ah[32][136];
  __shared__ __align__(16) unsigned short al[32][136];
  __shared__ int   ssrc[32];
  __shared__ float sw[32];
  __shared__ float sdp[32][3];
  if (t < 32){
    int s; float wt;
    if (t < 16){ s = soft_src[i*16+t]; wt = top_v[i*16+t]; }
    else       { s = knn_src[i*16+(t-16)]; wt = 1.0f; }
    ssrc[t]=s; sw[t]=wt;
    sdp[t][0]=pos[i*3]-pos[s*3]; sdp[t][1]=pos[i*3+1]-pos[s*3+1]; sdp[t][2]=pos[i*3+2]-pos[s*3+2];
  }
  __syncthreads();
  // stage1: ph = relu(dpos @ Wp1 + bp1) -> bf16 hi/lo.  thread: wave rows x cols {2l,2l+1}
  {
    const float2* W1v = (const float2*)Wp1;
    float2 q0 = W1v[l], q1 = W1v[64+l], q2 = W1v[128+l];
    float2 bb = ((const float2*)bp1)[l];
    #pragma unroll
    for (int e=0; e<8; e++){
      int row = 8*w + e;
      float d0=sdp[row][0], d1=sdp[row][1], d2=sdp[row][2];
      float vx = fmaxf(d0*q0.x + d1*q1.x + d2*q2.x + bb.x, 0.0f);
      float vy = fmaxf(d0*q0.y + d1*q1.y + d2*q2.y + bb.y, 0.0f);
      u32 hx = bf16rne(vx), hy = bf16rne(vy);
      float lx = vx - __uint_as_float(hx<<16);
      float ly = vy - __uint_as_float(hy<<16);
      u32 lx16 = bf16rne(lx), ly16 = bf16rne(ly);
      *(u32*)(&ah[row][2*l]) = hx | (hy<<16);
      *(u32*)(&al[row][2*l]) = lx16 | (ly16<<16);
    }
  }
  __syncthreads();
  f32x4 c00={0,0,0,0}, c01={0,0,0,0}, c10={0,0,0,0}, c11={0,0,0,0};
  // GEMM1: delta = ph @ Wp2 + bp2
  MFMA3(WH, WL);
  f32x4 dl00, dl01, dl10, dl11;
  {
    float bi0 = bp2[cn0], bi1 = bp2[cn0+16];
    #pragma unroll
    for (int r=0; r<4; r++){
      dl00[r]=c00[r]+bi0; dl01[r]=c01[r]+bi1;
      dl10[r]=c10[r]+bi0; dl11[r]=c11[r]+bi1;
    }
  }
  __syncthreads();                 // all GEMM1 reads of ah/al done
  // q-stage: q = B[i] - A[src] + delta -> bf16 hi/lo (scatter per C-frag element)
  int ssv[8];
  {
    float B0 = B[(size_t)i*128 + cn0];
    float B1 = B[(size_t)i*128 + cn0 + 16];
    #pragma unroll
    for (int m=0; m<2; m++){
      #pragma unroll
      for (int r=0; r<4; r++){
        int row = 16*m + 4*g + r;
        int sv = ssrc[row]; ssv[m*4+r] = sv;
        float a0 = A[(size_t)sv*128 + cn0];
        float a1 = A[(size_t)sv*128 + cn0 + 16];
        float q0 = B0 - a0 + (m ? dl10[r] : dl00[r]);
        float q1 = B1 - a1 + (m ? dl11[r] : dl01[r]);
        u32 h0 = bf16rne(q0); float lf0 = q0 - __uint_as_float(h0<<16);
        u32 h1 = bf16rne(q1); float lf1 = q1 - __uint_as_float(h1<<16);
        ah[row][cn0]    = (unsigned short)h0;  al[row][cn0]    = (unsigned short)bf16rne(lf0);
        ah[row][cn0+16] = (unsigned short)h1;  al[row][cn0+16] = (unsigned short)bf16rne(lf1);
      }
    }
  }
  __syncthreads();
  // GEMM2: ah_pre = q @ Wa1 + ba1
  c00=(f32x4){0,0,0,0}; c01=c00; c10=c00; c11=c00;
  MFMA3(WH + 16384, WL + 16384);
  __syncthreads();                 // all GEMM2 reads done
  {
    float b0v = ba1[cn0], b1v = ba1[cn0+16];
    #pragma unroll
    for (int m=0; m<2; m++){
      #pragma unroll
      for (int r=0; r<4; r++){
        int row = 16*m + 4*g + r;
        float v0 = fmaxf((m ? c10[r] : c00[r]) + b0v, 0.0f);
        float v1 = fmaxf((m ? c11[r] : c01[r]) + b1v, 0.0f);
        u32 h0 = bf16rne(v0); float lf0 = v0 - __uint_as_float(h0<<16);
        u32 h1 = bf16rne(v1); float lf1 = v1 - __uint_as_float(h1<<16);
        ah[row][cn0]    = (unsigned short)h0;  al[row][cn0]    = (unsigned short)bf16rne(lf0);
        ah[row][cn0+16] = (unsigned short)h1;  al[row][cn0+16] = (unsigned short)bf16rne(lf1);
      }
    }
  }
  __syncthreads();
  // GEMM3: logits = relu_out @ Wa2 + ba2
  c00=(f32x4){0,0,0,0}; c01=c00; c10=c00; c11=c00;
  MFMA3(WH + 32768, WL + 32768);
  // epilogue: per-col softmax over 32 edges (wave-local: rows split over lane groups)
  {
    float b0v = ba2[cn0], b1v = ba2[cn0+16];
    float lg[2][2][4];
    float M0 = -1e30f, M1 = -1e30f;
    #pragma unroll
    for (int m=0; m<2; m++){
      #pragma unroll
      for (int r=0; r<4; r++){
        lg[m][0][r] = (m ? c10[r] : c00[r]) + b0v;
        lg[m][1][r] = (m ? c11[r] : c01[r]) + b1v;
        M0 = fmaxf(M0, lg[m][0][r]);
        M1 = fmaxf(M1, lg[m][1][r]);
      }
    }
    M0 = fmaxf(M0, __shfl_xor(M0, 16)); M0 = fmaxf(M0, __shfl_xor(M0, 32));
    M1 = fmaxf(M1, __shfl_xor(M1, 16)); M1 = fmaxf(M1, __shfl_xor(M1, 32));
    float s0=0.0f, s1=0.0f, o0=0.0f, o1=0.0f;
    #pragma unroll
    for (int m=0; m<2; m++){
      #pragma unroll
      for (int r=0; r<4; r++){
        int row = 16*m + 4*g + r;
        int sv = ssv[m*4+r]; float wt = sw[row];
        float p0 = __expf(lg[m][0][r] - M0);
        float p1 = __expf(lg[m][1][r] - M1);
        s0 += p0; s1 += p1;
        float v0 = V[(size_t)sv*128 + cn0];
        float v1 = V[(size_t)sv*128 + cn0 + 16];
        o0 += p0*(v0 + (m ? dl10[r] : dl00[r]))*wt;
        o1 += p1*(v1 + (m ? dl11[r] : dl01[r]))*wt;
      }
    }
    s0 += __shfl_xor(s0, 16); s0 += __shfl_xor(s0, 32);
    s1 += __shfl_xor(s1, 16); s1 += __shfl_xor(s1, 32);
    o0 += __shfl_xor(o0, 16); o0 += __shfl_xor(o0, 32);
    o1 += __shfl_xor(o1, 16); o1 += __shfl_xor(o1, 32);
    if (g == 0){
      h[(size_t)i*128 + cn0]      = o0/(s0 + 1e-16f);
      h[(size_t)i*128 + cn0 + 16] = o1/(s1 + 1e-16f);
    }
  }
}

// hd = relu(h @ Wd + bd)
__global__ __launch_bounds__(128) void k_down(const float* __restrict__ h,
    const float* __restrict__ Wd, const float* __restrict__ bd, float* __restrict__ hd){
  int g0 = blockIdx.x*8; int c = threadIdx.x;
  __shared__ float hs[8][128];
  for (int idx=c; idx<1024; idx+=128) hs[idx>>7][idx&127] = h[(g0 + (idx>>7))*128 + (idx&127)];
  __syncthreads();
  float acc[8]; float b = bd[c];
  #pragma unroll
  for (int g=0; g<8; g++) acc[g] = b;
  for (int k=0; k<128; k+=4){
    float w0=Wd[(k+0)*128+c], w1=Wd[(k+1)*128+c], w2=Wd[(k+2)*128+c], w3=Wd[(k+3)*128+c];
    #pragma unroll
    for (int g=0; g<8; g++){
      const float4 ev = *(const float4*)(&hs[g][k]);
      acc[g] += ev.x*w0 + ev.y*w1 + ev.z*w2 + ev.w*w3;
    }
  }
  #pragma unroll
  for (int g=0; g<8; g++) hd[(g0+g)*128+c] = fmaxf(acc[g], 0.0f);
}

// y = max(hd[i], max over 32 neighbors hd[src])
__global__ __launch_bounds__(128) void k_pool(const float* __restrict__ hd,
    const int* __restrict__ soft_src, const int* __restrict__ knn_src, float* __restrict__ y){
  int i = blockIdx.x; int c = threadIdx.x;
  __shared__ int ss[32];
  if (c < 16) ss[c] = soft_src[i*16+c];
  else if (c < 32) ss[c] = knn_src[i*16+(c-16)];
  __syncthreads();
  float p = hd[i*128+c];
  for (int e=0; e<32; e++) p = fmaxf(p, hd[ss[e]*128+c]);
  y[i*128+c] = p;
}

// ranks = sorted-unique inverse (count of nonzero bins with smaller vid)
__global__ __launch_bounds__(256) void k_scan(const int* __restrict__ hist,
    int* __restrict__ rank, int* __restrict__ ucnt, int* __restrict__ Uo){
  __shared__ int part[256];
  int t = threadIdx.x;
  int base = t*32;
  int cnt = 0;
  for (int b=0; b<32; b++) cnt += (hist[base+b] > 0);
  part[t] = cnt;
  __syncthreads();
  if (t == 0){
    int run = 0;
    for (int q=0; q<256; q++){ int v = part[q]; part[q] = run; run += v; }
    Uo[0] = run;
  }
  __syncthreads();
  int run = part[t];
  for (int b=0; b<32; b++){
    int bin = base + b;
    rank[bin] = run;
    int hv = hist[bin];
    if (hv > 0){ ucnt[run] = hv; run++; }
  }
}

__global__ __launch_bounds__(128) void k_agg(const float* __restrict__ y, const float* __restrict__ pos,
    const int* __restrict__ vid, const int* __restrict__ rank,
    float* __restrict__ accx, float* __restrict__ accp){
  int n = blockIdx.x; int c = threadIdx.x;
  int r = rank[vid[n]];
  atomicAdd(&accx[r*128+c], y[n*128+c]);
  if (c < 3) atomicAdd(&accp[r*3+c], pos[n*3+c]);
}

__global__ __launch_bounds__(128) void k_final(const float* __restrict__ accx, const float* __restrict__ accp,
    const int* __restrict__ ucnt, const int* __restrict__ Uo, float* __restrict__ out){
  int r = blockIdx.x; int c = threadIdx.x;
  int u = Uo[0];
  float cnt = (r < u) ? (float)ucnt[r] : 0.0f;
  float den = fmaxf(cnt, 1.0f);
  out[r*128+c] = (r < u) ? accx[r*128+c]/den : 0.0f;
  if (c < 3) out[(size_t)NN*128 + r*3 + c] = (r < u) ? accp[r*3+c]/den : 0.0f;
  if (c == 0) out[(size_t)NN*128 + (size_t)NN*3 + r] = cnt;
}

// ---------------- launcher ----------------
extern "C" void kernel_launch(void* const* d_in, const int* in_sizes, int n_in,
                              void* d_out, int out_size, void* d_ws, size_t ws_size,
                              hipStream_t stream){
  (void)in_sizes; (void)n_in; (void)out_size;
  const float* x    = (const float*)d_in[0];
  const float* pos  = (const float*)d_in[1];
  const float* Wg1  = (const float*)d_in[2];
  const float* bg1  = (const float*)d_in[3];
  const float* Wg2  = (const float*)d_in[4];
  const float* bg2  = (const float*)d_in[5];
  const float* Wlin = (const float*)d_in[6];
  const float* Wsrc = (const float*)d_in[7];
  const float* Wdst = (const float*)d_in[8];
  const float* Wp1  = (const float*)d_in[9];
  const float* bp1  = (const float*)d_in[10];
  const float* Wp2  = (const float*)d_in[11];
  const float* bp2  = (const float*)d_in[12];
  const float* Wa1  = (const float*)d_in[13];
  const float* ba1  = (const float*)d_in[14];
  const float* Wa2  = (const float*)d_in[15];
  const float* ba2  = (const float*)d_in[16];
  const float* Wd   = (const float*)d_in[17];
  const float* bd   = (const float*)d_in[18];

  char* ws = (char*)d_ws;
  float* embF   = (float*)(ws + OFF_EMBF);
  float* psum   = (float*)(ws + OFF_PSUM);
  int*   ssrc   = (int*)  (ws + OFF_SSRC);
  float* topv   = (float*)(ws + OFF_TOPV);
  int*   ksrc   = (int*)  (ws + OFF_KSRC);
  int*   hist   = (int*)  (ws + OFF_HIST);
  int*   rank   = (int*)  (ws + OFF_RANK);
  int*   ucnt   = (int*)  (ws + OFF_UCNT);
  int*   vid    = (int*)  (ws + OFF_VID);
  int*   mi     = (int*)  (ws + OFF_META);
  int*   mx     = (int*)  (ws + OFF_META + 16);
  int*   Uo     = (int*)  (ws + OFF_META + 32);
  int*   qKi    = (int*)  (ws + OFF_QKI);
  int*   cand   = (int*)  (ws + OFF_CAND);
  float4* pos4  = (float4*)(ws + OFF_POS4);
  unsigned short* WH = (unsigned short*)(ws + OFF_WH);
  unsigned short* WL = (unsigned short*)(ws + OFF_WL);
  float* A      = (float*)(ws + OFF_A);
  float* B      = (float*)(ws + OFF_B);
  float* V      = (float*)(ws + OFF_V);
  float* h      = (float*)(ws + OFF_H);
  float* hd     = (float*)(ws + OFF_HD);
  float* y      = (float*)(ws + OFF_Y);
  float* accx   = (float*)(ws + OFF_ACCX);
  float* accp   = (float*)(ws + OFF_ACCP);
  unsigned short* zq = (unsigned short*)(ws + OFF_ZQ);

  const bool use_q = (ws_size >= OFF_ZQ + ZQ_BYTES);   // constant per run -> deterministic

  // rk = jax.random.split(jax.random.key(42), 2)  -- host threefry (foldlike)
  u32 rk0a, rk0b, rk1a, rk1b;
  tf2x32(0u, 42u, 0u, 0u, rk0a, rk0b);
  tf2x32(0u, 42u, 0u, 1u, rk1a, rk1b);

  hipMemsetAsync(hist, 0, 8192*4, stream);
  k_wprep<<<384, 128, 0, stream>>>(Wp2, Wa1, Wa2, WH, WL);
  k_init0<<<1, 64, 0, stream>>>(mi, mx);
  k_min<<<32, 256, 0, stream>>>(pos, mi);
  k_ext<<<32, 256, 0, stream>>>(pos, mi, mx);
  k_vid<<<32, 256, 0, stream>>>(pos, mi, mx, vid, hist, pos4);
  k_emb<<<8192, 64, 0, stream>>>(x, Wg1, bg1, Wg2, bg2, rk0a, rk0b, embF);
  k_knn<<<8192, 64, 0, stream>>>(pos4, ksrc);
  if (use_q){
    k_colstats<true><<<dim3(32,32), 256, 0, stream>>>(embF, rk1a, rk1b, psum, zq);
    k_colfin<<<32, 256, 0, stream>>>(psum, embF, qKi);
    k_qtopk<<<8192, 64, 0, stream>>>(zq, qKi, cand);
    k_rescore<<<8192, 64, 0, stream>>>(embF, cand, rk1a, rk1b, ssrc, topv);
  } else {
    k_colstats<false><<<dim3(32,32), 256, 0, stream>>>(embF, rk1a, rk1b, psum, nullptr);
    k_colfin<<<32, 256, 0, stream>>>(psum, embF, qKi);
    k_rowtopk<<<8192, 64, 0, stream>>>(embF, rk1a, rk1b, ssrc, topv);
  }
  // Overlap region is free of z-cache readers from here on.
  k_xw<<<1024, 128, 0, stream>>>(x, Wsrc, Wdst, Wlin, A, B, V);
  k_edge<<<8192, 256, 0, stream>>>(pos, ssrc, topv, ksrc, A, B, V,
                                   Wp1, bp1, WH, WL, bp2, ba1, ba2, h);
  k_down<<<1024, 128, 0, stream>>>(h, Wd, bd, hd);
  k_pool<<<8192, 128, 0, stream>>>(hd, ssrc, ksrc, y);
  hipMemsetAsync(accx, 0, (size_t)8192*128*4, stream);
  hipMemsetAsync(accp, 0, (size_t)8192*3*4, stream);
  k_scan<<<1, 256, 0, stream>>>(hist, rank, ucnt, Uo);
  k_agg<<<8192, 128, 0, stream>>>(y, pos, vid, rank, accx, accp);
  k_final<<<8192, 128, 0, stream>>>(accx, accp, ucnt, Uo, (float*)d_out);
}

// Round 15
// 757.845 us; speedup vs baseline: 1.2258x; 1.0516x over previous
//
#include <hip/hip_runtime.h>
#include <stdint.h>

// ---------------------------------------------------------------------------
// Enc_block: KNN graph + gumbel-softmax soft edges + PointTransformerConv +
// down + neighbor max-pool + GridSampling.  N=8192, Cin=64, Cout=128, K=16.
// k_edge uses MFMA (bf16 hi/lo split => ~fp32 accuracy, ~2^-16 rel err).
// ---------------------------------------------------------------------------

typedef unsigned int u32;
typedef float f32x4 __attribute__((ext_vector_type(4)));
typedef short bf16x8 __attribute__((ext_vector_type(8)));

#define NN 8192
#define EPS20 1e-20f
#define QSCALE 489.0671f   // 65535/134; z in [-99.8, 33.3] -> q = (z+100)*QSCALE

// f32 -> bf16 round-to-nearest-even (returns low 16 bits)
__host__ __device__ static inline u32 bf16rne(float x){
  u32 b = __float_as_uint(x);
  return (b + 0x7fffu + ((b>>16)&1u)) >> 16;
}

// ---------------- threefry2x32 (JAX key schedule) ----------------
// __builtin_rotateleft32 -> guaranteed v_alignbit_b32 (1 inst, not shl/shr/or)
__host__ __device__ static inline u32 rotl32(u32 v, int r){ return __builtin_rotateleft32(v, (u32)r); }

__host__ __device__ static inline void tf2x32(u32 k0, u32 k1, u32 c0, u32 c1, u32& o0, u32& o1){
  u32 ks2 = k0 ^ k1 ^ 0x1BD11BDAu;
  u32 x0 = c0 + k0;
  u32 x1 = c1 + k1;
#define TFR(r) x0 += x1; x1 = rotl32(x1,(r)); x1 ^= x0;
  TFR(13) TFR(15) TFR(26) TFR(6)
  x0 += k1;  x1 += ks2 + 1u;
  TFR(17) TFR(29) TFR(16) TFR(24)
  x0 += ks2; x1 += k0 + 2u;
  TFR(13) TFR(15) TFR(26) TFR(6)
  x0 += k0;  x1 += k1 + 3u;
  TFR(17) TFR(29) TFR(16) TFR(24)
  x0 += k1;  x1 += ks2 + 4u;
  TFR(13) TFR(15) TFR(26) TFR(6)
  x0 += ks2; x1 += k0 + 5u;
#undef TFR
  o0 = x0; o1 = x1;
}

__device__ static inline u32 rbits(u32 k0, u32 k1, u32 idx){
  u32 o0,o1; tf2x32(k0,k1, 0u, idx, o0,o1);   // partitionable: counter (0, idx)
  return o0 ^ o1;                              // 32-bit fold
}

__device__ static inline float u01(u32 b){
  return __uint_as_float((b>>9) | 0x3f800000u) - 1.0f;   // [0,1), JAX formula
}

// z = 2*(g - d2); eps correction negligible for all selection-relevant entries
__device__ static inline float gumbel_g(u32 ub){
  float u = u01(ub);
  float w = -__logf(u + EPS20);
  return -__logf(w + EPS20);
}

// ---------------- workspace layout ----------------
static constexpr size_t OFF_EMBF = 0;                              // [8192][12] f32: e[10], se, K
static constexpr size_t OFF_SP   = OFF_EMBF + (size_t)8192*12*4;   // (unused, kept for layout)
static constexpr size_t OFF_PSUM = OFF_SP   + (size_t)8192*4;      // [32][8192]
static constexpr size_t OFF_SSRC = OFF_PSUM + (size_t)32*8192*4;   // int [8192][16]
static constexpr size_t OFF_TOPV = OFF_SSRC + (size_t)8192*16*4;
static constexpr size_t OFF_KSRC = OFF_TOPV + (size_t)8192*16*4;   // int [8192][16]
static constexpr size_t OFF_HIST = OFF_KSRC + (size_t)8192*16*4;   // int [8192]
static constexpr size_t OFF_RANK = OFF_HIST + (size_t)8192*4;
static constexpr size_t OFF_UCNT = OFF_RANK + (size_t)8192*4;
static constexpr size_t OFF_VID  = OFF_UCNT + (size_t)8192*4;
static constexpr size_t OFF_META = OFF_VID  + (size_t)8192*4;      // mi i[3] @0, mx i[3] @16B, U i @32B
static constexpr size_t OFF_QKI  = OFF_META + 64;                  // int [8192] quantized K
static constexpr size_t OFF_CAND = OFF_QKI  + (size_t)8192*4;      // int [8192][32] (unused now)
static constexpr size_t OFF_POS4 = OFF_CAND + (size_t)8192*32*4;   // float4 [8192] {x,y,z,|p|^2}
static constexpr size_t OFF_WH   = (OFF_POS4 + (size_t)8192*16 + 255) & ~(size_t)255; // bf16 [3][128c][128k]
static constexpr size_t OFF_WL   = OFF_WH + (size_t)3*16384*2;
static constexpr size_t OFF_BIG  = (OFF_WL + (size_t)3*16384*2 + 255) & ~(size_t)255;
// Overlap region: u16 z-cache [8192][8192] lives here during colstats..qtopk;
// A/B/V/H/HD/Y/ACCX/ACCP live here afterwards (k_xw launched after qtopk).
static constexpr size_t OFF_A    = OFF_BIG;
static constexpr size_t OFF_B    = OFF_A    + (size_t)8192*128*4;
static constexpr size_t OFF_V    = OFF_B    + (size_t)8192*128*4;
static constexpr size_t OFF_H    = OFF_V    + (size_t)8192*128*4;
static constexpr size_t OFF_HD   = OFF_H    + (size_t)8192*128*4;
static constexpr size_t OFF_Y    = OFF_HD   + (size_t)8192*128*4;
static constexpr size_t OFF_ACCX = OFF_Y    + (size_t)8192*128*4;
static constexpr size_t OFF_ACCP = OFF_ACCX + (size_t)8192*128*4;
static constexpr size_t OFF_ZQ   = OFF_BIG;
static constexpr size_t ZQ_BYTES = (size_t)NN*NN*2;

// ---------------- kernels ----------------

__global__ void k_init0(int* __restrict__ mi, int* __restrict__ mx){
  int t = threadIdx.x;
  if (t < 3){ mi[t] = 0x7f7fffff; mx[t] = 0; }
}

// weight prep: Wp2/Wa1/Wa2 -> transposed bf16 hi/lo: W*[k][c] -> wt[m][c][k]
__global__ __launch_bounds__(128) void k_wprep(const float* __restrict__ Wp2,
    const float* __restrict__ Wa1, const float* __restrict__ Wa2,
    unsigned short* __restrict__ WH, unsigned short* __restrict__ WL){
  int m = blockIdx.x >> 7;
  int c = blockIdx.x & 127;
  int k = threadIdx.x;
  const float* Wm = (m==0) ? Wp2 : (m==1) ? Wa1 : Wa2;
  float x = Wm[k*128 + c];
  u32 hi = bf16rne(x);
  float lo = x - __uint_as_float(hi<<16);
  u32 lo16 = bf16rne(lo);
  size_t base = (size_t)m*16384 + (size_t)c*128 + k;
  WH[base] = (unsigned short)hi;
  WL[base] = (unsigned short)lo16;
}

// per-dim min of pos (positive floats: int-bit compare is order-preserving)
__global__ __launch_bounds__(256) void k_min(const float* __restrict__ pos, int* __restrict__ mi){
  __shared__ int red[768];
  int t = threadIdx.x;
  int n = blockIdx.x*256 + t;
  red[t]     = __float_as_int(pos[n*3+0]);
  red[256+t] = __float_as_int(pos[n*3+1]);
  red[512+t] = __float_as_int(pos[n*3+2]);
  __syncthreads();
  for (int s=128; s>0; s>>=1){
    if (t < s){
      red[t]     = min(red[t],     red[t+s]);
      red[256+t] = min(red[256+t], red[256+t+s]);
      red[512+t] = min(red[512+t], red[512+t+s]);
    }
    __syncthreads();
  }
  if (t == 0){ atomicMin(&mi[0], red[0]); atomicMin(&mi[1], red[256]); atomicMin(&mi[2], red[512]); }
}

// per-dim max voxel index
__global__ __launch_bounds__(256) void k_ext(const float* __restrict__ pos, const int* __restrict__ mi,
                                             int* __restrict__ mx){
  __shared__ int red[768];
  int t = threadIdx.x;
  int n = blockIdx.x*256 + t;
  float p0 = __int_as_float(mi[0]), p1 = __int_as_float(mi[1]), p2 = __int_as_float(mi[2]);
  red[t]     = (int)floorf((pos[n*3+0]-p0)*2.0f);   // /0.5 == *2 exactly
  red[256+t] = (int)floorf((pos[n*3+1]-p1)*2.0f);
  red[512+t] = (int)floorf((pos[n*3+2]-p2)*2.0f);
  __syncthreads();
  for (int s=128; s>0; s>>=1){
    if (t < s){
      red[t]     = max(red[t],     red[t+s]);
      red[256+t] = max(red[256+t], red[256+t+s]);
      red[512+t] = max(red[512+t], red[512+t+s]);
    }
    __syncthreads();
  }
  if (t == 0){ atomicMax(&mx[0], red[0]); atomicMax(&mx[1], red[256]); atomicMax(&mx[2], red[512]); }
}

// voxel id + histogram + SoA pos4 = {x,y,z,|p|^2}
__global__ __launch_bounds__(256) void k_vid(const float* __restrict__ pos,
                                             const int* __restrict__ mi, const int* __restrict__ mx,
                                             int* __restrict__ vid, int* __restrict__ hist,
                                             float4* __restrict__ pos4){
  int n = blockIdx.x*256 + threadIdx.x;
  float p0=pos[n*3], p1=pos[n*3+1], p2=pos[n*3+2];
  float4 p4; p4.x=p0; p4.y=p1; p4.z=p2; p4.w = p0*p0 + p1*p1 + p2*p2;
  pos4[n] = p4;
  float q0 = __int_as_float(mi[0]), q1 = __int_as_float(mi[1]), q2 = __int_as_float(mi[2]);
  int v0 = (int)floorf((p0-q0)*2.0f);
  int v1 = (int)floorf((p1-q1)*2.0f);
  int v2 = (int)floorf((p2-q2)*2.0f);
  int nv1 = mx[1]+1, nv2 = mx[2]+1;
  int id = (v0*nv1 + v1)*nv2 + v2;
  vid[n] = id;
  atomicAdd(&hist[id], 1);
}

// embF[i] = { relu(x@Wg1+bg1)@Wg2+bg2 + u*0.001  (10), |emb|^2, 0 }
__global__ __launch_bounds__(64) void k_emb(const float* __restrict__ x,
    const float* __restrict__ Wg1, const float* __restrict__ bg1,
    const float* __restrict__ Wg2, const float* __restrict__ bg2,
    u32 ka, u32 kb, float* __restrict__ embF){
  int i = blockIdx.x; int t = threadIdx.x;
  __shared__ float xs[64], hs[64], esq[10];
  xs[t] = x[i*64+t];
  __syncthreads();
  float a = bg1[t];
  for (int k=0; k<64; k++) a += xs[k]*Wg1[k*64+t];
  hs[t] = fmaxf(a, 0.0f);
  __syncthreads();
  if (t < 10){
    float e = bg2[t];
    for (int k=0; k<64; k++) e += hs[k]*Wg2[k*10+t];
    e += u01(rbits(ka, kb, (u32)(i*10+t))) * 0.001f;
    embF[i*12+t] = e;
    esq[t] = e*e;
  }
  __syncthreads();
  if (t == 0){
    float ssum = 0.0f;
    #pragma unroll
    for (int d=0; d<10; d++) ssum += esq[d];
    embF[i*12+10] = ssum;
    embF[i*12+11] = 0.0f;
  }
}

// KNN: top-16 smallest d2 per row (diag excluded), ties -> lower index.
__global__ __launch_bounds__(64) void k_knn(const float4* __restrict__ pos4,
                                            int* __restrict__ knn_src){
  int i = blockIdx.x; int l = threadIdx.x;
  float4 pi = pos4[i];
  float lv[8]; int lj[8];
  #pragma unroll
  for (int s=0; s<8; s++){ lv[s]=1e30f; lj[s]=0x7fffffff; }
  for (int tt=0; tt<128; tt++){
    int j = l + 64*tt;
    float4 pj = pos4[j];
    float d = pi.w + pj.w - 2.0f*(pi.x*pj.x + pi.y*pj.y + pi.z*pj.z);
    d = fmaxf(d, 0.0f);
    if (j != i && d < lv[7]){
      lv[7]=d; lj[7]=j;
      #pragma unroll
      for (int s=7; s>0; s--){
        if (lv[s] < lv[s-1]){ float tv=lv[s]; lv[s]=lv[s-1]; lv[s-1]=tv; int tj=lj[s]; lj[s]=lj[s-1]; lj[s-1]=tj; }
      }
    }
  }
  for (int r=0; r<16; r++){
    float bv = lv[0]; int bj = lj[0];
    #pragma unroll
    for (int off=32; off>=1; off>>=1){
      float ov = __shfl_xor(bv, off);
      int   oj = __shfl_xor(bj, off);
      if (ov < bv || (ov == bv && oj < bj)){ bv = ov; bj = oj; }
    }
    if (l == 0) knn_src[i*16+r] = bj;
    if (lj[0] == bj){
      #pragma unroll
      for (int s=0; s<7; s++){ lv[s]=lv[s+1]; lj[s]=lj[s+1]; }
      lv[7]=1e30f; lj[7]=0x7fffffff;
    }
  }
}

// column partial sums of exp(z-40); stores quantized z (u16) into the cache.
template<bool STZ>
__global__ __launch_bounds__(256) void k_colstats(const float* __restrict__ embF,
                                                  u32 ka, u32 kb, float* __restrict__ psum,
                                                  unsigned short* __restrict__ zq){
  __shared__ float4 sE4[768];                 // 256 rows x 12 floats
  int t = threadIdx.x;
  int j = blockIdx.x*256 + t;
  int i0 = blockIdx.y*256;
  const float4* gF = (const float4*)embF;
  #pragma unroll
  for (int q=0; q<3; q++) sE4[t + 256*q] = gF[(size_t)i0*3 + t + 256*q];
  __syncthreads();
  float4 b0 = gF[j*3+0], b1 = gF[j*3+1], b2 = gF[j*3+2];
  float sej = b2.z;
  float s = 0.0f;
  unsigned short* zp = STZ ? (zq + ((size_t)i0<<13) + j) : nullptr;
  u32 idx = (u32)i0*8192u + (u32)j;
  #pragma unroll 4
  for (int r=0; r<256; r++){
    float4 a0 = sE4[r*3+0], a1 = sE4[r*3+1], a2 = sE4[r*3+2];
    float dot = a0.x*b0.x + a0.y*b0.y + a0.z*b0.z + a0.w*b0.w
              + a1.x*b1.x + a1.y*b1.y + a1.z*b1.z + a1.w*b1.w
              + a2.x*b2.x + a2.y*b2.y;
    float d2 = fmaxf(a2.z + sej - 2.0f*dot, 0.0f);
    float g = gumbel_g(rbits(ka, kb, idx));
    float z = 2.0f*(g - d2);
    s += __expf(z - 40.0f);
    if (STZ){
      float qf = (z + 100.0f)*QSCALE + 0.5f;
      qf = fminf(fmaxf(qf, 0.0f), 65535.0f);
      *zp = (unsigned short)qf;
      zp += NN;
    }
    idx += 8192u;
  }
  psum[blockIdx.y*NN + j] = s;
}

// K_j = 40 + log(sum_chunks psum); write f32 K into embF[j][11] and quantized K
__global__ __launch_bounds__(256) void k_colfin(const float* __restrict__ psum, float* __restrict__ embF,
                                                int* __restrict__ qKi){
  int j = blockIdx.x*256 + threadIdx.x;
  float S = 0.0f;
  for (int c=0; c<32; c++) S += psum[c*NN + j];
  float K = 40.0f + __logf(S);
  embF[j*12+11] = K;
  qKi[j] = (int)((K + 100.0f)*QSCALE + 0.5f);   // same transform as z
}

// FALLBACK: per-row top-16 of y = z - K_j by full recompute
__global__ __launch_bounds__(64) void k_rowtopk(const float* __restrict__ embF,
    u32 ka, u32 kb, int* __restrict__ soft_src, float* __restrict__ top_v){
  int i = blockIdx.x; int l = threadIdx.x;
  const float4* gF = (const float4*)embF;
  float4 b0 = gF[i*3+0], b1 = gF[i*3+1], b2 = gF[i*3+2];
  float sei = b2.z;
  float lv[16]; int lj[16];
  #pragma unroll
  for (int s=0; s<16; s++){ lv[s]=-1e30f; lj[s]=0x7fffffff; }
  for (int tt=0; tt<128; tt++){
    int j = l + 64*tt;
    float4 a0 = gF[j*3+0], a1 = gF[j*3+1], a2 = gF[j*3+2];
    float dot = a0.x*b0.x + a0.y*b0.y + a0.z*b0.z + a0.w*b0.w
              + a1.x*b1.x + a1.y*b1.y + a1.z*b1.z + a1.w*b1.w
              + a2.x*b2.x + a2.y*b2.y;
    float d2 = fmaxf(a2.z + sei - 2.0f*dot, 0.0f);
    float g = gumbel_g(rbits(ka, kb, (u32)i*8192u + (u32)j));
    float z = 2.0f*(g - d2);
    float y = z - a2.w;
    if (y > lv[15]){
      lv[15]=y; lj[15]=j;
      #pragma unroll
      for (int s=15; s>0; s--){
        if (lv[s] > lv[s-1]){ float tv=lv[s]; lv[s]=lv[s-1]; lv[s-1]=tv; int tj=lj[s]; lj[s]=lj[s-1]; lj[s-1]=tj; }
      }
    }
  }
  for (int r=0; r<16; r++){
    float bv = lv[0]; int bj = lj[0];
    #pragma unroll
    for (int off=32; off>=1; off>>=1){
      float ov = __shfl_xor(bv, off);
      int   oj = __shfl_xor(bj, off);
      if (ov > bv || (ov == bv && oj < bj)){ bv = ov; bj = oj; }
    }
    if (l == 0){ soft_src[i*16+r] = bj; top_v[i*16+r] = __expf(bv); }
    if (lj[0] == bj){
      #pragma unroll
      for (int s=0; s<15; s++){ lv[s]=lv[s+1]; lj[s]=lj[s+1]; }
      lv[15]=-1e30f; lj[15]=0x7fffffff;
    }
  }
}

// cached path: per-row top-32 candidates by integer qy = q_z - q_K, then
// FUSED exact rescore of the 32 candidates -> exact top-16 (same kernel).
__global__ __launch_bounds__(64) void k_qtopk(const unsigned short* __restrict__ zq,
    const int* __restrict__ qKi, const float* __restrict__ embF,
    u32 ka, u32 kb, int* __restrict__ soft_src, float* __restrict__ top_v){
  int i = blockIdx.x; int l = threadIdx.x;
  const uint4* zrow = (const uint4*)(zq + ((size_t)i<<13));   // 8 u16 per uint4
  int lv[8]; int lj[8];
  #pragma unroll
  for (int s=0; s<8; s++){ lv[s]=-0x40000000; lj[s]=0x7fffffff; }
  for (int tt=0; tt<16; tt++){
    int blk = l + 64*tt;
    uint4 zv = zrow[blk];
    int jb = blk*8;
    const int4* qk4 = (const int4*)(qKi + jb);
    int4 ka4 = qk4[0], kb4 = qk4[1];
    u32 wv[4] = {zv.x, zv.y, zv.z, zv.w};
    int qk[8] = {ka4.x,ka4.y,ka4.z,ka4.w, kb4.x,kb4.y,kb4.z,kb4.w};
    #pragma unroll
    for (int c=0; c<8; c++){
      int qz = (int)((wv[c>>1] >> ((c&1)*16)) & 0xffffu);
      int qy = qz - qk[c];
      if (qy > lv[7]){
        lv[7]=qy; lj[7]=jb+c;
        #pragma unroll
        for (int s=7; s>0; s--){
          if (lv[s] > lv[s-1]){ int tv=lv[s]; lv[s]=lv[s-1]; lv[s-1]=tv; int tj=lj[s]; lj[s]=lj[s-1]; lj[s-1]=tj; }
        }
      }
    }
  }
  int myc = 0x7fffffff;          // lane r keeps candidate rank r (r<32)
  for (int r=0; r<32; r++){
    int bv = lv[0]; int bj = lj[0];
    #pragma unroll
    for (int off=32; off>=1; off>>=1){
      int ov = __shfl_xor(bv, off);
      int oj = __shfl_xor(bj, off);
      if (ov > bv || (ov == bv && oj < bj)){ bv = ov; bj = oj; }
    }
    if (l == r) myc = bj;
    if (lj[0] == bj){
      #pragma unroll
      for (int s=0; s<7; s++){ lv[s]=lv[s+1]; lj[s]=lj[s+1]; }
      lv[7]=-0x40000000; lj[7]=0x7fffffff;
    }
  }
  // fused exact rescore (identical arithmetic to the old k_rescore)
  const float4* gF = (const float4*)embF;
  float4 b0 = gF[i*3+0], b1 = gF[i*3+1], b2 = gF[i*3+2];
  float sei = b2.z;
  float y = -1e30f; int jc = 0x7fffffff;
  if (l < 32 && myc != 0x7fffffff){
    jc = myc;
    float4 a0 = gF[jc*3+0], a1 = gF[jc*3+1], a2 = gF[jc*3+2];
    float dot = a0.x*b0.x + a0.y*b0.y + a0.z*b0.z + a0.w*b0.w
              + a1.x*b1.x + a1.y*b1.y + a1.z*b1.z + a1.w*b1.w
              + a2.x*b2.x + a2.y*b2.y;
    float d2 = fmaxf(a2.z + sei - 2.0f*dot, 0.0f);
    float g = gumbel_g(rbits(ka, kb, (u32)i*8192u + (u32)jc));
    float z = 2.0f*(g - d2);
    y = z - a2.w;
  }
  for (int r=0; r<16; r++){
    float bv = y; int bj = jc;
    #pragma unroll
    for (int off=32; off>=1; off>>=1){
      float ov = __shfl_xor(bv, off);
      int   oj = __shfl_xor(bj, off);
      if (ov > bv || (ov == bv && oj < bj)){ bv = ov; bj = oj; }
    }
    if (l == 0){ soft_src[i*16+r] = bj; top_v[i*16+r] = __expf(bv); }
    if (jc == bj){ y = -1e30f; jc = 0x7fffffff; }
  }
}

// A = x@Wsrc, B = x@Wdst, V = x@Wlin  (8 rows per block)
__global__ __launch_bounds__(128) void k_xw(const float* __restrict__ x,
    const float* __restrict__ Wsrc, const float* __restrict__ Wdst, const float* __restrict__ Wlin,
    float* __restrict__ A, float* __restrict__ B, float* __restrict__ V){
  int g0 = blockIdx.x*8; int c = threadIdx.x;
  __shared__ float xs[8][64];
  for (int idx=c; idx<512; idx+=128) xs[idx>>6][idx&63] = x[(g0 + (idx>>6))*64 + (idx&63)];
  __syncthreads();
  float aA[8], aB[8], aV[8];
  #pragma unroll
  for (int g=0; g<8; g++){ aA[g]=0.0f; aB[g]=0.0f; aV[g]=0.0f; }
  for (int k=0; k<64; k++){
    float ws=Wsrc[k*128+c], wd=Wdst[k*128+c], wl=Wlin[k*128+c];
    #pragma unroll
    for (int g=0; g<8; g++){
      float xv = xs[g][k];
      aA[g] += xv*ws; aB[g] += xv*wd; aV[g] += xv*wl;
    }
  }
  #pragma unroll
  for (int g=0; g<8; g++){
    A[(g0+g)*128+c]=aA[g]; B[(g0+g)*128+c]=aB[g]; V[(g0+g)*128+c]=aV[g];
  }
}

// 12 MFMA per k-step: (hi*hi + hi*lo + lo*hi) x 4 C-tiles.  A from LDS, B (weights) from L2.
#define MFMA3(WHP, WLP)                                                     \
  {                                                                         \
    _Pragma("unroll")                                                       \
    for (int s=0; s<4; s++){                                                \
      int kk = 32*s + 8*g;                                                  \
      bf16x8 a0h = *(const bf16x8*)(&ah[r0][kk]);                           \
      bf16x8 a1h = *(const bf16x8*)(&ah[16+r0][kk]);                        \
      bf16x8 a0l = *(const bf16x8*)(&al[r0][kk]);                           \
      bf16x8 a1l = *(const bf16x8*)(&al[16+r0][kk]);                        \
      const unsigned short* whp = (WHP) + (size_t)cn0*128 + kk;             \
      const unsigned short* wlp = (WLP) + (size_t)cn0*128 + kk;             \
      bf16x8 b0h = *(const bf16x8*)(whp);                                   \
      bf16x8 b1h = *(const bf16x8*)(whp + 2048);                            \
      bf16x8 b0l = *(const bf16x8*)(wlp);                                   \
      bf16x8 b1l = *(const bf16x8*)(wlp + 2048);                            \
      c00 = __builtin_amdgcn_mfma_f32_16x16x32_bf16(a0h,b0h,c00,0,0,0);     \
      c01 = __builtin_amdgcn_mfma_f32_16x16x32_bf16(a0h,b1h,c01,0,0,0);     \
      c10 = __builtin_amdgcn_mfma_f32_16x16x32_bf16(a1h,b0h,c10,0,0,0);     \
      c11 = __builtin_amdgcn_mfma_f32_16x16x32_bf16(a1h,b1h,c11,0,0,0);     \
      c00 = __builtin_amdgcn_mfma_f32_16x16x32_bf16(a0h,b0l,c00,0,0,0);     \
      c01 = __builtin_amdgcn_mfma_f32_16x16x32_bf16(a0h,b1l,c01,0,0,0);     \
      c10 = __builtin_amdgcn_mfma_f32_16x16x32_bf16(a1h,b0l,c10,0,0,0);     \
      c11 = __builtin_amdgcn_mfma_f32_16x16x32_bf16(a1h,b1l,c11,0,0,0);     \
      c00 = __builtin_amdgcn_mfma_f32_16x16x32_bf16(a0l,b0h,c00,0,0,0);     \
      c01 = __builtin_amdgcn_mfma_f32_16x16x32_bf16(a0l,b1h,c01,0,0,0);     \
      c10 = __builtin_amdgcn_mfma_f32_16x16x32_bf16(a1l,b0h,c10,0,0,0);     \
      c11 = __builtin_amdgcn_mfma_f32_16x16x32_bf16(a1l,b1h,c11,0,0,0);     \
    }                                                                       \
  }

// PointTransformerConv via MFMA.  256 threads = 4 waves; wave w owns output
// cols [32w, 32w+32).  A-fragments: row = l&15 (+16 per m-tile), k = 8*(l>>4)+i.
// B from transposed bf16 weights wt[col][k].  C/D: col = l&15 (+16n), row =
// (l>>4)*4 + reg (+16m)  [guide-verified mapping].
__global__ __launch_bounds__(256) void k_edge(const float* __restrict__ pos,
    const int* __restrict__ soft_src, const float* __restrict__ top_v, const int* __restrict__ knn_src,
    const float* __restrict__ A, const float* __restrict__ B, const float* __restrict__ V,
    const float* __restrict__ Wp1, const float* __restrict__ bp1,
    const unsigned short* __restrict__ WH, const unsigned short* __restrict__ WL,
    const float* __restrict__ bp2, const float* __restrict__ ba1, const float* __restrict__ ba2,
    float* __restrict__ h){
  int i = blockIdx.x; int t = threadIdx.x;
  int l = t & 63; int w = t >> 6;
  int g = l >> 4; int r0 = l & 15;
  int cn0 = 32*w + r0;
  __shared__ __align__(16) unsigned short ah[32][136];
  __shared__ __align__(16) unsigned short al[32][136];
  __shared__ int   ssrc[32];
  __shared__ float sw[32];
  __shared__ float sdp[32][3];
  if (t < 32){
    int s; float wt;
    if (t < 16){ s = soft_src[i*16+t]; wt = top_v[i*16+t]; }
    else       { s = knn_src[i*16+(t-16)]; wt = 1.0f; }
    ssrc[t]=s; sw[t]=wt;
    sdp[t][0]=pos[i*3]-pos[s*3]; sdp[t][1]=pos[i*3+1]-pos[s*3+1]; sdp[t][2]=pos[i*3+2]-pos[s*3+2];
  }
  __syncthreads();
  // stage1: ph = relu(dpos @ Wp1 + bp1) -> bf16 hi/lo.  thread: wave rows x cols {2l,2l+1}
  {
    const float2* W1v = (const float2*)Wp1;
    float2 q0 = W1v[l], q1 = W1v[64+l], q2 = W1v[128+l];
    float2 bb = ((const float2*)bp1)[l];
    #pragma unroll
    for (int e=0; e<8; e++){
      int row = 8*w + e;
      float d0=sdp[row][0], d1=sdp[row][1], d2=sdp[row][2];
      float vx = fmaxf(d0*q0.x + d1*q1.x + d2*q2.x + bb.x, 0.0f);
      float vy = fmaxf(d0*q0.y + d1*q1.y + d2*q2.y + bb.y, 0.0f);
      u32 hx = bf16rne(vx), hy = bf16rne(vy);
      float lx = vx - __uint_as_float(hx<<16);
      float ly = vy - __uint_as_float(hy<<16);
      u32 lx16 = bf16rne(lx), ly16 = bf16rne(ly);
      *(u32*)(&ah[row][2*l]) = hx | (hy<<16);
      *(u32*)(&al[row][2*l]) = lx16 | (ly16<<16);
    }
  }
  // prefetch q-stage operands (independent of GEMM1) -- hides gather latency
  int ssv[8];
  float pfA0[8], pfA1[8];
  float B0, B1;
  {
    B0 = B[(size_t)i*128 + cn0];
    B1 = B[(size_t)i*128 + cn0 + 16];
    #pragma unroll
    for (int m=0; m<2; m++){
      #pragma unroll
      for (int r=0; r<4; r++){
        int row = 16*m + 4*g + r;
        int sv = ssrc[row]; ssv[m*4+r] = sv;
        pfA0[m*4+r] = A[(size_t)sv*128 + cn0];
        pfA1[m*4+r] = A[(size_t)sv*128 + cn0 + 16];
      }
    }
  }
  __syncthreads();
  f32x4 c00={0,0,0,0}, c01={0,0,0,0}, c10={0,0,0,0}, c11={0,0,0,0};
  // GEMM1: delta = ph @ Wp2 + bp2
  MFMA3(WH, WL);
  f32x4 dl00, dl01, dl10, dl11;
  {
    float bi0 = bp2[cn0], bi1 = bp2[cn0+16];
    #pragma unroll
    for (int r=0; r<4; r++){
      dl00[r]=c00[r]+bi0; dl01[r]=c01[r]+bi1;
      dl10[r]=c10[r]+bi0; dl11[r]=c11[r]+bi1;
    }
  }
  __syncthreads();                 // all GEMM1 reads of ah/al done
  // q-stage: q = B[i] - A[src] + delta -> bf16 hi/lo (prefetched operands)
  {
    #pragma unroll
    for (int m=0; m<2; m++){
      #pragma unroll
      for (int r=0; r<4; r++){
        int row = 16*m + 4*g + r;
        float q0 = B0 - pfA0[m*4+r] + (m ? dl10[r] : dl00[r]);
        float q1 = B1 - pfA1[m*4+r] + (m ? dl11[r] : dl01[r]);
        u32 h0 = bf16rne(q0); float lf0 = q0 - __uint_as_float(h0<<16);
        u32 h1 = bf16rne(q1); float lf1 = q1 - __uint_as_float(h1<<16);
        ah[row][cn0]    = (unsigned short)h0;  al[row][cn0]    = (unsigned short)bf16rne(lf0);
        ah[row][cn0+16] = (unsigned short)h1;  al[row][cn0+16] = (unsigned short)bf16rne(lf1);
      }
    }
  }
  __syncthreads();
  // GEMM2: ah_pre = q @ Wa1 + ba1
  c00=(f32x4){0,0,0,0}; c01=c00; c10=c00; c11=c00;
  MFMA3(WH + 16384, WL + 16384);
  __syncthreads();                 // all GEMM2 reads done
  {
    float b0v = ba1[cn0], b1v = ba1[cn0+16];
    #pragma unroll
    for (int m=0; m<2; m++){
      #pragma unroll
      for (int r=0; r<4; r++){
        int row = 16*m + 4*g + r;
        float v0 = fmaxf((m ? c10[r] : c00[r]) + b0v, 0.0f);
        float v1 = fmaxf((m ? c11[r] : c01[r]) + b1v, 0.0f);
        u32 h0 = bf16rne(v0); float lf0 = v0 - __uint_as_float(h0<<16);
        u32 h1 = bf16rne(v1); float lf1 = v1 - __uint_as_float(h1<<16);
        ah[row][cn0]    = (unsigned short)h0;  al[row][cn0]    = (unsigned short)bf16rne(lf0);
        ah[row][cn0+16] = (unsigned short)h1;  al[row][cn0+16] = (unsigned short)bf16rne(lf1);
      }
    }
  }
  __syncthreads();
  // prefetch V (epilogue operand, independent of GEMM3)
  float pfV0[8], pfV1[8];
  #pragma unroll
  for (int m=0; m<2; m++){
    #pragma unroll
    for (int r=0; r<4; r++){
      int sv = ssv[m*4+r];
      pfV0[m*4+r] = V[(size_t)sv*128 + cn0];
      pfV1[m*4+r] = V[(size_t)sv*128 + cn0 + 16];
    }
  }
  // GEMM3: logits = relu_out @ Wa2 + ba2
  c00=(f32x4){0,0,0,0}; c01=c00; c10=c00; c11=c00;
  MFMA3(WH + 32768, WL + 32768);
  // epilogue: per-col softmax over 32 edges (wave-local: rows split over lane groups)
  {
    float b0v = ba2[cn0], b1v = ba2[cn0+16];
    float lg[2][2][4];
    float M0 = -1e30f, M1 = -1e30f;
    #pragma unroll
    for (int m=0; m<2; m++){
      #pragma unroll
      for (int r=0; r<4; r++){
        lg[m][0][r] = (m ? c10[r] : c00[r]) + b0v;
        lg[m][1][r] = (m ? c11[r] : c01[r]) + b1v;
        M0 = fmaxf(M0, lg[m][0][r]);
        M1 = fmaxf(M1, lg[m][1][r]);
      }
    }
    M0 = fmaxf(M0, __shfl_xor(M0, 16)); M0 = fmaxf(M0, __shfl_xor(M0, 32));
    M1 = fmaxf(M1, __shfl_xor(M1, 16)); M1 = fmaxf(M1, __shfl_xor(M1, 32));
    float s0=0.0f, s1=0.0f, o0=0.0f, o1=0.0f;
    #pragma unroll
    for (int m=0; m<2; m++){
      #pragma unroll
      for (int r=0; r<4; r++){
        int row = 16*m + 4*g + r;
        float wt = sw[row];
        float p0 = __expf(lg[m][0][r] - M0);
        float p1 = __expf(lg[m][1][r] - M1);
        s0 += p0; s1 += p1;
        o0 += p0*(pfV0[m*4+r] + (m ? dl10[r] : dl00[r]))*wt;
        o1 += p1*(pfV1[m*4+r] + (m ? dl11[r] : dl01[r]))*wt;
      }
    }
    s0 += __shfl_xor(s0, 16); s0 += __shfl_xor(s0, 32);
    s1 += __shfl_xor(s1, 16); s1 += __shfl_xor(s1, 32);
    o0 += __shfl_xor(o0, 16); o0 += __shfl_xor(o0, 32);
    o1 += __shfl_xor(o1, 16); o1 += __shfl_xor(o1, 32);
    if (g == 0){
      h[(size_t)i*128 + cn0]      = o0/(s0 + 1e-16f);
      h[(size_t)i*128 + cn0 + 16] = o1/(s1 + 1e-16f);
    }
  }
}

// hd = relu(h @ Wd + bd)
__global__ __launch_bounds__(128) void k_down(const float* __restrict__ h,
    const float* __restrict__ Wd, const float* __restrict__ bd, float* __restrict__ hd){
  int g0 = blockIdx.x*8; int c = threadIdx.x;
  __shared__ float hs[8][128];
  for (int idx=c; idx<1024; idx+=128) hs[idx>>7][idx&127] = h[(g0 + (idx>>7))*128 + (idx&127)];
  __syncthreads();
  float acc[8]; float b = bd[c];
  #pragma unroll
  for (int g=0; g<8; g++) acc[g] = b;
  for (int k=0; k<128; k+=4){
    float w0=Wd[(k+0)*128+c], w1=Wd[(k+1)*128+c], w2=Wd[(k+2)*128+c], w3=Wd[(k+3)*128+c];
    #pragma unroll
    for (int g=0; g<8; g++){
      const float4 ev = *(const float4*)(&hs[g][k]);
      acc[g] += ev.x*w0 + ev.y*w1 + ev.z*w2 + ev.w*w3;
    }
  }
  #pragma unroll
  for (int g=0; g<8; g++) hd[(g0+g)*128+c] = fmaxf(acc[g], 0.0f);
}

// y = max(hd[i], max over 32 neighbors hd[src])
__global__ __launch_bounds__(128) void k_pool(const float* __restrict__ hd,
    const int* __restrict__ soft_src, const int* __restrict__ knn_src, float* __restrict__ y){
  int i = blockIdx.x; int c = threadIdx.x;
  __shared__ int ss[32];
  if (c < 16) ss[c] = soft_src[i*16+c];
  else if (c < 32) ss[c] = knn_src[i*16+(c-16)];
  __syncthreads();
  float p = hd[i*128+c];
  for (int e=0; e<32; e++) p = fmaxf(p, hd[ss[e]*128+c]);
  y[i*128+c] = p;
}

// ranks = sorted-unique inverse (count of nonzero bins with smaller vid)
__global__ __launch_bounds__(256) void k_scan(const int* __restrict__ hist,
    int* __restrict__ rank, int* __restrict__ ucnt, int* __restrict__ Uo){
  __shared__ int part[256];
  int t = threadIdx.x;
  int base = t*32;
  int cnt = 0;
  for (int b=0; b<32; b++) cnt += (hist[base+b] > 0);
  part[t] = cnt;
  __syncthreads();
  if (t == 0){
    int run = 0;
    for (int q=0; q<256; q++){ int v = part[q]; part[q] = run; run += v; }
    Uo[0] = run;
  }
  __syncthreads();
  int run = part[t];
  for (int b=0; b<32; b++){
    int bin = base + b;
    rank[bin] = run;
    int hv = hist[bin];
    if (hv > 0){ ucnt[run] = hv; run++; }
  }
}

__global__ __launch_bounds__(128) void k_agg(const float* __restrict__ y, const float* __restrict__ pos,
    const int* __restrict__ vid, const int* __restrict__ rank,
    float* __restrict__ accx, float* __restrict__ accp){
  int n = blockIdx.x; int c = threadIdx.x;
  int r = rank[vid[n]];
  atomicAdd(&accx[r*128+c], y[n*128+c]);
  if (c < 3) atomicAdd(&accp[r*3+c], pos[n*3+c]);
}

__global__ __launch_bounds__(128) void k_final(const float* __restrict__ accx, const float* __restrict__ accp,
    const int* __restrict__ ucnt, const int* __restrict__ Uo, float* __restrict__ out){
  int r = blockIdx.x; int c = threadIdx.x;
  int u = Uo[0];
  float cnt = (r < u) ? (float)ucnt[r] : 0.0f;
  float den = fmaxf(cnt, 1.0f);
  out[r*128+c] = (r < u) ? accx[r*128+c]/den : 0.0f;
  if (c < 3) out[(size_t)NN*128 + r*3 + c] = (r < u) ? accp[r*3+c]/den : 0.0f;
  if (c == 0) out[(size_t)NN*128 + (size_t)NN*3 + r] = cnt;
}

// ---------------- launcher ----------------
extern "C" void kernel_launch(void* const* d_in, const int* in_sizes, int n_in,
                              void* d_out, int out_size, void* d_ws, size_t ws_size,
                              hipStream_t stream){
  (void)in_sizes; (void)n_in; (void)out_size;
  const float* x    = (const float*)d_in[0];
  const float* pos  = (const float*)d_in[1];
  const float* Wg1  = (const float*)d_in[2];
  const float* bg1  = (const float*)d_in[3];
  const float* Wg2  = (const float*)d_in[4];
  const float* bg2  = (const float*)d_in[5];
  const float* Wlin = (const float*)d_in[6];
  const float* Wsrc = (const float*)d_in[7];
  const float* Wdst = (const float*)d_in[8];
  const float* Wp1  = (const float*)d_in[9];
  const float* bp1  = (const float*)d_in[10];
  const float* Wp2  = (const float*)d_in[11];
  const float* bp2  = (const float*)d_in[12];
  const float* Wa1  = (const float*)d_in[13];
  const float* ba1  = (const float*)d_in[14];
  const float* Wa2  = (const float*)d_in[15];
  const float* ba2  = (const float*)d_in[16];
  const float* Wd   = (const float*)d_in[17];
  const float* bd   = (const float*)d_in[18];

  char* ws = (char*)d_ws;
  float* embF   = (float*)(ws + OFF_EMBF);
  float* psum   = (float*)(ws + OFF_PSUM);
  int*   ssrc   = (int*)  (ws + OFF_SSRC);
  float* topv   = (float*)(ws + OFF_TOPV);
  int*   ksrc   = (int*)  (ws + OFF_KSRC);
  int*   hist   = (int*)  (ws + OFF_HIST);
  int*   rank   = (int*)  (ws + OFF_RANK);
  int*   ucnt   = (int*)  (ws + OFF_UCNT);
  int*   vid    = (int*)  (ws + OFF_VID);
  int*   mi     = (int*)  (ws + OFF_META);
  int*   mx     = (int*)  (ws + OFF_META + 16);
  int*   Uo     = (int*)  (ws + OFF_META + 32);
  int*   qKi    = (int*)  (ws + OFF_QKI);
  float4* pos4  = (float4*)(ws + OFF_POS4);
  unsigned short* WH = (unsigned short*)(ws + OFF_WH);
  unsigned short* WL = (unsigned short*)(ws + OFF_WL);
  float* A      = (float*)(ws + OFF_A);
  float* B      = (float*)(ws + OFF_B);
  float* V      = (float*)(ws + OFF_V);
  float* h      = (float*)(ws + OFF_H);
  float* hd     = (float*)(ws + OFF_HD);
  float* y      = (float*)(ws + OFF_Y);
  float* accx   = (float*)(ws + OFF_ACCX);
  float* accp   = (float*)(ws + OFF_ACCP);
  unsigned short* zq = (unsigned short*)(ws + OFF_ZQ);

  const bool use_q = (ws_size >= OFF_ZQ + ZQ_BYTES);   // constant per run -> deterministic

  // rk = jax.random.split(jax.random.key(42), 2)  -- host threefry (foldlike)
  u32 rk0a, rk0b, rk1a, rk1b;
  tf2x32(0u, 42u, 0u, 0u, rk0a, rk0b);
  tf2x32(0u, 42u, 0u, 1u, rk1a, rk1b);

  hipMemsetAsync(hist, 0, 8192*4, stream);
  k_wprep<<<384, 128, 0, stream>>>(Wp2, Wa1, Wa2, WH, WL);
  k_init0<<<1, 64, 0, stream>>>(mi, mx);
  k_min<<<32, 256, 0, stream>>>(pos, mi);
  k_ext<<<32, 256, 0, stream>>>(pos, mi, mx);
  k_vid<<<32, 256, 0, stream>>>(pos, mi, mx, vid, hist, pos4);
  k_emb<<<8192, 64, 0, stream>>>(x, Wg1, bg1, Wg2, bg2, rk0a, rk0b, embF);
  k_knn<<<8192, 64, 0, stream>>>(pos4, ksrc);
  if (use_q){
    k_colstats<true><<<dim3(32,32), 256, 0, stream>>>(embF, rk1a, rk1b, psum, zq);
    k_colfin<<<32, 256, 0, stream>>>(psum, embF, qKi);
    k_qtopk<<<8192, 64, 0, stream>>>(zq, qKi, embF, rk1a, rk1b, ssrc, topv);
  } else {
    k_colstats<false><<<dim3(32,32), 256, 0, stream>>>(embF, rk1a, rk1b, psum, nullptr);
    k_colfin<<<32, 256, 0, stream>>>(psum, embF, qKi);
    k_rowtopk<<<8192, 64, 0, stream>>>(embF, rk1a, rk1b, ssrc, topv);
  }
  // Overlap region is free of z-cache readers from here on.
  k_xw<<<1024, 128, 0, stream>>>(x, Wsrc, Wdst, Wlin, A, B, V);
  k_edge<<<8192, 256, 0, stream>>>(pos, ssrc, topv, ksrc, A, B, V,
                                   Wp1, bp1, WH, WL, bp2, ba1, ba2, h);
  k_down<<<1024, 128, 0, stream>>>(h, Wd, bd, hd);
  k_pool<<<8192, 128, 0, stream>>>(hd, ssrc, ksrc, y);
  hipMemsetAsync(accx, 0, (size_t)8192*128*4, stream);
  hipMemsetAsync(accp, 0, (size_t)8192*3*4, stream);
  k_scan<<<1, 256, 0, stream>>>(hist, rank, ucnt, Uo);
  k_agg<<<8192, 128, 0, stream>>>(y, pos, vid, rank, accx, accp);
  k_final<<<8192, 128, 0, stream>>>(accx, accp, ucnt, Uo, (float*)d_out);
}

// Round 16
// 739.063 us; speedup vs baseline: 1.2570x; 1.0254x over previous
//
#include <hip/hip_runtime.h>
#include <stdint.h>

// ---------------------------------------------------------------------------
// Enc_block: KNN graph + gumbel-softmax soft edges + PointTransformerConv +
// down + neighbor max-pool + GridSampling.  N=8192, Cin=64, Cout=128, K=16.
// k_edge uses MFMA (bf16 hi/lo split => ~fp32 accuracy, ~2^-16 rel err).
// ---------------------------------------------------------------------------

typedef unsigned int u32;
typedef float f32x4 __attribute__((ext_vector_type(4)));
typedef short bf16x8 __attribute__((ext_vector_type(8)));

#define NN 8192
#define EPS20 1e-20f
#define QSCALE 489.0671f   // 65535/134; z in [-99.8, 33.3] -> q = z*QSCALE + QBIAS
#define QBIAS  48907.21f   // 100*QSCALE + 0.5 (same transform for z and K)

// f32 -> bf16 round-to-nearest-even (returns low 16 bits)
__host__ __device__ static inline u32 bf16rne(float x){
  u32 b = __float_as_uint(x);
  return (b + 0x7fffu + ((b>>16)&1u)) >> 16;
}

// ---------------- threefry2x32 (JAX key schedule) ----------------
__host__ __device__ static inline u32 rotl32(u32 v, int r){ return __builtin_rotateleft32(v, (u32)r); }

__host__ __device__ static inline void tf2x32(u32 k0, u32 k1, u32 c0, u32 c1, u32& o0, u32& o1){
  u32 ks2 = k0 ^ k1 ^ 0x1BD11BDAu;
  u32 x0 = c0 + k0;
  u32 x1 = c1 + k1;
#define TFR(r) x0 += x1; x1 = rotl32(x1,(r)); x1 ^= x0;
  TFR(13) TFR(15) TFR(26) TFR(6)
  x0 += k1;  x1 += ks2 + 1u;
  TFR(17) TFR(29) TFR(16) TFR(24)
  x0 += ks2; x1 += k0 + 2u;
  TFR(13) TFR(15) TFR(26) TFR(6)
  x0 += k0;  x1 += k1 + 3u;
  TFR(17) TFR(29) TFR(16) TFR(24)
  x0 += k1;  x1 += ks2 + 4u;
  TFR(13) TFR(15) TFR(26) TFR(6)
  x0 += ks2; x1 += k0 + 5u;
#undef TFR
  o0 = x0; o1 = x1;
}

__device__ static inline u32 rbits(u32 k0, u32 k1, u32 idx){
  u32 o0,o1; tf2x32(k0,k1, 0u, idx, o0,o1);   // partitionable: counter (0, idx)
  return o0 ^ o1;                              // 32-bit fold
}

__device__ static inline float u01(u32 b){
  return __uint_as_float((b>>9) | 0x3f800000u) - 1.0f;   // [0,1), JAX formula
}

// z = 2*(g - d2); eps correction negligible for all selection-relevant entries
__device__ static inline float gumbel_g(u32 ub){
  float u = u01(ub);
  float w = -__logf(u + EPS20);
  return -__logf(w + EPS20);
}

// ---------------- workspace layout ----------------
static constexpr size_t OFF_EMBF = 0;                              // [8192][12] f32: e[10], se, K
static constexpr size_t OFF_SP   = OFF_EMBF + (size_t)8192*12*4;   // (unused, kept for layout)
static constexpr size_t OFF_PSUM = OFF_SP   + (size_t)8192*4;      // [128][8192] (64-row chunks)
static constexpr size_t OFF_SSRC = OFF_PSUM + (size_t)128*8192*4;  // int [8192][16]
static constexpr size_t OFF_TOPV = OFF_SSRC + (size_t)8192*16*4;
static constexpr size_t OFF_KSRC = OFF_TOPV + (size_t)8192*16*4;   // int [8192][16]
static constexpr size_t OFF_HIST = OFF_KSRC + (size_t)8192*16*4;   // int [8192]
static constexpr size_t OFF_RANK = OFF_HIST + (size_t)8192*4;
static constexpr size_t OFF_UCNT = OFF_RANK + (size_t)8192*4;
static constexpr size_t OFF_VID  = OFF_UCNT + (size_t)8192*4;
static constexpr size_t OFF_META = OFF_VID  + (size_t)8192*4;      // mi i[3] @0, mx i[3] @16B, U i @32B
static constexpr size_t OFF_QKI  = OFF_META + 64;                  // int [8192] quantized K
static constexpr size_t OFF_POS4 = OFF_QKI  + (size_t)8192*4;      // float4 [8192] {x,y,z,|p|^2}
static constexpr size_t OFF_WH   = (OFF_POS4 + (size_t)8192*16 + 255) & ~(size_t)255; // bf16 [3][128c][128k]
static constexpr size_t OFF_WL   = OFF_WH + (size_t)3*16384*2;
static constexpr size_t OFF_BIG  = (OFF_WL + (size_t)3*16384*2 + 255) & ~(size_t)255;
// Overlap region: u16 z-cache [8192][8192] lives here during colstats..qtopk;
// A/B/V/H/HD/Y/ACCX/ACCP live here afterwards (k_xw launched after qtopk).
static constexpr size_t OFF_A    = OFF_BIG;
static constexpr size_t OFF_B    = OFF_A    + (size_t)8192*128*4;
static constexpr size_t OFF_V    = OFF_B    + (size_t)8192*128*4;
static constexpr size_t OFF_H    = OFF_V    + (size_t)8192*128*4;
static constexpr size_t OFF_HD   = OFF_H    + (size_t)8192*128*4;
static constexpr size_t OFF_Y    = OFF_HD   + (size_t)8192*128*4;
static constexpr size_t OFF_ACCX = OFF_Y    + (size_t)8192*128*4;
static constexpr size_t OFF_ACCP = OFF_ACCX + (size_t)8192*128*4;
static constexpr size_t OFF_ZQ   = OFF_BIG;
static constexpr size_t ZQ_BYTES = (size_t)NN*NN*2;

// ---------------- kernels ----------------

__global__ void k_init0(int* __restrict__ mi, int* __restrict__ mx){
  int t = threadIdx.x;
  if (t < 3){ mi[t] = 0x7f7fffff; mx[t] = 0; }
}

// weight prep: Wp2/Wa1/Wa2 -> transposed bf16 hi/lo: W*[k][c] -> wt[m][c][k]
__global__ __launch_bounds__(128) void k_wprep(const float* __restrict__ Wp2,
    const float* __restrict__ Wa1, const float* __restrict__ Wa2,
    unsigned short* __restrict__ WH, unsigned short* __restrict__ WL){
  int m = blockIdx.x >> 7;
  int c = blockIdx.x & 127;
  int k = threadIdx.x;
  const float* Wm = (m==0) ? Wp2 : (m==1) ? Wa1 : Wa2;
  float x = Wm[k*128 + c];
  u32 hi = bf16rne(x);
  float lo = x - __uint_as_float(hi<<16);
  u32 lo16 = bf16rne(lo);
  size_t base = (size_t)m*16384 + (size_t)c*128 + k;
  WH[base] = (unsigned short)hi;
  WL[base] = (unsigned short)lo16;
}

// per-dim min of pos (positive floats: int-bit compare is order-preserving)
__global__ __launch_bounds__(256) void k_min(const float* __restrict__ pos, int* __restrict__ mi){
  __shared__ int red[768];
  int t = threadIdx.x;
  int n = blockIdx.x*256 + t;
  red[t]     = __float_as_int(pos[n*3+0]);
  red[256+t] = __float_as_int(pos[n*3+1]);
  red[512+t] = __float_as_int(pos[n*3+2]);
  __syncthreads();
  for (int s=128; s>0; s>>=1){
    if (t < s){
      red[t]     = min(red[t],     red[t+s]);
      red[256+t] = min(red[256+t], red[256+t+s]);
      red[512+t] = min(red[512+t], red[512+t+s]);
    }
    __syncthreads();
  }
  if (t == 0){ atomicMin(&mi[0], red[0]); atomicMin(&mi[1], red[256]); atomicMin(&mi[2], red[512]); }
}

// per-dim max voxel index
__global__ __launch_bounds__(256) void k_ext(const float* __restrict__ pos, const int* __restrict__ mi,
                                             int* __restrict__ mx){
  __shared__ int red[768];
  int t = threadIdx.x;
  int n = blockIdx.x*256 + t;
  float p0 = __int_as_float(mi[0]), p1 = __int_as_float(mi[1]), p2 = __int_as_float(mi[2]);
  red[t]     = (int)floorf((pos[n*3+0]-p0)*2.0f);   // /0.5 == *2 exactly
  red[256+t] = (int)floorf((pos[n*3+1]-p1)*2.0f);
  red[512+t] = (int)floorf((pos[n*3+2]-p2)*2.0f);
  __syncthreads();
  for (int s=128; s>0; s>>=1){
    if (t < s){
      red[t]     = max(red[t],     red[t+s]);
      red[256+t] = max(red[256+t], red[256+t+s]);
      red[512+t] = max(red[512+t], red[512+t+s]);
    }
    __syncthreads();
  }
  if (t == 0){ atomicMax(&mx[0], red[0]); atomicMax(&mx[1], red[256]); atomicMax(&mx[2], red[512]); }
}

// voxel id + histogram + SoA pos4 = {x,y,z,|p|^2}
__global__ __launch_bounds__(256) void k_vid(const float* __restrict__ pos,
                                             const int* __restrict__ mi, const int* __restrict__ mx,
                                             int* __restrict__ vid, int* __restrict__ hist,
                                             float4* __restrict__ pos4){
  int n = blockIdx.x*256 + threadIdx.x;
  float p0=pos[n*3], p1=pos[n*3+1], p2=pos[n*3+2];
  float4 p4; p4.x=p0; p4.y=p1; p4.z=p2; p4.w = p0*p0 + p1*p1 + p2*p2;
  pos4[n] = p4;
  float q0 = __int_as_float(mi[0]), q1 = __int_as_float(mi[1]), q2 = __int_as_float(mi[2]);
  int v0 = (int)floorf((p0-q0)*2.0f);
  int v1 = (int)floorf((p1-q1)*2.0f);
  int v2 = (int)floorf((p2-q2)*2.0f);
  int nv1 = mx[1]+1, nv2 = mx[2]+1;
  int id = (v0*nv1 + v1)*nv2 + v2;
  vid[n] = id;
  atomicAdd(&hist[id], 1);
}

// embF[i] = { relu(x@Wg1+bg1)@Wg2+bg2 + u*0.001  (10), |emb|^2, 0 }
__global__ __launch_bounds__(64) void k_emb(const float* __restrict__ x,
    const float* __restrict__ Wg1, const float* __restrict__ bg1,
    const float* __restrict__ Wg2, const float* __restrict__ bg2,
    u32 ka, u32 kb, float* __restrict__ embF){
  int i = blockIdx.x; int t = threadIdx.x;
  __shared__ float xs[64], hs[64], esq[10];
  xs[t] = x[i*64+t];
  __syncthreads();
  float a = bg1[t];
  for (int k=0; k<64; k++) a += xs[k]*Wg1[k*64+t];
  hs[t] = fmaxf(a, 0.0f);
  __syncthreads();
  if (t < 10){
    float e = bg2[t];
    for (int k=0; k<64; k++) e += hs[k]*Wg2[k*10+t];
    e += u01(rbits(ka, kb, (u32)(i*10+t))) * 0.001f;
    embF[i*12+t] = e;
    esq[t] = e*e;
  }
  __syncthreads();
  if (t == 0){
    float ssum = 0.0f;
    #pragma unroll
    for (int d=0; d<10; d++) ssum += esq[d];
    embF[i*12+10] = ssum;
    embF[i*12+11] = 0.0f;
  }
}

// KNN: top-16 smallest d2 per row (diag excluded), ties -> lower index.
__global__ __launch_bounds__(64) void k_knn(const float4* __restrict__ pos4,
                                            int* __restrict__ knn_src){
  int i = blockIdx.x; int l = threadIdx.x;
  float4 pi = pos4[i];
  float lv[8]; int lj[8];
  #pragma unroll
  for (int s=0; s<8; s++){ lv[s]=1e30f; lj[s]=0x7fffffff; }
  for (int tt=0; tt<128; tt++){
    int j = l + 64*tt;
    float4 pj = pos4[j];
    float d = pi.w + pj.w - 2.0f*(pi.x*pj.x + pi.y*pj.y + pi.z*pj.z);
    d = fmaxf(d, 0.0f);
    if (j != i && d < lv[7]){
      lv[7]=d; lj[7]=j;
      #pragma unroll
      for (int s=7; s>0; s--){
        if (lv[s] < lv[s-1]){ float tv=lv[s]; lv[s]=lv[s-1]; lv[s-1]=tv; int tj=lj[s]; lj[s]=lj[s-1]; lj[s-1]=tj; }
      }
    }
  }
  for (int r=0; r<16; r++){
    float bv = lv[0]; int bj = lj[0];
    #pragma unroll
    for (int off=32; off>=1; off>>=1){
      float ov = __shfl_xor(bv, off);
      int   oj = __shfl_xor(bj, off);
      if (ov < bv || (ov == bv && oj < bj)){ bv = ov; bj = oj; }
    }
    if (l == 0) knn_src[i*16+r] = bj;
    if (lj[0] == bj){
      #pragma unroll
      for (int s=0; s<7; s++){ lv[s]=lv[s+1]; lj[s]=lj[s+1]; }
      lv[7]=1e30f; lj[7]=0x7fffffff;
    }
  }
}

// column partial sums of exp(z-40) over a 64-ROW chunk (grid 32x128 = 16k waves
// -> 16 waves/SIMD; was 4/SIMD grid-starved, stalling threefry's serial chain).
template<bool STZ>
__global__ __launch_bounds__(256) void k_colstats(const float* __restrict__ embF,
                                                  u32 ka, u32 kb, float* __restrict__ psum,
                                                  unsigned short* __restrict__ zq){
  __shared__ float4 sE4[192];                 // 64 rows x 12 floats
  int t = threadIdx.x;
  int j = blockIdx.x*256 + t;
  int i0 = blockIdx.y*64;
  const float4* gF = (const float4*)embF;
  if (t < 192) sE4[t] = gF[(size_t)i0*3 + t];
  __syncthreads();
  float4 b0 = gF[j*3+0], b1 = gF[j*3+1], b2 = gF[j*3+2];
  float sej = b2.z;
  float s = 0.0f;
  unsigned short* zp = STZ ? (zq + ((size_t)i0<<13) + j) : nullptr;
  u32 idx = (u32)i0*8192u + (u32)j;
  #pragma unroll 4
  for (int r=0; r<64; r++){
    float4 a0 = sE4[r*3+0], a1 = sE4[r*3+1], a2 = sE4[r*3+2];
    float dot = a0.x*b0.x + a0.y*b0.y + a0.z*b0.z + a0.w*b0.w
              + a1.x*b1.x + a1.y*b1.y + a1.z*b1.z + a1.w*b1.w
              + a2.x*b2.x + a2.y*b2.y;
    float d2 = fmaxf(a2.z + sej - 2.0f*dot, 0.0f);
    float g = gumbel_g(rbits(ka, kb, idx));
    float z = 2.0f*(g - d2);
    s += __expf(z - 40.0f);
    if (STZ){
      float qf = z*QSCALE + QBIAS;
      qf = fminf(fmaxf(qf, 0.0f), 65535.0f);
      *zp = (unsigned short)qf;
      zp += NN;
    }
    idx += 8192u;
  }
  psum[blockIdx.y*NN + j] = s;
}

// K_j = 40 + log(sum_chunks psum); write f32 K into embF[j][11] and quantized K
__global__ __launch_bounds__(256) void k_colfin(const float* __restrict__ psum, float* __restrict__ embF,
                                                int* __restrict__ qKi){
  int j = blockIdx.x*256 + threadIdx.x;
  float S = 0.0f;
  for (int c=0; c<128; c++) S += psum[c*NN + j];
  float K = 40.0f + __logf(S);
  embF[j*12+11] = K;
  qKi[j] = (int)(K*QSCALE + QBIAS);   // same transform as z
}

// FALLBACK: per-row top-16 of y = z - K_j by full recompute
__global__ __launch_bounds__(64) void k_rowtopk(const float* __restrict__ embF,
    u32 ka, u32 kb, int* __restrict__ soft_src, float* __restrict__ top_v){
  int i = blockIdx.x; int l = threadIdx.x;
  const float4* gF = (const float4*)embF;
  float4 b0 = gF[i*3+0], b1 = gF[i*3+1], b2 = gF[i*3+2];
  float sei = b2.z;
  float lv[16]; int lj[16];
  #pragma unroll
  for (int s=0; s<16; s++){ lv[s]=-1e30f; lj[s]=0x7fffffff; }
  for (int tt=0; tt<128; tt++){
    int j = l + 64*tt;
    float4 a0 = gF[j*3+0], a1 = gF[j*3+1], a2 = gF[j*3+2];
    float dot = a0.x*b0.x + a0.y*b0.y + a0.z*b0.z + a0.w*b0.w
              + a1.x*b1.x + a1.y*b1.y + a1.z*b1.z + a1.w*b1.w
              + a2.x*b2.x + a2.y*b2.y;
    float d2 = fmaxf(a2.z + sei - 2.0f*dot, 0.0f);
    float g = gumbel_g(rbits(ka, kb, (u32)i*8192u + (u32)j));
    float z = 2.0f*(g - d2);
    float y = z - a2.w;
    if (y > lv[15]){
      lv[15]=y; lj[15]=j;
      #pragma unroll
      for (int s=15; s>0; s--){
        if (lv[s] > lv[s-1]){ float tv=lv[s]; lv[s]=lv[s-1]; lv[s-1]=tv; int tj=lj[s]; lj[s]=lj[s-1]; lj[s-1]=tj; }
      }
    }
  }
  for (int r=0; r<16; r++){
    float bv = lv[0]; int bj = lj[0];
    #pragma unroll
    for (int off=32; off>=1; off>>=1){
      float ov = __shfl_xor(bv, off);
      int   oj = __shfl_xor(bj, off);
      if (ov > bv || (ov == bv && oj < bj)){ bv = ov; bj = oj; }
    }
    if (l == 0){ soft_src[i*16+r] = bj; top_v[i*16+r] = __expf(bv); }
    if (lj[0] == bj){
      #pragma unroll
      for (int s=0; s<15; s++){ lv[s]=lv[s+1]; lj[s]=lj[s+1]; }
      lv[15]=-1e30f; lj[15]=0x7fffffff;
    }
  }
}

// cached path: per-row top-32 candidates by integer qy = q_z - q_K, then
// FUSED exact rescore of the 32 candidates -> exact top-16 (same kernel).
__global__ __launch_bounds__(64) void k_qtopk(const unsigned short* __restrict__ zq,
    const int* __restrict__ qKi, const float* __restrict__ embF,
    u32 ka, u32 kb, int* __restrict__ soft_src, float* __restrict__ top_v){
  int i = blockIdx.x; int l = threadIdx.x;
  const uint4* zrow = (const uint4*)(zq + ((size_t)i<<13));   // 8 u16 per uint4
  int lv[8]; int lj[8];
  #pragma unroll
  for (int s=0; s<8; s++){ lv[s]=-0x40000000; lj[s]=0x7fffffff; }
  for (int tt=0; tt<16; tt++){
    int blk = l + 64*tt;
    uint4 zv = zrow[blk];
    int jb = blk*8;
    const int4* qk4 = (const int4*)(qKi + jb);
    int4 ka4 = qk4[0], kb4 = qk4[1];
    u32 wv[4] = {zv.x, zv.y, zv.z, zv.w};
    int qk[8] = {ka4.x,ka4.y,ka4.z,ka4.w, kb4.x,kb4.y,kb4.z,kb4.w};
    #pragma unroll
    for (int c=0; c<8; c++){
      int qz = (int)((wv[c>>1] >> ((c&1)*16)) & 0xffffu);
      int qy = qz - qk[c];
      if (qy > lv[7]){
        lv[7]=qy; lj[7]=jb+c;
        #pragma unroll
        for (int s=7; s>0; s--){
          if (lv[s] > lv[s-1]){ int tv=lv[s]; lv[s]=lv[s-1]; lv[s-1]=tv; int tj=lj[s]; lj[s]=lj[s-1]; lj[s-1]=tj; }
        }
      }
    }
  }
  int myc = 0x7fffffff;          // lane r keeps candidate rank r (r<32)
  for (int r=0; r<32; r++){
    int bv = lv[0]; int bj = lj[0];
    #pragma unroll
    for (int off=32; off>=1; off>>=1){
      int ov = __shfl_xor(bv, off);
      int oj = __shfl_xor(bj, off);
      if (ov > bv || (ov == bv && oj < bj)){ bv = ov; bj = oj; }
    }
    if (l == r) myc = bj;
    if (lj[0] == bj){
      #pragma unroll
      for (int s=0; s<7; s++){ lv[s]=lv[s+1]; lj[s]=lj[s+1]; }
      lv[7]=-0x40000000; lj[7]=0x7fffffff;
    }
  }
  // fused exact rescore (identical arithmetic to the fallback path)
  const float4* gF = (const float4*)embF;
  float4 b0 = gF[i*3+0], b1 = gF[i*3+1], b2 = gF[i*3+2];
  float sei = b2.z;
  float y = -1e30f; int jc = 0x7fffffff;
  if (l < 32 && myc != 0x7fffffff){
    jc = myc;
    float4 a0 = gF[jc*3+0], a1 = gF[jc*3+1], a2 = gF[jc*3+2];
    float dot = a0.x*b0.x + a0.y*b0.y + a0.z*b0.z + a0.w*b0.w
              + a1.x*b1.x + a1.y*b1.y + a1.z*b1.z + a1.w*b1.w
              + a2.x*b2.x + a2.y*b2.y;
    float d2 = fmaxf(a2.z + sei - 2.0f*dot, 0.0f);
    float g = gumbel_g(rbits(ka, kb, (u32)i*8192u + (u32)jc));
    float z = 2.0f*(g - d2);
    y = z - a2.w;
  }
  for (int r=0; r<16; r++){
    float bv = y; int bj = jc;
    #pragma unroll
    for (int off=32; off>=1; off>>=1){
      float ov = __shfl_xor(bv, off);
      int   oj = __shfl_xor(bj, off);
      if (ov > bv || (ov == bv && oj < bj)){ bv = ov; bj = oj; }
    }
    if (l == 0){ soft_src[i*16+r] = bj; top_v[i*16+r] = __expf(bv); }
    if (jc == bj){ y = -1e30f; jc = 0x7fffffff; }
  }
}

// A = x@Wsrc, B = x@Wdst, V = x@Wlin  (8 rows per block)
__global__ __launch_bounds__(128) void k_xw(const float* __restrict__ x,
    const float* __restrict__ Wsrc, const float* __restrict__ Wdst, const float* __restrict__ Wlin,
    float* __restrict__ A, float* __restrict__ B, float* __restrict__ V){
  int g0 = blockIdx.x*8; int c = threadIdx.x;
  __shared__ float xs[8][64];
  for (int idx=c; idx<512; idx+=128) xs[idx>>6][idx&63] = x[(g0 + (idx>>6))*64 + (idx&63)];
  __syncthreads();
  float aA[8], aB[8], aV[8];
  #pragma unroll
  for (int g=0; g<8; g++){ aA[g]=0.0f; aB[g]=0.0f; aV[g]=0.0f; }
  for (int k=0; k<64; k++){
    float ws=Wsrc[k*128+c], wd=Wdst[k*128+c], wl=Wlin[k*128+c];
    #pragma unroll
    for (int g=0; g<8; g++){
      float xv = xs[g][k];
      aA[g] += xv*ws; aB[g] += xv*wd; aV[g] += xv*wl;
    }
  }
  #pragma unroll
  for (int g=0; g<8; g++){
    A[(g0+g)*128+c]=aA[g]; B[(g0+g)*128+c]=aB[g]; V[(g0+g)*128+c]=aV[g];
  }
}

// 12 MFMA per k-step: (hi*hi + hi*lo + lo*hi) x 4 C-tiles.  A from LDS, B (weights) from L2.
#define MFMA3(WHP, WLP)                                                     \
  {                                                                         \
    _Pragma("unroll")                                                       \
    for (int s=0; s<4; s++){                                                \
      int kk = 32*s + 8*g;                                                  \
      bf16x8 a0h = *(const bf16x8*)(&ah[r0][kk]);                           \
      bf16x8 a1h = *(const bf16x8*)(&ah[16+r0][kk]);                        \
      bf16x8 a0l = *(const bf16x8*)(&al[r0][kk]);                           \
      bf16x8 a1l = *(const bf16x8*)(&al[16+r0][kk]);                        \
      const unsigned short* whp = (WHP) + (size_t)cn0*128 + kk;             \
      const unsigned short* wlp = (WLP) + (size_t)cn0*128 + kk;             \
      bf16x8 b0h = *(const bf16x8*)(whp);                                   \
      bf16x8 b1h = *(const bf16x8*)(whp + 2048);                            \
      bf16x8 b0l = *(const bf16x8*)(wlp);                                   \
      bf16x8 b1l = *(const bf16x8*)(wlp + 2048);                            \
      c00 = __builtin_amdgcn_mfma_f32_16x16x32_bf16(a0h,b0h,c00,0,0,0);     \
      c01 = __builtin_amdgcn_mfma_f32_16x16x32_bf16(a0h,b1h,c01,0,0,0);     \
      c10 = __builtin_amdgcn_mfma_f32_16x16x32_bf16(a1h,b0h,c10,0,0,0);     \
      c11 = __builtin_amdgcn_mfma_f32_16x16x32_bf16(a1h,b1h,c11,0,0,0);     \
      c00 = __builtin_amdgcn_mfma_f32_16x16x32_bf16(a0h,b0l,c00,0,0,0);     \
      c01 = __builtin_amdgcn_mfma_f32_16x16x32_bf16(a0h,b1l,c01,0,0,0);     \
      c10 = __builtin_amdgcn_mfma_f32_16x16x32_bf16(a1h,b0l,c10,0,0,0);     \
      c11 = __builtin_amdgcn_mfma_f32_16x16x32_bf16(a1h,b1l,c11,0,0,0);     \
      c00 = __builtin_amdgcn_mfma_f32_16x16x32_bf16(a0l,b0h,c00,0,0,0);     \
      c01 = __builtin_amdgcn_mfma_f32_16x16x32_bf16(a0l,b1h,c01,0,0,0);     \
      c10 = __builtin_amdgcn_mfma_f32_16x16x32_bf16(a1l,b0h,c10,0,0,0);     \
      c11 = __builtin_amdgcn_mfma_f32_16x16x32_bf16(a1l,b1h,c11,0,0,0);     \
    }                                                                       \
  }

// PointTransformerConv via MFMA.  256 threads = 4 waves; wave w owns output
// cols [32w, 32w+32).  A-fragments: row = l&15 (+16 per m-tile), k = 8*(l>>4)+i.
// B from transposed bf16 weights wt[col][k].  C/D: col = l&15 (+16n), row =
// (l>>4)*4 + reg (+16m)  [guide-verified mapping].
__global__ __launch_bounds__(256) void k_edge(const float* __restrict__ pos,
    const int* __restrict__ soft_src, const float* __restrict__ top_v, const int* __restrict__ knn_src,
    const float* __restrict__ A, const float* __restrict__ B, const float* __restrict__ V,
    const float* __restrict__ Wp1, const float* __restrict__ bp1,
    const unsigned short* __restrict__ WH, const unsigned short* __restrict__ WL,
    const float* __restrict__ bp2, const float* __restrict__ ba1, const float* __restrict__ ba2,
    float* __restrict__ h){
  int i = blockIdx.x; int t = threadIdx.x;
  int l = t & 63; int w = t >> 6;
  int g = l >> 4; int r0 = l & 15;
  int cn0 = 32*w + r0;
  __shared__ __align__(16) unsigned short ah[32][136];
  __shared__ __align__(16) unsigned short al[32][136];
  __shared__ int   ssrc[32];
  __shared__ float sw[32];
  __shared__ float sdp[32][3];
  if (t < 32){
    int s; float wt;
    if (t < 16){ s = soft_src[i*16+t]; wt = top_v[i*16+t]; }
    else       { s = knn_src[i*16+(t-16)]; wt = 1.0f; }
    ssrc[t]=s; sw[t]=wt;
    sdp[t][0]=pos[i*3]-pos[s*3]; sdp[t][1]=pos[i*3+1]-pos[s*3+1]; sdp[t][2]=pos[i*3+2]-pos[s*3+2];
  }
  __syncthreads();
  // stage1: ph = relu(dpos @ Wp1 + bp1) -> bf16 hi/lo.  thread: wave rows x cols {2l,2l+1}
  {
    const float2* W1v = (const float2*)Wp1;
    float2 q0 = W1v[l], q1 = W1v[64+l], q2 = W1v[128+l];
    float2 bb = ((const float2*)bp1)[l];
    #pragma unroll
    for (int e=0; e<8; e++){
      int row = 8*w + e;
      float d0=sdp[row][0], d1=sdp[row][1], d2=sdp[row][2];
      float vx = fmaxf(d0*q0.x + d1*q1.x + d2*q2.x + bb.x, 0.0f);
      float vy = fmaxf(d0*q0.y + d1*q1.y + d2*q2.y + bb.y, 0.0f);
      u32 hx = bf16rne(vx), hy = bf16rne(vy);
      float lx = vx - __uint_as_float(hx<<16);
      float ly = vy - __uint_as_float(hy<<16);
      u32 lx16 = bf16rne(lx), ly16 = bf16rne(ly);
      *(u32*)(&ah[row][2*l]) = hx | (hy<<16);
      *(u32*)(&al[row][2*l]) = lx16 | (ly16<<16);
    }
  }
  // prefetch q-stage operands (independent of GEMM1) -- hides gather latency
  int ssv[8];
  float pfA0[8], pfA1[8];
  float B0, B1;
  {
    B0 = B[(size_t)i*128 + cn0];
    B1 = B[(size_t)i*128 + cn0 + 16];
    #pragma unroll
    for (int m=0; m<2; m++){
      #pragma unroll
      for (int r=0; r<4; r++){
        int row = 16*m + 4*g + r;
        int sv = ssrc[row]; ssv[m*4+r] = sv;
        pfA0[m*4+r] = A[(size_t)sv*128 + cn0];
        pfA1[m*4+r] = A[(size_t)sv*128 + cn0 + 16];
      }
    }
  }
  __syncthreads();
  f32x4 c00={0,0,0,0}, c01={0,0,0,0}, c10={0,0,0,0}, c11={0,0,0,0};
  // GEMM1: delta = ph @ Wp2 + bp2
  MFMA3(WH, WL);
  f32x4 dl00, dl01, dl10, dl11;
  {
    float bi0 = bp2[cn0], bi1 = bp2[cn0+16];
    #pragma unroll
    for (int r=0; r<4; r++){
      dl00[r]=c00[r]+bi0; dl01[r]=c01[r]+bi1;
      dl10[r]=c10[r]+bi0; dl11[r]=c11[r]+bi1;
    }
  }
  __syncthreads();                 // all GEMM1 reads of ah/al done
  // q-stage: q = B[i] - A[src] + delta -> bf16 hi/lo (prefetched operands)
  {
    #pragma unroll
    for (int m=0; m<2; m++){
      #pragma unroll
      for (int r=0; r<4; r++){
        int row = 16*m + 4*g + r;
        float q0 = B0 - pfA0[m*4+r] + (m ? dl10[r] : dl00[r]);
        float q1 = B1 - pfA1[m*4+r] + (m ? dl11[r] : dl01[r]);
        u32 h0 = bf16rne(q0); float lf0 = q0 - __uint_as_float(h0<<16);
        u32 h1 = bf16rne(q1); float lf1 = q1 - __uint_as_float(h1<<16);
        ah[row][cn0]    = (unsigned short)h0;  al[row][cn0]    = (unsigned short)bf16rne(lf0);
        ah[row][cn0+16] = (unsigned short)h1;  al[row][cn0+16] = (unsigned short)bf16rne(lf1);
      }
    }
  }
  __syncthreads();
  // GEMM2: ah_pre = q @ Wa1 + ba1
  c00=(f32x4){0,0,0,0}; c01=c00; c10=c00; c11=c00;
  MFMA3(WH + 16384, WL + 16384);
  __syncthreads();                 // all GEMM2 reads done
  {
    float b0v = ba1[cn0], b1v = ba1[cn0+16];
    #pragma unroll
    for (int m=0; m<2; m++){
      #pragma unroll
      for (int r=0; r<4; r++){
        int row = 16*m + 4*g + r;
        float v0 = fmaxf((m ? c10[r] : c00[r]) + b0v, 0.0f);
        float v1 = fmaxf((m ? c11[r] : c01[r]) + b1v, 0.0f);
        u32 h0 = bf16rne(v0); float lf0 = v0 - __uint_as_float(h0<<16);
        u32 h1 = bf16rne(v1); float lf1 = v1 - __uint_as_float(h1<<16);
        ah[row][cn0]    = (unsigned short)h0;  al[row][cn0]    = (unsigned short)bf16rne(lf0);
        ah[row][cn0+16] = (unsigned short)h1;  al[row][cn0+16] = (unsigned short)bf16rne(lf1);
      }
    }
  }
  __syncthreads();
  // prefetch V (epilogue operand, independent of GEMM3)
  float pfV0[8], pfV1[8];
  #pragma unroll
  for (int m=0; m<2; m++){
    #pragma unroll
    for (int r=0; r<4; r++){
      int sv = ssv[m*4+r];
      pfV0[m*4+r] = V[(size_t)sv*128 + cn0];
      pfV1[m*4+r] = V[(size_t)sv*128 + cn0 + 16];
    }
  }
  // GEMM3: logits = relu_out @ Wa2 + ba2
  c00=(f32x4){0,0,0,0}; c01=c00; c10=c00; c11=c00;
  MFMA3(WH + 32768, WL + 32768);
  // epilogue: per-col softmax over 32 edges (wave-local: rows split over lane groups)
  {
    float b0v = ba2[cn0], b1v = ba2[cn0+16];
    float lg[2][2][4];
    float M0 = -1e30f, M1 = -1e30f;
    #pragma unroll
    for (int m=0; m<2; m++){
      #pragma unroll
      for (int r=0; r<4; r++){
        lg[m][0][r] = (m ? c10[r] : c00[r]) + b0v;
        lg[m][1][r] = (m ? c11[r] : c01[r]) + b1v;
        M0 = fmaxf(M0, lg[m][0][r]);
        M1 = fmaxf(M1, lg[m][1][r]);
      }
    }
    M0 = fmaxf(M0, __shfl_xor(M0, 16)); M0 = fmaxf(M0, __shfl_xor(M0, 32));
    M1 = fmaxf(M1, __shfl_xor(M1, 16)); M1 = fmaxf(M1, __shfl_xor(M1, 32));
    float s0=0.0f, s1=0.0f, o0=0.0f, o1=0.0f;
    #pragma unroll
    for (int m=0; m<2; m++){
      #pragma unroll
      for (int r=0; r<4; r++){
        int row = 16*m + 4*g + r;
        float wt = sw[row];
        float p0 = __expf(lg[m][0][r] - M0);
        float p1 = __expf(lg[m][1][r] - M1);
        s0 += p0; s1 += p1;
        o0 += p0*(pfV0[m*4+r] + (m ? dl10[r] : dl00[r]))*wt;
        o1 += p1*(pfV1[m*4+r] + (m ? dl11[r] : dl01[r]))*wt;
      }
    }
    s0 += __shfl_xor(s0, 16); s0 += __shfl_xor(s0, 32);
    s1 += __shfl_xor(s1, 16); s1 += __shfl_xor(s1, 32);
    o0 += __shfl_xor(o0, 16); o0 += __shfl_xor(o0, 32);
    o1 += __shfl_xor(o1, 16); o1 += __shfl_xor(o1, 32);
    if (g == 0){
      h[(size_t)i*128 + cn0]      = o0/(s0 + 1e-16f);
      h[(size_t)i*128 + cn0 + 16] = o1/(s1 + 1e-16f);
    }
  }
}

// hd = relu(h @ Wd + bd)
__global__ __launch_bounds__(128) void k_down(const float* __restrict__ h,
    const float* __restrict__ Wd, const float* __restrict__ bd, float* __restrict__ hd){
  int g0 = blockIdx.x*8; int c = threadIdx.x;
  __shared__ float hs[8][128];
  for (int idx=c; idx<1024; idx+=128) hs[idx>>7][idx&127] = h[(g0 + (idx>>7))*128 + (idx&127)];
  __syncthreads();
  float acc[8]; float b = bd[c];
  #pragma unroll
  for (int g=0; g<8; g++) acc[g] = b;
  for (int k=0; k<128; k+=4){
    float w0=Wd[(k+0)*128+c], w1=Wd[(k+1)*128+c], w2=Wd[(k+2)*128+c], w3=Wd[(k+3)*128+c];
    #pragma unroll
    for (int g=0; g<8; g++){
      const float4 ev = *(const float4*)(&hs[g][k]);
      acc[g] += ev.x*w0 + ev.y*w1 + ev.z*w2 + ev.w*w3;
    }
  }
  #pragma unroll
  for (int g=0; g<8; g++) hd[(g0+g)*128+c] = fmaxf(acc[g], 0.0f);
}

// y = max(hd[i], max over 32 neighbors hd[src])
__global__ __launch_bounds__(128) void k_pool(const float* __restrict__ hd,
    const int* __restrict__ soft_src, const int* __restrict__ knn_src, float* __restrict__ y){
  int i = blockIdx.x; int c = threadIdx.x;
  __shared__ int ss[32];
  if (c < 16) ss[c] = soft_src[i*16+c];
  else if (c < 32) ss[c] = knn_src[i*16+(c-16)];
  __syncthreads();
  float p = hd[i*128+c];
  for (int e=0; e<32; e++) p = fmaxf(p, hd[ss[e]*128+c]);
  y[i*128+c] = p;
}

// ranks = sorted-unique inverse (count of nonzero bins with smaller vid)
__global__ __launch_bounds__(256) void k_scan(const int* __restrict__ hist,
    int* __restrict__ rank, int* __restrict__ ucnt, int* __restrict__ Uo){
  __shared__ int part[256];
  int t = threadIdx.x;
  int base = t*32;
  int cnt = 0;
  for (int b=0; b<32; b++) cnt += (hist[base+b] > 0);
  part[t] = cnt;
  __syncthreads();
  if (t == 0){
    int run = 0;
    for (int q=0; q<256; q++){ int v = part[q]; part[q] = run; run += v; }
    Uo[0] = run;
  }
  __syncthreads();
  int run = part[t];
  for (int b=0; b<32; b++){
    int bin = base + b;
    rank[bin] = run;
    int hv = hist[bin];
    if (hv > 0){ ucnt[run] = hv; run++; }
  }
}

__global__ __launch_bounds__(128) void k_agg(const float* __restrict__ y, const float* __restrict__ pos,
    const int* __restrict__ vid, const int* __restrict__ rank,
    float* __restrict__ accx, float* __restrict__ accp){
  int n = blockIdx.x; int c = threadIdx.x;
  int r = rank[vid[n]];
  atomicAdd(&accx[r*128+c], y[n*128+c]);
  if (c < 3) atomicAdd(&accp[r*3+c], pos[n*3+c]);
}

__global__ __launch_bounds__(128) void k_final(const float* __restrict__ accx, const float* __restrict__ accp,
    const int* __restrict__ ucnt, const int* __restrict__ Uo, float* __restrict__ out){
  int r = blockIdx.x; int c = threadIdx.x;
  int u = Uo[0];
  float cnt = (r < u) ? (float)ucnt[r] : 0.0f;
  float den = fmaxf(cnt, 1.0f);
  out[r*128+c] = (r < u) ? accx[r*128+c]/den : 0.0f;
  if (c < 3) out[(size_t)NN*128 + r*3 + c] = (r < u) ? accp[r*3+c]/den : 0.0f;
  if (c == 0) out[(size_t)NN*128 + (size_t)NN*3 + r] = cnt;
}

// ---------------- launcher ----------------
extern "C" void kernel_launch(void* const* d_in, const int* in_sizes, int n_in,
                              void* d_out, int out_size, void* d_ws, size_t ws_size,
                              hipStream_t stream){
  (void)in_sizes; (void)n_in; (void)out_size;
  const float* x    = (const float*)d_in[0];
  const float* pos  = (const float*)d_in[1];
  const float* Wg1  = (const float*)d_in[2];
  const float* bg1  = (const float*)d_in[3];
  const float* Wg2  = (const float*)d_in[4];
  const float* bg2  = (const float*)d_in[5];
  const float* Wlin = (const float*)d_in[6];
  const float* Wsrc = (const float*)d_in[7];
  const float* Wdst = (const float*)d_in[8];
  const float* Wp1  = (const float*)d_in[9];
  const float* bp1  = (const float*)d_in[10];
  const float* Wp2  = (const float*)d_in[11];
  const float* bp2  = (const float*)d_in[12];
  const float* Wa1  = (const float*)d_in[13];
  const float* ba1  = (const float*)d_in[14];
  const float* Wa2  = (const float*)d_in[15];
  const float* ba2  = (const float*)d_in[16];
  const float* Wd   = (const float*)d_in[17];
  const float* bd   = (const float*)d_in[18];

  char* ws = (char*)d_ws;
  float* embF   = (float*)(ws + OFF_EMBF);
  float* psum   = (float*)(ws + OFF_PSUM);
  int*   ssrc   = (int*)  (ws + OFF_SSRC);
  float* topv   = (float*)(ws + OFF_TOPV);
  int*   ksrc   = (int*)  (ws + OFF_KSRC);
  int*   hist   = (int*)  (ws + OFF_HIST);
  int*   rank   = (int*)  (ws + OFF_RANK);
  int*   ucnt   = (int*)  (ws + OFF_UCNT);
  int*   vid    = (int*)  (ws + OFF_VID);
  int*   mi     = (int*)  (ws + OFF_META);
  int*   mx     = (int*)  (ws + OFF_META + 16);
  int*   Uo     = (int*)  (ws + OFF_META + 32);
  int*   qKi    = (int*)  (ws + OFF_QKI);
  float4* pos4  = (float4*)(ws + OFF_POS4);
  unsigned short* WH = (unsigned short*)(ws + OFF_WH);
  unsigned short* WL = (unsigned short*)(ws + OFF_WL);
  float* A      = (float*)(ws + OFF_A);
  float* B      = (float*)(ws + OFF_B);
  float* V      = (float*)(ws + OFF_V);
  float* h      = (float*)(ws + OFF_H);
  float* hd     = (float*)(ws + OFF_HD);
  float* y      = (float*)(ws + OFF_Y);
  float* accx   = (float*)(ws + OFF_ACCX);
  float* accp   = (float*)(ws + OFF_ACCP);
  unsigned short* zq = (unsigned short*)(ws + OFF_ZQ);

  const bool use_q = (ws_size >= OFF_ZQ + ZQ_BYTES);   // constant per run -> deterministic

  // rk = jax.random.split(jax.random.key(42), 2)  -- host threefry (foldlike)
  u32 rk0a, rk0b, rk1a, rk1b;
  tf2x32(0u, 42u, 0u, 0u, rk0a, rk0b);
  tf2x32(0u, 42u, 0u, 1u, rk1a, rk1b);

  hipMemsetAsync(hist, 0, 8192*4, stream);
  k_wprep<<<384, 128, 0, stream>>>(Wp2, Wa1, Wa2, WH, WL);
  k_init0<<<1, 64, 0, stream>>>(mi, mx);
  k_min<<<32, 256, 0, stream>>>(pos, mi);
  k_ext<<<32, 256, 0, stream>>>(pos, mi, mx);
  k_vid<<<32, 256, 0, stream>>>(pos, mi, mx, vid, hist, pos4);
  k_emb<<<8192, 64, 0, stream>>>(x, Wg1, bg1, Wg2, bg2, rk0a, rk0b, embF);
  k_knn<<<8192, 64, 0, stream>>>(pos4, ksrc);
  if (use_q){
    k_colstats<true><<<dim3(32,128), 256, 0, stream>>>(embF, rk1a, rk1b, psum, zq);
    k_colfin<<<32, 256, 0, stream>>>(psum, embF, qKi);
    k_qtopk<<<8192, 64, 0, stream>>>(zq, qKi, embF, rk1a, rk1b, ssrc, topv);
  } else {
    k_colstats<false><<<dim3(32,128), 256, 0, stream>>>(embF, rk1a, rk1b, psum, nullptr);
    k_colfin<<<32, 256, 0, stream>>>(psum, embF, qKi);
    k_rowtopk<<<8192, 64, 0, stream>>>(embF, rk1a, rk1b, ssrc, topv);
  }
  // Overlap region is free of z-cache readers from here on.
  k_xw<<<1024, 128, 0, stream>>>(x, Wsrc, Wdst, Wlin, A, B, V);
  k_edge<<<8192, 256, 0, stream>>>(pos, ssrc, topv, ksrc, A, B, V,
                                   Wp1, bp1, WH, WL, bp2, ba1, ba2, h);
  k_down<<<1024, 128, 0, stream>>>(h, Wd, bd, hd);
  k_pool<<<8192, 128, 0, stream>>>(hd, ssrc, ksrc, y);
  hipMemsetAsync(accx, 0, (size_t)8192*128*4, stream);
  hipMemsetAsync(accp, 0, (size_t)8192*3*4, stream);
  k_scan<<<1, 256, 0, stream>>>(hist, rank, ucnt, Uo);
  k_agg<<<8192, 128, 0, stream>>>(y, pos, vid, rank, accx, accp);
  k_final<<<8192, 128, 0, stream>>>(accx, accp, ucnt, Uo, (float*)d_out);
}